// Round 20
// baseline (805.885 us; speedup 1.0000x reference)
//
#include <hip/hip_runtime.h>

// ---------------- types ----------------
typedef __attribute__((ext_vector_type(4))) float f32x4;
typedef __attribute__((ext_vector_type(8))) __bf16 bf16x8;
typedef __attribute__((ext_vector_type(4))) __bf16 bf16x4;
typedef __attribute__((ext_vector_type(8))) _Float16 f16x8;
typedef __attribute__((ext_vector_type(4))) _Float16 f16x4;

#define D_MODEL 2560
#define D_INNER 5120
#define N_STATE 128
#define HEADS 80
#define P_HEAD 64
#define CONV_DIM 5376
#define D_INPROJ 10576
#define SEQ 1024
#define NCHUNK 16
#define QCHUNK 64
#define NEXP 16
#define M_INTER 864
#define MS_INTER 1728
#define NSLOT 2048
#define NSLOTP 2176   // padded slot rows

__device__ __forceinline__ float siluf(float x) { return x / (1.f + __expf(-x)); }

// 32-group swizzle (ALL 16-bit GEMM planes): 16B chunk c (of 4) stored at c ^ P, P = 2-bit key
__device__ __forceinline__ int swz_p(int k4, int P) {
  return (k4 & ~31) | ((((k4 >> 3) & 3) ^ P) << 3) | (k4 & 7);
}

__device__ __forceinline__ void gl16(const __bf16* g, __bf16* l) {
  __builtin_amdgcn_global_load_lds((const __attribute__((address_space(1))) unsigned int*)g,
                                   (__attribute__((address_space(3))) unsigned int*)l, 16, 0, 0);
}

__device__ __forceinline__ float block_sum256(float v, float* red) {
#pragma unroll
  for (int m = 32; m > 0; m >>= 1) v += __shfl_xor(v, m, 64);
  int w = threadIdx.x >> 6;
  if ((threadIdx.x & 63) == 0) red[w] = v;
  __syncthreads();
  return red[0] + red[1] + red[2] + red[3];
}

// ---------------- RMSNorm -> swz32 16-bit plane + optional swz32 bf16 hi/lo planes ----------------
template <bool FP16>
__global__ __launch_bounds__(256) void k_rmsnorm_p(const float* __restrict__ in,
                                                   const float* __restrict__ w,
                                                   float* __restrict__ f32out,
                                                   __bf16* __restrict__ ph,
                                                   __bf16* __restrict__ pdh,
                                                   __bf16* __restrict__ pdl, int D) {
  __shared__ float red[4];
  int t = blockIdx.x, tid = threadIdx.x;
  const float* x = in + (size_t)t * D;
  int nd4 = D >> 2;
  float ss = 0.f;
  for (int i = tid; i < nd4; i += 256) {
    float4 v = ((const float4*)x)[i];
    ss += v.x * v.x + v.y * v.y + v.z * v.z + v.w * v.w;
  }
  float tot = block_sum256(ss, red);
  float r = rsqrtf(tot / (float)D + 1e-6f);
  int P = (t >> 1) & 3;
  for (int i = tid; i < nd4; i += 256) {
    float4 v = ((const float4*)x)[i];
    float4 wv = ((const float4*)w)[i];
    float4 o;
    o.x = wv.x * v.x * r; o.y = wv.y * v.y * r; o.z = wv.z * v.z * r; o.w = wv.w * v.w * r;
    if (f32out) ((float4*)(f32out + (size_t)t * D))[i] = o;
    int p = swz_p(i * 4, P);
    if constexpr (FP16) {
      f16x4 hv;
      hv[0] = (_Float16)o.x; hv[1] = (_Float16)o.y; hv[2] = (_Float16)o.z; hv[3] = (_Float16)o.w;
      *(f16x4*)&ph[(size_t)t * D + p] = hv;
    } else {
      bf16x4 hv;
      hv[0] = (__bf16)o.x; hv[1] = (__bf16)o.y; hv[2] = (__bf16)o.z; hv[3] = (__bf16)o.w;
      *(bf16x4*)&ph[(size_t)t * D + p] = hv;
    }
    if (pdh) {
      int pp = swz_p(i * 4, P);
      bf16x4 hv, lv;
      hv[0] = (__bf16)o.x; hv[1] = (__bf16)o.y; hv[2] = (__bf16)o.z; hv[3] = (__bf16)o.w;
      lv[0] = (__bf16)(o.x - (float)hv[0]); lv[1] = (__bf16)(o.y - (float)hv[1]);
      lv[2] = (__bf16)(o.z - (float)hv[2]); lv[3] = (__bf16)(o.w - (float)hv[3]);
      *(bf16x4*)&pdh[(size_t)t * D + pp] = hv;
      *(bf16x4*)&pdl[(size_t)t * D + pp] = lv;
    }
  }
}

// ---------------- fused: sum 4 out_proj partials + residual -> hidden; rmsnorm -> xmf + swz32 bf16 ----------------
__global__ __launch_bounds__(256) void k_redrms(const float* __restrict__ Pp,
                                                const float* __restrict__ res,
                                                float* __restrict__ hidden,
                                                const float* __restrict__ w,
                                                float* __restrict__ f32out,
                                                __bf16* __restrict__ ph) {
  __shared__ float vbuf[D_MODEL];
  __shared__ float red[4];
  int t = blockIdx.x, tid = threadIdx.x;
  const int n4 = D_MODEL / 4;
  float ss = 0.f;
  for (int i = tid; i < n4; i += 256) {
    f32x4 a = *(const f32x4*)&res[(size_t)t * D_MODEL + i * 4];
#pragma unroll
    for (int z = 0; z < 4; z++)
      a += *(const f32x4*)&Pp[(size_t)z * SEQ * D_MODEL + (size_t)t * D_MODEL + i * 4];
    *(f32x4*)&vbuf[i * 4] = a;
    *(f32x4*)&hidden[(size_t)t * D_MODEL + i * 4] = a;
    ss += a[0] * a[0] + a[1] * a[1] + a[2] * a[2] + a[3] * a[3];
  }
  float tot = block_sum256(ss, red);
  float r = rsqrtf(tot / (float)D_MODEL + 1e-6f);
  int P = (t >> 1) & 3;
  for (int i = tid; i < n4; i += 256) {
    f32x4 v = *(const f32x4*)&vbuf[i * 4];
    float4 wv = *(const float4*)&w[i * 4];
    f32x4 o;
    o[0] = wv.x * v[0] * r; o[1] = wv.y * v[1] * r; o[2] = wv.z * v[2] * r; o[3] = wv.w * v[3] * r;
    *(f32x4*)&f32out[(size_t)t * D_MODEL + i * 4] = o;
    int p = swz_p(i * 4, P);
    bf16x4 hv;
    hv[0] = (__bf16)o[0]; hv[1] = (__bf16)o[1]; hv[2] = (__bf16)o[2]; hv[3] = (__bf16)o[3];
    *(bf16x4*)&ph[(size_t)t * D_MODEL + p] = hv;
  }
}

// ---------------- weight transpose+convert: f32 [K][ld] (cols n0..n0+N) -> 16-bit [Npad][K] (swz32) ----------------
template <bool SPLIT, bool FP16>
__global__ __launch_bounds__(256) void k_transW(const float* __restrict__ W, int ld, int K, int N,
                                                __bf16* __restrict__ Th, __bf16* __restrict__ Tl) {
  __shared__ float T[64][65];
  const int n0 = blockIdx.x * 64, k0 = blockIdx.y * 64, tid = threadIdx.x;
#pragma unroll
  for (int i = 0; i < 16; i++) {
    int idx = tid + i * 256;
    int k = idx >> 6, n = idx & 63;
    float v = 0.f;
    if (n0 + n < N) v = W[(size_t)(k0 + k) * ld + n0 + n];
    T[k][n] = v;
  }
  __syncthreads();
#pragma unroll
  for (int i = 0; i < 4; i++) {
    int idx = tid + i * 256;
    int n = idx >> 4, p4 = (idx & 15) * 4;
    int nn = n0 + n;
    int P = (nn >> 1) & 3;
    if constexpr (SPLIT) {
      bf16x4 hv, lv;
#pragma unroll
      for (int e = 0; e < 4; e++) {
        int p = p4 + e;
        int kk = swz_p(p, P);
        float v = T[kk][n];
        __bf16 h = (__bf16)v;
        hv[e] = h;
        lv[e] = (__bf16)(v - (float)h);
      }
      *(bf16x4*)&Th[(size_t)nn * K + k0 + p4] = hv;
      *(bf16x4*)&Tl[(size_t)nn * K + k0 + p4] = lv;
    } else if constexpr (FP16) {
      f16x4 hv;
#pragma unroll
      for (int e = 0; e < 4; e++) {
        int p = p4 + e;
        int kk = swz_p(p, P);
        hv[e] = (_Float16)T[kk][n];
      }
      *(f16x4*)&Th[(size_t)nn * K + k0 + p4] = hv;
    } else {
      bf16x4 hv;
#pragma unroll
      for (int e = 0; e < 4; e++) {
        int p = p4 + e;
        int kk = swz_p(p, P);
        hv[e] = (__bf16)T[kk][n];
      }
      *(bf16x4*)&Th[(size_t)nn * K + k0 + p4] = hv;
    }
  }
}

// ---------------- 16-bit MFMA GEMM, BK=32, swz32 planes, XCD-grouped remap, optional dbuf pipeline ----------------
// logical grid: (bm=8, bn, z) — all launches have gridDim.x == 8, total % 8 == 0.
template <bool SPLIT, bool FP16, bool PIPE>
__global__ __launch_bounds__(256) void k_gemm2(const __bf16* __restrict__ Ah,
                                               const __bf16* __restrict__ Al,
                                               const __bf16* __restrict__ Bh,
                                               const __bf16* __restrict__ Bl,
                                               float* __restrict__ C,
                                               int M, int N, int K, int ks, int nst) {
  constexpr int PLE = 4096;                   // 128 rows x 32 k
  constexpr int NPL = SPLIT ? 4 : 2;
  constexpr int NBUF = PIPE ? 2 : 1;
  __shared__ __bf16 lds[NBUF * NPL * PLE];

  const int tid = threadIdx.x;
  const int T = gridDim.x * gridDim.y * gridDim.z;
  const int linear = blockIdx.x + gridDim.x * (blockIdx.y + gridDim.y * blockIdx.z);
  const int s_idx = (linear & 7) * (T >> 3) + (linear >> 3);
  const int bm = s_idx & 7;
  const int g = s_idx >> 3;
  const int bn = g % gridDim.y;
  const int z = g / gridDim.y;

  const int m0 = bm * 128, n0 = bn * 128;
  const int s0 = (int)(((long long)z * nst) / ks);
  const int s1 = (int)(((long long)(z + 1) * nst) / ks);
  float* __restrict__ Cp = C + (size_t)z * M * N;

  const int lane = tid & 63, wid = tid >> 6;
  const int wr = wid >> 1, wc = wid & 1;
  const int l16 = lane & 15, kl = lane >> 4;

  const int srow = tid >> 2;
  const int schunk = (tid & 3) * 8;
  const size_t aB0 = (size_t)(m0 + srow) * K + schunk;
  const size_t aB1 = aB0 + (size_t)64 * K;
  const size_t bB0 = (size_t)(n0 + srow) * K + schunk;
  const size_t bB1 = bB0 + (size_t)64 * K;

  int aoff[4], boff[4];
#pragma unroll
  for (int mi = 0; mi < 4; mi++) {
    int ra = wr * 64 + mi * 16 + l16;
    int rb = wc * 64 + mi * 16 + l16;
    aoff[mi] = ra * 64 + ((kl ^ ((ra >> 1) & 3)) << 4);
    boff[mi] = rb * 64 + ((kl ^ ((rb >> 1) & 3)) << 4);
  }

  f32x4 acc[4][4];
#pragma unroll
  for (int mi = 0; mi < 4; mi++)
#pragma unroll
    for (int ni = 0; ni < 4; ni++) acc[mi][ni] = f32x4{0.f, 0.f, 0.f, 0.f};

  auto STAGE = [&](int b, int kof) {
    __bf16* L = lds + (size_t)b * NPL * PLE;
    gl16(Ah + aB0 + kof, L + tid * 8);
    gl16(Ah + aB1 + kof, L + (tid + 256) * 8);
    gl16(Bh + bB0 + kof, L + (SPLIT ? 2 : 1) * PLE + tid * 8);
    gl16(Bh + bB1 + kof, L + (SPLIT ? 2 : 1) * PLE + (tid + 256) * 8);
    if constexpr (SPLIT) {
      gl16(Al + aB0 + kof, L + PLE + tid * 8);
      gl16(Al + aB1 + kof, L + PLE + (tid + 256) * 8);
      gl16(Bl + bB0 + kof, L + 3 * PLE + tid * 8);
      gl16(Bl + bB1 + kof, L + 3 * PLE + (tid + 256) * 8);
    }
  };

  auto COMPUTE = [&](const __bf16* L) {
    const char* AsH = (const char*)L;
    const char* BsH = (const char*)(L + (SPLIT ? 2 : 1) * PLE);
    if constexpr (!SPLIT && FP16) {
      f16x8 ah[4], bh[4];
#pragma unroll
      for (int mi = 0; mi < 4; mi++) ah[mi] = *(const f16x8*)(AsH + aoff[mi]);
#pragma unroll
      for (int ni = 0; ni < 4; ni++) bh[ni] = *(const f16x8*)(BsH + boff[ni]);
#pragma unroll
      for (int mi = 0; mi < 4; mi++)
#pragma unroll
        for (int ni = 0; ni < 4; ni++)
          acc[mi][ni] = __builtin_amdgcn_mfma_f32_16x16x32_f16(ah[mi], bh[ni], acc[mi][ni], 0, 0, 0);
    } else {
      bf16x8 ah[4], bh[4];
#pragma unroll
      for (int mi = 0; mi < 4; mi++) ah[mi] = *(const bf16x8*)(AsH + aoff[mi]);
#pragma unroll
      for (int ni = 0; ni < 4; ni++) bh[ni] = *(const bf16x8*)(BsH + boff[ni]);
#pragma unroll
      for (int mi = 0; mi < 4; mi++)
#pragma unroll
        for (int ni = 0; ni < 4; ni++)
          acc[mi][ni] = __builtin_amdgcn_mfma_f32_16x16x32_bf16(ah[mi], bh[ni], acc[mi][ni], 0, 0, 0);
      if constexpr (SPLIT) {
        const char* AsL = (const char*)(L + PLE);
        const char* BsL = (const char*)(L + 3 * PLE);
        bf16x8 al[4], bl[4];
#pragma unroll
        for (int mi = 0; mi < 4; mi++) al[mi] = *(const bf16x8*)(AsL + aoff[mi]);
#pragma unroll
        for (int ni = 0; ni < 4; ni++) bl[ni] = *(const bf16x8*)(BsL + boff[ni]);
#pragma unroll
        for (int mi = 0; mi < 4; mi++)
#pragma unroll
          for (int ni = 0; ni < 4; ni++) {
            acc[mi][ni] = __builtin_amdgcn_mfma_f32_16x16x32_bf16(ah[mi], bl[ni], acc[mi][ni], 0, 0, 0);
            acc[mi][ni] = __builtin_amdgcn_mfma_f32_16x16x32_bf16(al[mi], bh[ni], acc[mi][ni], 0, 0, 0);
          }
      }
    }
  };

  if constexpr (PIPE) {
    STAGE(0, s0 * 32);
    __syncthreads();
    int cur = 0;
    for (int s = s0; s < s1; ++s) {
      if (s + 1 < s1) STAGE(cur ^ 1, (s + 1) * 32);
      COMPUTE(lds + (size_t)cur * NPL * PLE);
      __syncthreads();
      cur ^= 1;
    }
  } else {
    for (int s = s0; s < s1; ++s) {
      __syncthreads();
      STAGE(0, s * 32);
      __syncthreads();
      COMPUTE(lds);
    }
  }

#pragma unroll
  for (int mi = 0; mi < 4; mi++)
#pragma unroll
    for (int ni = 0; ni < 4; ni++)
#pragma unroll
      for (int r = 0; r < 4; r++) {
        int row = m0 + wr * 64 + mi * 16 + kl * 4 + r;
        int col = n0 + wc * 64 + ni * 16 + l16;
        if (col < N) Cp[(size_t)row * N + col] = acc[mi][ni][r];
      }
}

// ---------------- partial reduce (no residual) ----------------
__global__ void k_reduce(const float* __restrict__ Pp, int np, int n4, float* __restrict__ out) {
  int i = blockIdx.x * 256 + threadIdx.x;
  int stride = gridDim.x * 256;
  for (; i < n4; i += stride) {
    float4 a = ((const float4*)Pp)[i];
    for (int z = 1; z < np; z++) {
      float4 b = ((const float4*)Pp)[(size_t)z * n4 + i];
      a.x += b.x; a.y += b.y; a.z += b.z; a.w += b.w;
    }
    ((float4*)out)[i] = a;
  }
}

// ---------------- dt finalize: sum 8 split-K partials + bias -> softplus ----------------
__global__ void k_dtfin(const float* __restrict__ dtP, const float* __restrict__ dt_bias,
                        const float* __restrict__ A_log, float* __restrict__ dtp,
                        float* __restrict__ dtA) {
  int t = blockIdx.x, h = threadIdx.x;
  if (h < HEADS) {
    float v = dt_bias[h];
#pragma unroll
    for (int z = 0; z < 8; z++) v += dtP[((size_t)z * SEQ + t) * 80 + h];
    float sp = fmaxf(v, 0.f) + log1pf(expf(-fabsf(v)));
    dtp[t * HEADS + h] = sp;
    dtA[t * HEADS + h] = sp * (-expf(A_log[h]));
  }
}

// ---------------- gather slot activations -> swz32 bf16 ----------------
__global__ __launch_bounds__(256) void k_gatherA(const float* __restrict__ xm,
                                                 const int* __restrict__ perm,
                                                 __bf16* __restrict__ Aslots) {
  int s = blockIdx.x, tid = threadIdx.x;
  int t = perm[s];
  int P = (s >> 1) & 3;
  const float* src = xm + (size_t)t * D_MODEL;
  __bf16* dst = Aslots + (size_t)s * D_MODEL;
  for (int i = tid; i < D_MODEL / 4; i += 256) {
    float4 v = ((const float4*)src)[i];
    int p = swz_p(i * 4, P);
    bf16x4 h;
    h[0] = (__bf16)v.x; h[1] = (__bf16)v.y; h[2] = (__bf16)v.z; h[3] = (__bf16)v.w;
    *(bf16x4*)&dst[p] = h;
  }
}

// ---------------- routed expert GEMM: BARRIER-FREE — A bf16 swz32 direct-to-reg (L3-hot), B f32 gather->bf16 in-reg ----------------
// No LDS, no __syncthreads in the K-loop: pure register dataflow, compiler software-pipelines loads across kt.
// step split-K (exact for any KS) + M-split; XCD-grouped remap.
template <int KS, int MS, bool DUAL>
__global__ __launch_bounds__(256) void k_gemmE2(const __bf16* __restrict__ Aall,
                                                const float* __restrict__ Bg,
                                                const float* __restrict__ Bg2,
                                                float* __restrict__ Cp,
                                                float* __restrict__ Cp2,
                                                const int* __restrict__ expOff,
                                                const int* __restrict__ expCnt,
                                                int N, int K, long long strideB, int bnHalf) {
  const int tid = threadIdx.x;
  // ---- XCD-grouped remap (bijective; hw xcd = linear % 8). Requires total % 8 == 0. ----
  const int nbn = gridDim.x;
  const int T = gridDim.x * gridDim.y * gridDim.z;
  const int lin = blockIdx.x + gridDim.x * (blockIdx.y + gridDim.y * blockIdx.z);
  const int s_rm = (lin & 7) * (T >> 3) + (lin >> 3);
  const int chunk = T >> 3;
  const int xcd = s_rm / chunk;
  const int cpos = s_rm % chunk;
  const int gsub = cpos / nbn;
  int bn = cpos % nbn;
  const int grp = xcd + 8 * gsub;
  const int sub = grp % (KS * MS);
  const int ks = sub % KS;
  const int mh = sub / KS;
  const int e = grp / (KS * MS);

  const int cnt = expCnt[e], base = expOff[e];
  if (cnt == 0) return;
  const float* Bp = Bg;
  float* Cdst = Cp;
  if constexpr (DUAL) {
    if (bn >= bnHalf) {
      bn -= bnHalf;
      Bp = Bg2;
      Cdst = Cp2;
    }
  }
  Bp += (long long)e * strideB;
  const int n0 = bn * 128;
  const int nSteps = K / 32;
  const int st0 = (ks * nSteps) / KS;
  const int st1 = ((ks + 1) * nSteps) / KS;
  const int kBeg = st0 * 32;
  const int nIter = st1 - st0;
  float* __restrict__ Cpl = Cdst + (size_t)ks * NSLOTP * N;
  const int lane = tid & 63, wid = tid >> 6;
  const int wr = wid >> 1, wc = wid & 1;
  const int l16 = lane & 15, kl = lane >> 4;

  // B column (clamped; acc for col>=N is garbage but never stored)
  const float* bptr[4];
#pragma unroll
  for (int ni = 0; ni < 4; ni++) {
    int c = n0 + wc * 64 + ni * 16 + l16;
    if (c >= N) c = N - 1;
    bptr[ni] = Bp + (size_t)(kBeg + kl * 8) * N + c;
  }

  for (int bm = mh; bm * 128 < cnt; bm += MS) {
    const int rbase = base + bm * 128;
    // per-mi A fragment base pointers (swz32: logical chunk kl lives at kl^P)
    const __bf16* aptr[4];
#pragma unroll
    for (int mi = 0; mi < 4; mi++) {
      int r = rbase + wr * 64 + mi * 16 + l16;
      int P = (r >> 1) & 3;
      aptr[mi] = Aall + (size_t)r * K + kBeg + ((kl ^ P) << 3);
    }
    f32x4 acc[4][4];
#pragma unroll
    for (int mi = 0; mi < 4; mi++)
#pragma unroll
      for (int ni = 0; ni < 4; ni++) acc[mi][ni] = f32x4{0.f, 0.f, 0.f, 0.f};

    for (int kt = 0; kt < nIter; ++kt) {
      bf16x8 ah[4];
#pragma unroll
      for (int mi = 0; mi < 4; mi++) ah[mi] = *(const bf16x8*)(aptr[mi] + kt * 32);
      bf16x8 bh[4];
#pragma unroll
      for (int ni = 0; ni < 4; ni++) {
        const float* s = bptr[ni] + (size_t)kt * 32 * N;
        float bv0 = s[0];
        float bv1 = s[(size_t)N];
        float bv2 = s[(size_t)2 * N];
        float bv3 = s[(size_t)3 * N];
        float bv4 = s[(size_t)4 * N];
        float bv5 = s[(size_t)5 * N];
        float bv6 = s[(size_t)6 * N];
        float bv7 = s[(size_t)7 * N];
        bf16x8 b;
        b[0] = (__bf16)bv0; b[1] = (__bf16)bv1; b[2] = (__bf16)bv2; b[3] = (__bf16)bv3;
        b[4] = (__bf16)bv4; b[5] = (__bf16)bv5; b[6] = (__bf16)bv6; b[7] = (__bf16)bv7;
        bh[ni] = b;
      }
#pragma unroll
      for (int mi = 0; mi < 4; mi++)
#pragma unroll
        for (int ni = 0; ni < 4; ni++)
          acc[mi][ni] = __builtin_amdgcn_mfma_f32_16x16x32_bf16(ah[mi], bh[ni], acc[mi][ni], 0, 0, 0);
    }

#pragma unroll
    for (int mi = 0; mi < 4; mi++)
#pragma unroll
      for (int ni = 0; ni < 4; ni++)
#pragma unroll
        for (int r = 0; r < 4; r++) {
          int rl = bm * 128 + wr * 64 + mi * 16 + kl * 4 + r;
          int col = n0 + wc * 64 + ni * 16 + l16;
          if (rl < cnt && col < N) Cpl[(size_t)(base + rl) * N + col] = acc[mi][ni][r];
        }
  }
}

// ---------------- routed: reduce gate/up partials (4 planes) + silu-mul + scale -> swz32 bf16 ----------------
__global__ __launch_bounds__(256) void k_silumulE(const float* __restrict__ gP,
                                                  const float* __restrict__ uP,
                                                  const float* __restrict__ slotw,
                                                  __bf16* __restrict__ outp) {
  int s = blockIdx.x, tid = threadIdx.x;
  float w = slotw[s];
  int P = (s >> 1) & 3;
  const size_t PL = (size_t)NSLOTP * M_INTER;
  for (int i = tid; i < M_INTER / 4; i += 256) {
    f32x4 g = f32x4{0.f, 0.f, 0.f, 0.f}, u = f32x4{0.f, 0.f, 0.f, 0.f};
#pragma unroll
    for (int z = 0; z < 4; z++) {
      g += *(const f32x4*)&gP[z * PL + (size_t)s * M_INTER + i * 4];
      u += *(const f32x4*)&uP[z * PL + (size_t)s * M_INTER + i * 4];
    }
    int p = swz_p(i * 4, P);
    bf16x4 h;
    h[0] = (__bf16)(siluf(g[0]) * u[0] * w);
    h[1] = (__bf16)(siluf(g[1]) * u[1] * w);
    h[2] = (__bf16)(siluf(g[2]) * u[2] * w);
    h[3] = (__bf16)(siluf(g[3]) * u[3] * w);
    *(bf16x4*)&outp[(size_t)s * M_INTER + p] = h;
  }
}

// ---------------- shared: reduce combined gate|up partials + silu-mul -> swz32 bf16 ----------------
__global__ __launch_bounds__(256) void k_silumul_sh2(const float* __restrict__ P4,
                                                     __bf16* __restrict__ outp) {
  int t = blockIdx.x, tid = threadIdx.x;
  int P = (t >> 1) & 3;
  const size_t PL = (size_t)SEQ * 3456;
  for (int i = tid; i < MS_INTER / 4; i += 256) {
    f32x4 g = f32x4{0.f, 0.f, 0.f, 0.f}, u = f32x4{0.f, 0.f, 0.f, 0.f};
#pragma unroll
    for (int z = 0; z < 4; z++) {
      g += *(const f32x4*)&P4[z * PL + (size_t)t * 3456 + i * 4];
      u += *(const f32x4*)&P4[z * PL + (size_t)t * 3456 + 1728 + i * 4];
    }
    int p = swz_p(i * 4, P);
    bf16x4 h;
    h[0] = (__bf16)(siluf(g[0]) * u[0]);
    h[1] = (__bf16)(siluf(g[1]) * u[1]);
    h[2] = (__bf16)(siluf(g[2]) * u[2]);
    h[3] = (__bf16)(siluf(g[3]) * u[3]);
    *(bf16x4*)&outp[(size_t)t * MS_INTER + p] = h;
  }
}

// ---------------- causal depthwise conv + SiLU ----------------
__global__ void k_conv(const float* __restrict__ zx, const float* __restrict__ cw,
                       const float* __restrict__ cb, float* __restrict__ xBC) {
  int cidx = blockIdx.x * 256 + threadIdx.x;
  int t = blockIdx.y;
  if (cidx < CONV_DIM) {
    float acc = cb[cidx];
#pragma unroll
    for (int j = 0; j < 4; j++) {
      int tt = t - 3 + j;
      if (tt >= 0) acc += zx[(size_t)tt * D_INPROJ + D_INNER + cidx] * cw[cidx * 4 + j];
    }
    xBC[(size_t)t * CONV_DIM + cidx] = siluf(acc);
  }
}

// ---------------- scan: intra-chunk (Q=64, swizzled LDS key (r>>2)&7, Cs/Gs union, fp16 X) ----------------
__global__ __launch_bounds__(256) void k_scan_intra(
    const float* __restrict__ xBC, const float* __restrict__ dtp,
    const float* __restrict__ dtA, float* __restrict__ y, float* __restrict__ S,
    float* __restrict__ cumA, float* __restrict__ Atot) {
  __shared__ float Bs[64 * 128];
  __shared__ float CG[64 * 128];
  __shared__ _Float16 Xs[64 * 64];
  __shared__ float da_s[64], a_s[64], dt_sh[64], w_sh[64];
  int c = blockIdx.x, h = blockIdx.y, tid = threadIdx.x;
  int t0 = c * QCHUNK;
#pragma unroll
  for (int i = 0; i < 8; i++) {
    int id = tid + 256 * i;
    int r = id >> 5, nc = id & 31;
    int sc = (nc ^ ((r >> 2) & 7)) * 4;
    *(float4*)&Bs[r * 128 + sc] = *(const float4*)&xBC[(size_t)(t0 + r) * CONV_DIM + D_INNER + nc * 4];
    *(float4*)&CG[r * 128 + sc] = *(const float4*)&xBC[(size_t)(t0 + r) * CONV_DIM + D_INNER + N_STATE + nc * 4];
  }
#pragma unroll
  for (int i = 0; i < 4; i++) {
    int id = tid + 256 * i;
    int r = id >> 4, p4 = (id & 15) * 4;
    float4 v = *(const float4*)&xBC[(size_t)(t0 + r) * CONV_DIM + h * P_HEAD + p4];
    f16x4 hv;
    hv[0] = (_Float16)v.x; hv[1] = (_Float16)v.y; hv[2] = (_Float16)v.z; hv[3] = (_Float16)v.w;
    *(f16x4*)&Xs[r * 64 + p4] = hv;
  }
  if (tid < 64) {
    da_s[tid] = dtA[(size_t)(t0 + tid) * HEADS + h];
    dt_sh[tid] = dtp[(size_t)(t0 + tid) * HEADS + h];
  }
  __syncthreads();
  if (tid < 64) {
    float a = 0.f;
    for (int i = 0; i <= tid; i++) a += da_s[i];
    a_s[tid] = a;
    cumA[((size_t)c * HEADS + h) * QCHUNK + tid] = a;
  }
  __syncthreads();
  if (tid < 64) {
    w_sh[tid] = __expf(a_s[63] - a_s[tid]) * dt_sh[tid];
    if (tid == 0) Atot[c * HEADS + h] = a_s[63];
  }
  __syncthreads();
  float gacc[4][4];
  {
    int tq = tid >> 4, sq = tid & 15;
#pragma unroll
    for (int j = 0; j < 4; j++)
#pragma unroll
      for (int jj = 0; jj < 4; jj++) gacc[j][jj] = 0.f;
    for (int nc = 0; nc < 32; nc++) {
      float4 cv[4], bv[4];
#pragma unroll
      for (int j = 0; j < 4; j++) {
        int rt = tq * 4 + j;
        cv[j] = *(const float4*)&CG[rt * 128 + ((nc ^ ((rt >> 2) & 7)) * 4)];
        int rs = sq * 4 + j;
        bv[j] = *(const float4*)&Bs[rs * 128 + ((nc ^ ((rs >> 2) & 7)) * 4)];
      }
#pragma unroll
      for (int j = 0; j < 4; j++)
#pragma unroll
        for (int jj = 0; jj < 4; jj++)
          gacc[j][jj] += cv[j].x * bv[jj].x + cv[j].y * bv[jj].y + cv[j].z * bv[jj].z + cv[j].w * bv[jj].w;
    }
  }
  __syncthreads();
  {
    int tq = tid >> 4, sq = tid & 15;
#pragma unroll
    for (int j = 0; j < 4; j++) {
      int t = tq * 4 + j;
      f32x4 gr;
#pragma unroll
      for (int jj = 0; jj < 4; jj++) {
        int s = sq * 4 + jj;
        float arg = fminf(a_s[t] - a_s[s], 0.f);
        gr[jj] = (s <= t) ? gacc[j][jj] * __expf(arg) * dt_sh[s] : 0.f;
      }
      *(f32x4*)&CG[t * 64 + ((sq ^ (t & 7)) * 4)] = gr;
    }
  }
  __syncthreads();
  {
    int tq = tid >> 4, pq = tid & 15;
    float4 acc[4];
#pragma unroll
    for (int j = 0; j < 4; j++) acc[j] = float4{0.f, 0.f, 0.f, 0.f};
    for (int s = 0; s < 64; s++) {
      f16x4 xh = *(const f16x4*)&Xs[s * 64 + pq * 4];
      float xv0 = (float)xh[0], xv1 = (float)xh[1], xv2 = (float)xh[2], xv3 = (float)xh[3];
#pragma unroll
      for (int j = 0; j < 4; j++) {
        int t = tq * 4 + j;
        float g = CG[t * 64 + (((s >> 2) ^ (t & 7)) * 4) + (s & 3)];
        acc[j].x += g * xv0; acc[j].y += g * xv1; acc[j].z += g * xv2; acc[j].w += g * xv3;
      }
    }
#pragma unroll
    for (int j = 0; j < 4; j++) {
      int t = tq * 4 + j;
      *(float4*)&y[(size_t)(t0 + t) * D_INNER + h * P_HEAD + pq * 4] = acc[j];
    }
  }
  {
    int p2 = tid >> 5, ncc = tid & 31;
    float4 acc[8];
#pragma unroll
    for (int j = 0; j < 8; j++) acc[j] = float4{0.f, 0.f, 0.f, 0.f};
    for (int s = 0; s < 64; s++) {
      float4 bvv = *(const float4*)&Bs[s * 128 + ((ncc ^ ((s >> 2) & 7)) * 4)];
      float ws = w_sh[s];
#pragma unroll
      for (int j = 0; j < 8; j++) {
        float xw = (float)Xs[s * 64 + p2 * 8 + j] * ws;
        acc[j].x += xw * bvv.x; acc[j].y += xw * bvv.y; acc[j].z += xw * bvv.z; acc[j].w += xw * bvv.w;
      }
    }
    size_t bb = ((size_t)(c * HEADS + h) * 64) * 128;
#pragma unroll
    for (int j = 0; j < 8; j++)
      *(float4*)&S[bb + (size_t)(p2 * 8 + j) * 128 + ncc * 4] = acc[j];
  }
}

// ---------------- scan: inter-chunk state recurrence ----------------
__global__ void k_scan_state(float* __restrict__ S, const float* __restrict__ Atot) {
  int gid = blockIdx.x * 256 + threadIdx.x;
  int h = gid >> 13;
  int rem = gid & 8191;
  float run = 0.f;
#pragma unroll
  for (int c = 0; c < NCHUNK; c++) {
    size_t idx = ((size_t)(c * HEADS + h) << 13) + rem;
    float s = S[idx];
    S[idx] = run;
    run = run * __expf(Atot[c * HEADS + h]) + s;
  }
}

// ---------------- scan: inter-chunk contribution + D*x (swizzled [64][128] Hs/Cs) ----------------
__global__ __launch_bounds__(256) void k_scan_inter(
    const float* __restrict__ xBC, const float* __restrict__ Hin,
    const float* __restrict__ cumA, const float* __restrict__ Dv,
    float* __restrict__ y) {
  __shared__ float Hs[64 * 128];
  __shared__ float Cs[64 * 128];
  __shared__ float a_l[64];
  int c = blockIdx.x, h = blockIdx.y, tid = threadIdx.x;
  int t0 = c * QCHUNK;
#pragma unroll
  for (int i = 0; i < 8; i++) {
    int id = tid + 256 * i;
    int r = id >> 5, nc = id & 31;
    int sc = (nc ^ ((r >> 2) & 7)) * 4;
    *(float4*)&Hs[r * 128 + sc] = *(const float4*)&Hin[(((size_t)(c * HEADS + h) * 64 + r) << 7) + nc * 4];
    *(float4*)&Cs[r * 128 + sc] = *(const float4*)&xBC[(size_t)(t0 + r) * CONV_DIM + D_INNER + N_STATE + nc * 4];
  }
  if (tid < 64) a_l[tid] = cumA[((size_t)c * HEADS + h) * QCHUNK + tid];
  __syncthreads();
  float Dh = Dv[h];
  int tq = tid >> 4, pq = tid & 15;
  float4 acc[4];
#pragma unroll
  for (int j = 0; j < 4; j++) acc[j] = float4{0.f, 0.f, 0.f, 0.f};
  for (int nc = 0; nc < 32; nc++) {
    float4 cv[4], hv[4];
#pragma unroll
    for (int j = 0; j < 4; j++) {
      int rt = tq * 4 + j;
      cv[j] = *(const float4*)&Cs[rt * 128 + ((nc ^ ((rt >> 2) & 7)) * 4)];
      int rp = pq * 4 + j;
      hv[j] = *(const float4*)&Hs[rp * 128 + ((nc ^ ((rp >> 2) & 7)) * 4)];
    }
#pragma unroll
    for (int j = 0; j < 4; j++) {
      acc[j].x += cv[j].x * hv[0].x + cv[j].y * hv[0].y + cv[j].z * hv[0].z + cv[j].w * hv[0].w;
      acc[j].y += cv[j].x * hv[1].x + cv[j].y * hv[1].y + cv[j].z * hv[1].z + cv[j].w * hv[1].w;
      acc[j].z += cv[j].x * hv[2].x + cv[j].y * hv[2].y + cv[j].z * hv[2].z + cv[j].w * hv[2].w;
      acc[j].w += cv[j].x * hv[3].x + cv[j].y * hv[3].y + cv[j].z * hv[3].z + cv[j].w * hv[3].w;
    }
  }
#pragma unroll
  for (int j = 0; j < 4; j++) {
    int t = tq * 4 + j;
    float e = __expf(a_l[t]);
    float4 xv = *(const float4*)&xBC[(size_t)(t0 + t) * CONV_DIM + h * P_HEAD + pq * 4];
    size_t yoff = (size_t)(t0 + t) * D_INNER + h * P_HEAD + pq * 4;
    float4 yv = *(float4*)&y[yoff];
    yv.x += e * acc[j].x + Dh * xv.x;
    yv.y += e * acc[j].y + Dh * xv.y;
    yv.z += e * acc[j].z + Dh * xv.z;
    yv.w += e * acc[j].w + Dh * xv.w;
    *(float4*)&y[yoff] = yv;
  }
}

// ---------------- gated RMSNorm -> swz32 fp16 plane ----------------
__global__ __launch_bounds__(256) void k_gatednorm_p(const float* __restrict__ y,
                                                     const float* __restrict__ zx,
                                                     const float* __restrict__ w,
                                                     __bf16* __restrict__ ph) {
  __shared__ float vbuf[D_INNER];
  __shared__ float red[4];
  int t = blockIdx.x, tid = threadIdx.x;
  float ss = 0.f;
  for (int i = tid; i < D_INNER / 4; i += 256) {
    float4 yv = *(const float4*)&y[(size_t)t * D_INNER + i * 4];
    float4 zv = *(const float4*)&zx[(size_t)t * D_INPROJ + i * 4];
    float4 v;
    v.x = yv.x * siluf(zv.x); v.y = yv.y * siluf(zv.y);
    v.z = yv.z * siluf(zv.z); v.w = yv.w * siluf(zv.w);
    *(float4*)&vbuf[i * 4] = v;
    ss += v.x * v.x + v.y * v.y + v.z * v.z + v.w * v.w;
  }
  float tot = block_sum256(ss, red);
  float r = rsqrtf(tot / (float)D_INNER + 1e-6f);
  int P = (t >> 1) & 3;
  for (int i = tid; i < D_INNER / 4; i += 256) {
    float4 v = *(const float4*)&vbuf[i * 4];
    float4 wv = *(const float4*)&w[i * 4];
    float4 o;
    o.x = wv.x * v.x * r; o.y = wv.y * v.y * r; o.z = wv.z * v.z * r; o.w = wv.w * v.w * r;
    int p = swz_p(i * 4, P);
    f16x4 hv;
    hv[0] = (_Float16)o.x; hv[1] = (_Float16)o.y; hv[2] = (_Float16)o.z; hv[3] = (_Float16)o.w;
    *(f16x4*)&ph[(size_t)t * D_INNER + p] = hv;
  }
}

// ---------------- router ----------------
__global__ void k_zero(int* counts, int* cursor) {
  int i = threadIdx.x;
  if (i < NEXP) { counts[i] = 0; cursor[i] = 0; }
}

__global__ __launch_bounds__(256) void k_router(const float* __restrict__ xm,
                                                const float* __restrict__ Wr,
                                                int* __restrict__ top_i,
                                                float* __restrict__ top_v,
                                                int* __restrict__ counts) {
  __shared__ float part[16][17];
  __shared__ float lg[16];
  int t = blockIdx.x, tid = threadIdx.x;
  int e = tid & 15, seg = tid >> 4;
  const float* xr = xm + (size_t)t * D_MODEL;
  float s = 0.f;
  for (int i = 0; i < 160; i++) {
    int k = seg * 160 + i;
    s += xr[k] * Wr[(size_t)k * NEXP + e];
  }
  part[seg][e] = s;
  __syncthreads();
  if (tid < 16) {
    float l = 0.f;
    for (int g = 0; g < 16; g++) l += part[g][tid];
    lg[tid] = l;
  }
  __syncthreads();
  if (tid == 0) {
    float mx = lg[0];
    for (int i = 1; i < 16; i++) mx = fmaxf(mx, lg[i]);
    float pe[16];
    for (int i = 0; i < 16; i++) pe[i] = expf(lg[i] - mx);
    int i0 = 0; float v0 = pe[0];
    for (int i = 1; i < 16; i++) if (pe[i] > v0) { v0 = pe[i]; i0 = i; }
    int i1 = -1; float v1 = -1.f;
    for (int i = 0; i < 16; i++) if (i != i0 && pe[i] > v1) { v1 = pe[i]; i1 = i; }
    float inv = 1.f / (v0 + v1);
    top_i[t * 2] = i0; top_i[t * 2 + 1] = i1;
    top_v[t * 2] = v0 * inv; top_v[t * 2 + 1] = v1 * inv;
    atomicAdd(&counts[i0], 1);
    atomicAdd(&counts[i1], 1);
  }
}

__global__ void k_offsets(const int* counts, int* offs, int* cursor) {
  if (threadIdx.x == 0) {
    int s = 0;
    for (int e = 0; e < NEXP; e++) { offs[e] = s; cursor[e] = s; s += counts[e]; }
  }
}

__global__ void k_scatter(const int* __restrict__ top_i, const float* __restrict__ top_v,
                          int* __restrict__ cursor, int* __restrict__ perm,
                          int* __restrict__ slotOf, float* __restrict__ slotw) {
  int t = blockIdx.x * 256 + threadIdx.x;
  if (t < SEQ) {
    for (int k = 0; k < 2; k++) {
      int e = top_i[t * 2 + k];
      int pos = atomicAdd(&cursor[e], 1);
      perm[pos] = t;
      slotOf[t * 2 + k] = pos;
      slotw[pos] = top_v[t * 2 + k];
    }
  }
}

// ---------------- final combine (3 down-partial planes) ----------------
__global__ void k_final2(const float* __restrict__ hidden, const float* __restrict__ sh,
                         const float* __restrict__ dsP, const int* __restrict__ slotOf,
                         float* __restrict__ out) {
  int t = blockIdx.y;
  int d4 = (blockIdx.x * 256 + threadIdx.x) * 4;
  if (d4 < D_MODEL) {
    int s0 = slotOf[t * 2], s1 = slotOf[t * 2 + 1];
    f32x4 a = *(const f32x4*)&hidden[(size_t)t * D_MODEL + d4];
    f32x4 b = *(const f32x4*)&sh[(size_t)t * D_MODEL + d4];
    f32x4 acc = a + b;
    const size_t PL = (size_t)NSLOTP * D_MODEL;
#pragma unroll
    for (int z = 0; z < 3; z++) {
      acc += *(const f32x4*)&dsP[z * PL + (size_t)s0 * D_MODEL + d4];
      acc += *(const f32x4*)&dsP[z * PL + (size_t)s1 * D_MODEL + d4];
    }
    *(f32x4*)&out[(size_t)t * D_MODEL + d4] = acc;
  }
}

// ---------------- launch ----------------
extern "C" void kernel_launch(void* const* d_in, const int* in_sizes, int n_in,
                              void* d_out, int out_size, void* d_ws, size_t ws_size,
                              hipStream_t stream) {
  const float* hs = (const float*)d_in[0];
  const float* w_in = (const float*)d_in[1];
  const float* conv_w = (const float*)d_in[2];
  const float* conv_b = (const float*)d_in[3];
  const float* dt_bias = (const float*)d_in[4];
  const float* A_log = (const float*)d_in[5];
  const float* Dv = (const float*)d_in[6];
  const float* mnw = (const float*)d_in[7];
  const float* w_out = (const float*)d_in[8];
  const float* ln1 = (const float*)d_in[9];
  const float* ln2 = (const float*)d_in[10];
  const float* router_w = (const float*)d_in[11];
  const float* we_gate = (const float*)d_in[12];
  const float* we_up = (const float*)d_in[13];
  const float* we_down = (const float*)d_in[14];
  const float* ws_gate = (const float*)d_in[15];
  const float* ws_up = (const float*)d_in[16];
  const float* ws_down = (const float*)d_in[17];

  char* base = (char*)d_ws;
  size_t off = 0;
  auto A = [&](size_t bytes) -> void* {
    void* p = base + off;
    off += (bytes + 255) & ~(size_t)255;
    return p;
  };
  float* xbc = (float*)A((size_t)SEQ * CONV_DIM * 4);
  float* xmf = (float*)A((size_t)SEQ * D_MODEL * 4);
  float* dtp = (float*)A((size_t)SEQ * HEADS * 4);
  float* dtA = (float*)A((size_t)SEQ * HEADS * 4);
  float* yf = (float*)A((size_t)SEQ * D_INNER * 4);
  float* cumA = (float*)A((size_t)NCHUNK * HEADS * QCHUNK * 4);
  float* Atot = (float*)A((size_t)NCHUNK * HEADS * 4);
  float* Sbuf = (float*)A((size_t)NCHUNK * HEADS * 64 * 128 * 4);
  float* hidden = (float*)A((size_t)SEQ * D_MODEL * 4);
  float* shout = (float*)A((size_t)SEQ * D_MODEL * 4);
  float* top_v = (float*)A(8192);
  float* slotw = (float*)A(8192);
  int* top_i = (int*)A(8192);
  int* counts = (int*)A(64);
  int* offs = (int*)A(64);
  int* cursor = (int*)A(64);
  int* perm = (int*)A(8192);
  int* slotOf = (int*)A(8192);
  __bf16* xp_h = (__bf16*)A((size_t)SEQ * D_MODEL * 2);
  __bf16* ybp_h = (__bf16*)A((size_t)SEQ * D_INNER * 2);
  __bf16* gbuf_bh = (__bf16*)A((size_t)SEQ * MS_INTER * 2);
  char* REG = (char*)A((size_t)163000000);

  // Phase M aliases
  __bf16* winT_h = (__bf16*)REG;                       // [10624][2560] f16 (54.4MB)
  float* zx = (float*)(REG + 60000000);                // [1024][10576] f32 (43.3MB)
  float* partials = (float*)(REG + 104000000);         // 4x1024x2560 f32 (41.9MB)
  __bf16* xdt_h = (__bf16*)(REG + 147000000);          // [1024][2560] bf16 hi (swz32)
  __bf16* xdt_l = (__bf16*)(REG + 152500000);
  __bf16* wdt_h = (__bf16*)(REG + 158000000);          // [128][2560] bf16 hi (swz32)
  __bf16* wdt_l = (__bf16*)(REG + 158700000);
  float* dtP = (float*)(REG + 159400000);              // 8x[1024][80] f32
  __bf16* woutT_h = (__bf16*)REG;                      // [2560][5120] f16 (after in_proj done)
  // Phase S aliases
  __bf16* guT = (__bf16*)REG;                          // [3456][2560] bf16 (gate | up)
  __bf16* downT = (__bf16*)(REG + 18350080);           // [2560][1728] bf16
  float* partials4 = (float*)(REG + 30000000);         // 4x[1024][3456] f32 (56.6 MB)
  // Phase R aliases
  __bf16* Aslots = (__bf16*)REG;                       // [2176][2560] bf16 (11.2MB)
  __bf16* gsl = (__bf16*)(REG + 12000000);             // [2176][864] bf16 (3.8MB)
  float* gateP = (float*)(REG + 16000000);             // 4x[2176][864] f32 (30.1MB, dead after silumulE)
  float* upP = (float*)(REG + 77000000);               // 4x[2176][864] f32 (30.1MB, dead after silumulE)
  float* dslotsP = (float*)(REG + 16000000);           // 3x[2176][2560] f32 (66.8MB, aliases dead gateP)

  // ---- Mamba sub-block ----
  k_rmsnorm_p<true><<<SEQ, 256, 0, stream>>>(hs, ln1, nullptr, xp_h, xdt_h, xdt_l, D_MODEL);
  k_transW<false, true><<<dim3(166, 40), 256, 0, stream>>>(w_in, D_INPROJ, D_MODEL, D_INPROJ,
                                                           winT_h, nullptr);
  k_transW<true, false><<<dim3(2, 40), 256, 0, stream>>>(w_in + 10496, D_INPROJ, D_MODEL, 80,
                                                         wdt_h, wdt_l);
  k_gemm2<false, true, true><<<dim3(8, 83, 1), 256, 0, stream>>>(
      xp_h, nullptr, winT_h, nullptr, zx, SEQ, D_INPROJ, D_MODEL, 1, 80);
  k_gemm2<true, false, false><<<dim3(8, 1, 8), 256, 0, stream>>>(
      xdt_h, xdt_l, wdt_h, wdt_l, dtP, SEQ, 80, D_MODEL, 8, 80);
  k_dtfin<<<SEQ, 128, 0, stream>>>(dtP, dt_bias, A_log, dtp, dtA);
  k_conv<<<dim3(21, SEQ), 256, 0, stream>>>(zx, conv_w, conv_b, xbc);
  k_scan_intra<<<dim3(NCHUNK, HEADS), 256, 0, stream>>>(xbc, dtp, dtA, yf, Sbuf, cumA, Atot);
  k_scan_state<<<2560, 256, 0, stream>>>(Sbuf, Atot);
  k_scan_inter<<<dim3(NCHUNK, HEADS), 256, 0, stream>>>(xbc, Sbuf, cumA, Dv, yf);
  k_gatednorm_p<<<SEQ, 256, 0, stream>>>(yf, zx, mnw, ybp_h);
  k_transW<false, true><<<dim3(40, 80), 256, 0, stream>>>(w_out, D_MODEL, D_INNER, D_MODEL,
                                                          woutT_h, nullptr);
  k_gemm2<false, true, true><<<dim3(8, 20, 4), 256, 0, stream>>>(
      ybp_h, nullptr, woutT_h, nullptr, partials, SEQ, D_MODEL, D_INNER, 4, 160);
  // fused: partials+residual -> hidden; rmsnorm -> xmf + xp_h (bf16 swz32)
  k_redrms<<<SEQ, 256, 0, stream>>>(partials, hs, hidden, ln2, xmf, xp_h);

  // ---- MoE sub-block ----
  k_zero<<<1, 64, 0, stream>>>(counts, cursor);
  k_router<<<SEQ, 256, 0, stream>>>(xmf, router_w, top_i, top_v, counts);
  k_offsets<<<1, 32, 0, stream>>>(counts, offs, cursor);
  k_scatter<<<4, 256, 0, stream>>>(top_i, top_v, cursor, perm, slotOf, slotw);

  // shared experts: combined gate|up GEMM (N=3456), fused reduce+silu
  k_transW<false, false><<<dim3(27, 40), 256, 0, stream>>>(ws_gate, MS_INTER, D_MODEL, MS_INTER,
                                                           guT, nullptr);
  k_transW<false, false><<<dim3(27, 40), 256, 0, stream>>>(ws_up, MS_INTER, D_MODEL, MS_INTER,
                                                           guT + (size_t)MS_INTER * D_MODEL, nullptr);
  k_gemm2<false, false, true><<<dim3(8, 27, 4), 256, 0, stream>>>(
      xp_h, nullptr, guT, nullptr, partials4, SEQ, 3456, D_MODEL, 4, 80);
  k_silumul_sh2<<<SEQ, 256, 0, stream>>>(partials4, gbuf_bh);
  k_transW<false, false><<<dim3(40, 27), 256, 0, stream>>>(ws_down, D_MODEL, MS_INTER, D_MODEL,
                                                           downT, nullptr);
  k_gemm2<false, false, true><<<dim3(8, 20, 4), 256, 0, stream>>>(
      gbuf_bh, nullptr, downT, nullptr, partials4, SEQ, D_MODEL, MS_INTER, 4, 54);
  k_reduce<<<2048, 256, 0, stream>>>(partials4, 4, SEQ * D_MODEL / 4, shout);

  // routed experts: barrier-free direct-reg GEMMs — gate|up (KS=4, MS=2), down (KS=3, MS=2)
  k_gatherA<<<NSLOT, 256, 0, stream>>>(xmf, perm, Aslots);
  k_gemmE2<4, 2, true><<<dim3(14, 8, NEXP), 256, 0, stream>>>(
      Aslots, we_gate, we_up, gateP, upP, offs, counts,
      M_INTER, D_MODEL, (long long)D_MODEL * M_INTER, 7);
  k_silumulE<<<NSLOT, 256, 0, stream>>>(gateP, upP, slotw, gsl);
  k_gemmE2<3, 2, false><<<dim3(20, 6, NEXP), 256, 0, stream>>>(
      gsl, we_down, nullptr, dslotsP, nullptr, offs, counts,
      D_MODEL, M_INTER, (long long)M_INTER * D_MODEL, 0);

  k_final2<<<dim3(3, SEQ), 256, 0, stream>>>(hidden, shout, dslotsP, slotOf, (float*)d_out);
}

// Round 21
// 725.746 us; speedup vs baseline: 1.1104x; 1.1104x over previous
//
#include <hip/hip_runtime.h>

// ---------------- types ----------------
typedef __attribute__((ext_vector_type(4))) float f32x4;
typedef __attribute__((ext_vector_type(8))) __bf16 bf16x8;
typedef __attribute__((ext_vector_type(4))) __bf16 bf16x4;
typedef __attribute__((ext_vector_type(8))) _Float16 f16x8;
typedef __attribute__((ext_vector_type(4))) _Float16 f16x4;

#define D_MODEL 2560
#define D_INNER 5120
#define N_STATE 128
#define HEADS 80
#define P_HEAD 64
#define CONV_DIM 5376
#define D_INPROJ 10576
#define SEQ 1024
#define NCHUNK 16
#define QCHUNK 64
#define NEXP 16
#define M_INTER 864
#define MS_INTER 1728
#define NSLOT 2048
#define NSLOTP 2176   // padded slot rows

__device__ __forceinline__ float siluf(float x) { return x / (1.f + __expf(-x)); }

// 32-group swizzle (ALL 16-bit GEMM planes): 16B chunk c (of 4) stored at c ^ P, P = 2-bit key
__device__ __forceinline__ int swz_p(int k4, int P) {
  return (k4 & ~31) | ((((k4 >> 3) & 3) ^ P) << 3) | (k4 & 7);
}

__device__ __forceinline__ void gl16(const __bf16* g, __bf16* l) {
  __builtin_amdgcn_global_load_lds((const __attribute__((address_space(1))) unsigned int*)g,
                                   (__attribute__((address_space(3))) unsigned int*)l, 16, 0, 0);
}

__device__ __forceinline__ float block_sum256(float v, float* red) {
#pragma unroll
  for (int m = 32; m > 0; m >>= 1) v += __shfl_xor(v, m, 64);
  int w = threadIdx.x >> 6;
  if ((threadIdx.x & 63) == 0) red[w] = v;
  __syncthreads();
  return red[0] + red[1] + red[2] + red[3];
}

// ---------------- RMSNorm -> swz32 16-bit plane + optional swz32 bf16 hi/lo planes ----------------
template <bool FP16>
__global__ __launch_bounds__(256) void k_rmsnorm_p(const float* __restrict__ in,
                                                   const float* __restrict__ w,
                                                   float* __restrict__ f32out,
                                                   __bf16* __restrict__ ph,
                                                   __bf16* __restrict__ pdh,
                                                   __bf16* __restrict__ pdl, int D) {
  __shared__ float red[4];
  int t = blockIdx.x, tid = threadIdx.x;
  const float* x = in + (size_t)t * D;
  int nd4 = D >> 2;
  float ss = 0.f;
  for (int i = tid; i < nd4; i += 256) {
    float4 v = ((const float4*)x)[i];
    ss += v.x * v.x + v.y * v.y + v.z * v.z + v.w * v.w;
  }
  float tot = block_sum256(ss, red);
  float r = rsqrtf(tot / (float)D + 1e-6f);
  int P = (t >> 1) & 3;
  for (int i = tid; i < nd4; i += 256) {
    float4 v = ((const float4*)x)[i];
    float4 wv = ((const float4*)w)[i];
    float4 o;
    o.x = wv.x * v.x * r; o.y = wv.y * v.y * r; o.z = wv.z * v.z * r; o.w = wv.w * v.w * r;
    if (f32out) ((float4*)(f32out + (size_t)t * D))[i] = o;
    int p = swz_p(i * 4, P);
    if constexpr (FP16) {
      f16x4 hv;
      hv[0] = (_Float16)o.x; hv[1] = (_Float16)o.y; hv[2] = (_Float16)o.z; hv[3] = (_Float16)o.w;
      *(f16x4*)&ph[(size_t)t * D + p] = hv;
    } else {
      bf16x4 hv;
      hv[0] = (__bf16)o.x; hv[1] = (__bf16)o.y; hv[2] = (__bf16)o.z; hv[3] = (__bf16)o.w;
      *(bf16x4*)&ph[(size_t)t * D + p] = hv;
    }
    if (pdh) {
      int pp = swz_p(i * 4, P);
      bf16x4 hv, lv;
      hv[0] = (__bf16)o.x; hv[1] = (__bf16)o.y; hv[2] = (__bf16)o.z; hv[3] = (__bf16)o.w;
      lv[0] = (__bf16)(o.x - (float)hv[0]); lv[1] = (__bf16)(o.y - (float)hv[1]);
      lv[2] = (__bf16)(o.z - (float)hv[2]); lv[3] = (__bf16)(o.w - (float)hv[3]);
      *(bf16x4*)&pdh[(size_t)t * D + pp] = hv;
      *(bf16x4*)&pdl[(size_t)t * D + pp] = lv;
    }
  }
}

// ---------------- fused: sum 4 out_proj partials + residual -> hidden; rmsnorm -> xmf + swz32 bf16 ----------------
__global__ __launch_bounds__(256) void k_redrms(const float* __restrict__ Pp,
                                                const float* __restrict__ res,
                                                float* __restrict__ hidden,
                                                const float* __restrict__ w,
                                                float* __restrict__ f32out,
                                                __bf16* __restrict__ ph) {
  __shared__ float vbuf[D_MODEL];
  __shared__ float red[4];
  int t = blockIdx.x, tid = threadIdx.x;
  const int n4 = D_MODEL / 4;
  float ss = 0.f;
  for (int i = tid; i < n4; i += 256) {
    f32x4 a = *(const f32x4*)&res[(size_t)t * D_MODEL + i * 4];
#pragma unroll
    for (int z = 0; z < 4; z++)
      a += *(const f32x4*)&Pp[(size_t)z * SEQ * D_MODEL + (size_t)t * D_MODEL + i * 4];
    *(f32x4*)&vbuf[i * 4] = a;
    *(f32x4*)&hidden[(size_t)t * D_MODEL + i * 4] = a;
    ss += a[0] * a[0] + a[1] * a[1] + a[2] * a[2] + a[3] * a[3];
  }
  float tot = block_sum256(ss, red);
  float r = rsqrtf(tot / (float)D_MODEL + 1e-6f);
  int P = (t >> 1) & 3;
  for (int i = tid; i < n4; i += 256) {
    f32x4 v = *(const f32x4*)&vbuf[i * 4];
    float4 wv = *(const float4*)&w[i * 4];
    f32x4 o;
    o[0] = wv.x * v[0] * r; o[1] = wv.y * v[1] * r; o[2] = wv.z * v[2] * r; o[3] = wv.w * v[3] * r;
    *(f32x4*)&f32out[(size_t)t * D_MODEL + i * 4] = o;
    int p = swz_p(i * 4, P);
    bf16x4 hv;
    hv[0] = (__bf16)o[0]; hv[1] = (__bf16)o[1]; hv[2] = (__bf16)o[2]; hv[3] = (__bf16)o[3];
    *(bf16x4*)&ph[(size_t)t * D_MODEL + p] = hv;
  }
}

// ---------------- weight transpose+convert: f32 [K][ld] (cols n0..n0+N) -> 16-bit [Npad][K] (swz32) ----------------
template <bool SPLIT, bool FP16>
__global__ __launch_bounds__(256) void k_transW(const float* __restrict__ W, int ld, int K, int N,
                                                __bf16* __restrict__ Th, __bf16* __restrict__ Tl) {
  __shared__ float T[64][65];
  const int n0 = blockIdx.x * 64, k0 = blockIdx.y * 64, tid = threadIdx.x;
#pragma unroll
  for (int i = 0; i < 16; i++) {
    int idx = tid + i * 256;
    int k = idx >> 6, n = idx & 63;
    float v = 0.f;
    if (n0 + n < N) v = W[(size_t)(k0 + k) * ld + n0 + n];
    T[k][n] = v;
  }
  __syncthreads();
#pragma unroll
  for (int i = 0; i < 4; i++) {
    int idx = tid + i * 256;
    int n = idx >> 4, p4 = (idx & 15) * 4;
    int nn = n0 + n;
    int P = (nn >> 1) & 3;
    if constexpr (SPLIT) {
      bf16x4 hv, lv;
#pragma unroll
      for (int e = 0; e < 4; e++) {
        int p = p4 + e;
        int kk = swz_p(p, P);
        float v = T[kk][n];
        __bf16 h = (__bf16)v;
        hv[e] = h;
        lv[e] = (__bf16)(v - (float)h);
      }
      *(bf16x4*)&Th[(size_t)nn * K + k0 + p4] = hv;
      *(bf16x4*)&Tl[(size_t)nn * K + k0 + p4] = lv;
    } else if constexpr (FP16) {
      f16x4 hv;
#pragma unroll
      for (int e = 0; e < 4; e++) {
        int p = p4 + e;
        int kk = swz_p(p, P);
        hv[e] = (_Float16)T[kk][n];
      }
      *(f16x4*)&Th[(size_t)nn * K + k0 + p4] = hv;
    } else {
      bf16x4 hv;
#pragma unroll
      for (int e = 0; e < 4; e++) {
        int p = p4 + e;
        int kk = swz_p(p, P);
        hv[e] = (__bf16)T[kk][n];
      }
      *(bf16x4*)&Th[(size_t)nn * K + k0 + p4] = hv;
    }
  }
}

// ---------------- 16-bit MFMA GEMM, BK=32, swz32 planes, XCD-grouped remap, optional dbuf pipeline ----------------
// logical grid: (bm=8, bn, z) — all launches have gridDim.x == 8, total % 8 == 0.
template <bool SPLIT, bool FP16, bool PIPE>
__global__ __launch_bounds__(256) void k_gemm2(const __bf16* __restrict__ Ah,
                                               const __bf16* __restrict__ Al,
                                               const __bf16* __restrict__ Bh,
                                               const __bf16* __restrict__ Bl,
                                               float* __restrict__ C,
                                               int M, int N, int K, int ks, int nst) {
  constexpr int PLE = 4096;                   // 128 rows x 32 k
  constexpr int NPL = SPLIT ? 4 : 2;
  constexpr int NBUF = PIPE ? 2 : 1;
  __shared__ __bf16 lds[NBUF * NPL * PLE];

  const int tid = threadIdx.x;
  const int T = gridDim.x * gridDim.y * gridDim.z;
  const int linear = blockIdx.x + gridDim.x * (blockIdx.y + gridDim.y * blockIdx.z);
  const int s_idx = (linear & 7) * (T >> 3) + (linear >> 3);
  const int bm = s_idx & 7;
  const int g = s_idx >> 3;
  const int bn = g % gridDim.y;
  const int z = g / gridDim.y;

  const int m0 = bm * 128, n0 = bn * 128;
  const int s0 = (int)(((long long)z * nst) / ks);
  const int s1 = (int)(((long long)(z + 1) * nst) / ks);
  float* __restrict__ Cp = C + (size_t)z * M * N;

  const int lane = tid & 63, wid = tid >> 6;
  const int wr = wid >> 1, wc = wid & 1;
  const int l16 = lane & 15, kl = lane >> 4;

  const int srow = tid >> 2;
  const int schunk = (tid & 3) * 8;
  const size_t aB0 = (size_t)(m0 + srow) * K + schunk;
  const size_t aB1 = aB0 + (size_t)64 * K;
  const size_t bB0 = (size_t)(n0 + srow) * K + schunk;
  const size_t bB1 = bB0 + (size_t)64 * K;

  int aoff[4], boff[4];
#pragma unroll
  for (int mi = 0; mi < 4; mi++) {
    int ra = wr * 64 + mi * 16 + l16;
    int rb = wc * 64 + mi * 16 + l16;
    aoff[mi] = ra * 64 + ((kl ^ ((ra >> 1) & 3)) << 4);
    boff[mi] = rb * 64 + ((kl ^ ((rb >> 1) & 3)) << 4);
  }

  f32x4 acc[4][4];
#pragma unroll
  for (int mi = 0; mi < 4; mi++)
#pragma unroll
    for (int ni = 0; ni < 4; ni++) acc[mi][ni] = f32x4{0.f, 0.f, 0.f, 0.f};

  auto STAGE = [&](int b, int kof) {
    __bf16* L = lds + (size_t)b * NPL * PLE;
    gl16(Ah + aB0 + kof, L + tid * 8);
    gl16(Ah + aB1 + kof, L + (tid + 256) * 8);
    gl16(Bh + bB0 + kof, L + (SPLIT ? 2 : 1) * PLE + tid * 8);
    gl16(Bh + bB1 + kof, L + (SPLIT ? 2 : 1) * PLE + (tid + 256) * 8);
    if constexpr (SPLIT) {
      gl16(Al + aB0 + kof, L + PLE + tid * 8);
      gl16(Al + aB1 + kof, L + PLE + (tid + 256) * 8);
      gl16(Bl + bB0 + kof, L + 3 * PLE + tid * 8);
      gl16(Bl + bB1 + kof, L + 3 * PLE + (tid + 256) * 8);
    }
  };

  auto COMPUTE = [&](const __bf16* L) {
    const char* AsH = (const char*)L;
    const char* BsH = (const char*)(L + (SPLIT ? 2 : 1) * PLE);
    if constexpr (!SPLIT && FP16) {
      f16x8 ah[4], bh[4];
#pragma unroll
      for (int mi = 0; mi < 4; mi++) ah[mi] = *(const f16x8*)(AsH + aoff[mi]);
#pragma unroll
      for (int ni = 0; ni < 4; ni++) bh[ni] = *(const f16x8*)(BsH + boff[ni]);
#pragma unroll
      for (int mi = 0; mi < 4; mi++)
#pragma unroll
        for (int ni = 0; ni < 4; ni++)
          acc[mi][ni] = __builtin_amdgcn_mfma_f32_16x16x32_f16(ah[mi], bh[ni], acc[mi][ni], 0, 0, 0);
    } else {
      bf16x8 ah[4], bh[4];
#pragma unroll
      for (int mi = 0; mi < 4; mi++) ah[mi] = *(const bf16x8*)(AsH + aoff[mi]);
#pragma unroll
      for (int ni = 0; ni < 4; ni++) bh[ni] = *(const bf16x8*)(BsH + boff[ni]);
#pragma unroll
      for (int mi = 0; mi < 4; mi++)
#pragma unroll
        for (int ni = 0; ni < 4; ni++)
          acc[mi][ni] = __builtin_amdgcn_mfma_f32_16x16x32_bf16(ah[mi], bh[ni], acc[mi][ni], 0, 0, 0);
      if constexpr (SPLIT) {
        const char* AsL = (const char*)(L + PLE);
        const char* BsL = (const char*)(L + 3 * PLE);
        bf16x8 al[4], bl[4];
#pragma unroll
        for (int mi = 0; mi < 4; mi++) al[mi] = *(const bf16x8*)(AsL + aoff[mi]);
#pragma unroll
        for (int ni = 0; ni < 4; ni++) bl[ni] = *(const bf16x8*)(BsL + boff[ni]);
#pragma unroll
        for (int mi = 0; mi < 4; mi++)
#pragma unroll
          for (int ni = 0; ni < 4; ni++) {
            acc[mi][ni] = __builtin_amdgcn_mfma_f32_16x16x32_bf16(ah[mi], bl[ni], acc[mi][ni], 0, 0, 0);
            acc[mi][ni] = __builtin_amdgcn_mfma_f32_16x16x32_bf16(al[mi], bh[ni], acc[mi][ni], 0, 0, 0);
          }
      }
    }
  };

  if constexpr (PIPE) {
    STAGE(0, s0 * 32);
    __syncthreads();
    int cur = 0;
    for (int s = s0; s < s1; ++s) {
      if (s + 1 < s1) STAGE(cur ^ 1, (s + 1) * 32);
      COMPUTE(lds + (size_t)cur * NPL * PLE);
      __syncthreads();
      cur ^= 1;
    }
  } else {
    for (int s = s0; s < s1; ++s) {
      __syncthreads();
      STAGE(0, s * 32);
      __syncthreads();
      COMPUTE(lds);
    }
  }

#pragma unroll
  for (int mi = 0; mi < 4; mi++)
#pragma unroll
    for (int ni = 0; ni < 4; ni++)
#pragma unroll
      for (int r = 0; r < 4; r++) {
        int row = m0 + wr * 64 + mi * 16 + kl * 4 + r;
        int col = n0 + wc * 64 + ni * 16 + l16;
        if (col < N) Cp[(size_t)row * N + col] = acc[mi][ni][r];
      }
}

// ---------------- partial reduce (no residual) ----------------
__global__ void k_reduce(const float* __restrict__ Pp, int np, int n4, float* __restrict__ out) {
  int i = blockIdx.x * 256 + threadIdx.x;
  int stride = gridDim.x * 256;
  for (; i < n4; i += stride) {
    float4 a = ((const float4*)Pp)[i];
    for (int z = 1; z < np; z++) {
      float4 b = ((const float4*)Pp)[(size_t)z * n4 + i];
      a.x += b.x; a.y += b.y; a.z += b.z; a.w += b.w;
    }
    ((float4*)out)[i] = a;
  }
}

// ---------------- dt finalize: sum 8 split-K partials + bias -> softplus ----------------
__global__ void k_dtfin(const float* __restrict__ dtP, const float* __restrict__ dt_bias,
                        const float* __restrict__ A_log, float* __restrict__ dtp,
                        float* __restrict__ dtA) {
  int t = blockIdx.x, h = threadIdx.x;
  if (h < HEADS) {
    float v = dt_bias[h];
#pragma unroll
    for (int z = 0; z < 8; z++) v += dtP[((size_t)z * SEQ + t) * 80 + h];
    float sp = fmaxf(v, 0.f) + log1pf(expf(-fabsf(v)));
    dtp[t * HEADS + h] = sp;
    dtA[t * HEADS + h] = sp * (-expf(A_log[h]));
  }
}

// ---------------- gather slot activations -> swz32 bf16 ----------------
__global__ __launch_bounds__(256) void k_gatherA(const float* __restrict__ xm,
                                                 const int* __restrict__ perm,
                                                 __bf16* __restrict__ Aslots) {
  int s = blockIdx.x, tid = threadIdx.x;
  int t = perm[s];
  int P = (s >> 1) & 3;
  const float* src = xm + (size_t)t * D_MODEL;
  __bf16* dst = Aslots + (size_t)s * D_MODEL;
  for (int i = tid; i < D_MODEL / 4; i += 256) {
    float4 v = ((const float4*)src)[i];
    int p = swz_p(i * 4, P);
    bf16x4 h;
    h[0] = (__bf16)v.x; h[1] = (__bf16)v.y; h[2] = (__bf16)v.z; h[3] = (__bf16)v.w;
    *(bf16x4*)&dst[p] = h;
  }
}

// ---------------- routed expert GEMM: A bf16 slots (swz32), B f32 [K][N], step split-K + M-split, dual-B ----------------
// XCD-grouped remap; Bsl row permutation (write conflicts 16->4-way). bf16 partial-plane output.
// k-split by 32-step boundaries (exact for any KS); M-split: block mh handles bm = mh, mh+MS, ...
template <int KS, int MS, bool DUAL>
__global__ __launch_bounds__(256) void k_gemmE2(const __bf16* __restrict__ Aall,
                                                const float* __restrict__ Bg,
                                                const float* __restrict__ Bg2,
                                                __bf16* __restrict__ Cp,
                                                __bf16* __restrict__ Cp2,
                                                const int* __restrict__ expOff,
                                                const int* __restrict__ expCnt,
                                                int N, int K, long long strideB, int bnHalf) {
  __shared__ __bf16 Asl[2][128 * 32];
  __shared__ __bf16 Bsl[2][128][40];
  const int tid = threadIdx.x;
  // ---- XCD-grouped remap (bijective; hw xcd = linear % 8). Requires total % 8 == 0. ----
  const int nbn = gridDim.x;
  const int T = gridDim.x * gridDim.y * gridDim.z;
  const int lin = blockIdx.x + gridDim.x * (blockIdx.y + gridDim.y * blockIdx.z);
  const int s_rm = (lin & 7) * (T >> 3) + (lin >> 3);
  const int chunk = T >> 3;
  const int xcd = s_rm / chunk;
  const int cpos = s_rm % chunk;
  const int gsub = cpos / nbn;
  int bn = cpos % nbn;
  const int grp = xcd + 8 * gsub;
  const int sub = grp % (KS * MS);
  const int ks = sub % KS;
  const int mh = sub / KS;
  const int e = grp / (KS * MS);

  const int cnt = expCnt[e], base = expOff[e];
  if (cnt == 0) return;
  const float* Bp = Bg;
  __bf16* Cdst = Cp;
  if constexpr (DUAL) {
    if (bn >= bnHalf) {
      bn -= bnHalf;
      Bp = Bg2;
      Cdst = Cp2;
    }
  }
  Bp += (long long)e * strideB;
  const int n0 = bn * 128;
  const int nSteps = K / 32;
  const int st0 = (ks * nSteps) / KS;
  const int st1 = ((ks + 1) * nSteps) / KS;
  const int kBeg = st0 * 32;
  const int nIter = st1 - st0;
  __bf16* __restrict__ Cpl = Cdst + (size_t)ks * NSLOTP * N;
  const int lane = tid & 63, wid = tid >> 6;
  const int wr = wid >> 1, wc = wid & 1;
  const int l16 = lane & 15, kl = lane >> 4;
  const int kb = tid >> 5, cb = tid & 31;
  const int arow = tid >> 2, achk = (tid & 3) * 8;
  const bool bok = (n0 + cb * 4) < N;

  // Bsl physical rows for this thread's 4 written columns: (4cb+e4) -> 4cb + (e4 ^ (cb&3))
  const int cbl = cb & 3;
  int wrow[4];
#pragma unroll
  for (int e4 = 0; e4 < 4; e4++) wrow[e4] = cb * 4 + (e4 ^ cbl);

  int boffs[4];
#pragma unroll
  for (int ni = 0; ni < 4; ni++) {
    int col = wc * 64 + ni * 16 + l16;
    int prow = (col & ~3) | ((col & 3) ^ ((col >> 2) & 3));
    boffs[ni] = prow * 40 + kl * 8;
  }

  for (int bm = mh; bm * 128 < cnt; bm += MS) {
    const int rbase = base + bm * 128;
    int aoff[4];
#pragma unroll
    for (int mi = 0; mi < 4; mi++) {
      int r = wr * 64 + mi * 16 + l16;
      int P = ((rbase + r) >> 1) & 3;
      aoff[mi] = r * 64 + ((kl ^ P) << 4);
    }
    f32x4 acc[4][4];
#pragma unroll
    for (int mi = 0; mi < 4; mi++)
#pragma unroll
      for (int ni = 0; ni < 4; ni++) acc[mi][ni] = f32x4{0.f, 0.f, 0.f, 0.f};

    const size_t aBase = (size_t)(rbase + arow) * K + achk + kBeg;
    const size_t aBase2 = aBase + (size_t)64 * K;

    gl16(Aall + aBase, &Asl[0][tid * 8]);
    gl16(Aall + aBase2, &Asl[0][(tid + 256) * 8]);
    {
      const float* src = Bp + (size_t)(kBeg + kb * 4) * N + n0 + cb * 4;
      f32x4 bv[4];
#pragma unroll
      for (int j = 0; j < 4; j++)
        bv[j] = bok ? *(const f32x4*)(src + (size_t)j * N) : f32x4{0.f, 0.f, 0.f, 0.f};
#pragma unroll
      for (int e4 = 0; e4 < 4; e4++) {
        bf16x4 h;
        h[0] = (__bf16)bv[0][e4]; h[1] = (__bf16)bv[1][e4];
        h[2] = (__bf16)bv[2][e4]; h[3] = (__bf16)bv[3][e4];
        *(bf16x4*)&Bsl[0][wrow[e4]][kb * 4] = h;
      }
    }
    __syncthreads();
    int cur = 0;
    for (int kt = 0; kt < nIter; ++kt) {
      const bool more = (kt + 1 < nIter);
      f32x4 nv[4];
      if (more) {
        const int kOff = (kt + 1) * 32;
        gl16(Aall + aBase + kOff, &Asl[cur ^ 1][tid * 8]);
        gl16(Aall + aBase2 + kOff, &Asl[cur ^ 1][(tid + 256) * 8]);
        const float* src = Bp + (size_t)(kBeg + kOff + kb * 4) * N + n0 + cb * 4;
#pragma unroll
        for (int j = 0; j < 4; j++)
          nv[j] = bok ? *(const f32x4*)(src + (size_t)j * N) : f32x4{0.f, 0.f, 0.f, 0.f};
      }
      bf16x8 ah[4], bh[4];
#pragma unroll
      for (int mi = 0; mi < 4; mi++) ah[mi] = *(const bf16x8*)((const char*)&Asl[cur][0] + aoff[mi]);
#pragma unroll
      for (int ni = 0; ni < 4; ni++) bh[ni] = *(const bf16x8*)&Bsl[cur][0][boffs[ni]];
#pragma unroll
      for (int mi = 0; mi < 4; mi++)
#pragma unroll
        for (int ni = 0; ni < 4; ni++)
          acc[mi][ni] = __builtin_amdgcn_mfma_f32_16x16x32_bf16(ah[mi], bh[ni], acc[mi][ni], 0, 0, 0);
      if (more) {
#pragma unroll
        for (int e4 = 0; e4 < 4; e4++) {
          bf16x4 h;
          h[0] = (__bf16)nv[0][e4]; h[1] = (__bf16)nv[1][e4];
          h[2] = (__bf16)nv[2][e4]; h[3] = (__bf16)nv[3][e4];
          *(bf16x4*)&Bsl[cur ^ 1][wrow[e4]][kb * 4] = h;
        }
      }
      __syncthreads();
      cur ^= 1;
    }
#pragma unroll
    for (int mi = 0; mi < 4; mi++)
#pragma unroll
      for (int ni = 0; ni < 4; ni++)
#pragma unroll
        for (int r = 0; r < 4; r++) {
          int rl = bm * 128 + wr * 64 + mi * 16 + kl * 4 + r;
          int col = n0 + wc * 64 + ni * 16 + l16;
          if (rl < cnt && col < N) Cpl[(size_t)(base + rl) * N + col] = (__bf16)acc[mi][ni][r];
        }
  }
}

// ---------------- routed: reduce gate/up bf16 partials (4 planes) + silu-mul + scale -> swz32 bf16 ----------------
__global__ __launch_bounds__(256) void k_silumulE(const __bf16* __restrict__ gP,
                                                  const __bf16* __restrict__ uP,
                                                  const float* __restrict__ slotw,
                                                  __bf16* __restrict__ outp) {
  int s = blockIdx.x, tid = threadIdx.x;
  float w = slotw[s];
  int P = (s >> 1) & 3;
  const size_t PL = (size_t)NSLOTP * M_INTER;
  for (int i = tid; i < M_INTER / 4; i += 256) {
    f32x4 g = f32x4{0.f, 0.f, 0.f, 0.f}, u = f32x4{0.f, 0.f, 0.f, 0.f};
#pragma unroll
    for (int z = 0; z < 4; z++) {
      bf16x4 gv = *(const bf16x4*)&gP[z * PL + (size_t)s * M_INTER + i * 4];
      bf16x4 uv = *(const bf16x4*)&uP[z * PL + (size_t)s * M_INTER + i * 4];
#pragma unroll
      for (int j = 0; j < 4; j++) {
        g[j] += (float)gv[j];
        u[j] += (float)uv[j];
      }
    }
    int p = swz_p(i * 4, P);
    bf16x4 h;
    h[0] = (__bf16)(siluf(g[0]) * u[0] * w);
    h[1] = (__bf16)(siluf(g[1]) * u[1] * w);
    h[2] = (__bf16)(siluf(g[2]) * u[2] * w);
    h[3] = (__bf16)(siluf(g[3]) * u[3] * w);
    *(bf16x4*)&outp[(size_t)s * M_INTER + p] = h;
  }
}

// ---------------- shared: reduce combined gate|up partials + silu-mul -> swz32 bf16 ----------------
__global__ __launch_bounds__(256) void k_silumul_sh2(const float* __restrict__ P4,
                                                     __bf16* __restrict__ outp) {
  int t = blockIdx.x, tid = threadIdx.x;
  int P = (t >> 1) & 3;
  const size_t PL = (size_t)SEQ * 3456;
  for (int i = tid; i < MS_INTER / 4; i += 256) {
    f32x4 g = f32x4{0.f, 0.f, 0.f, 0.f}, u = f32x4{0.f, 0.f, 0.f, 0.f};
#pragma unroll
    for (int z = 0; z < 4; z++) {
      g += *(const f32x4*)&P4[z * PL + (size_t)t * 3456 + i * 4];
      u += *(const f32x4*)&P4[z * PL + (size_t)t * 3456 + 1728 + i * 4];
    }
    int p = swz_p(i * 4, P);
    bf16x4 h;
    h[0] = (__bf16)(siluf(g[0]) * u[0]);
    h[1] = (__bf16)(siluf(g[1]) * u[1]);
    h[2] = (__bf16)(siluf(g[2]) * u[2]);
    h[3] = (__bf16)(siluf(g[3]) * u[3]);
    *(bf16x4*)&outp[(size_t)t * MS_INTER + p] = h;
  }
}

// ---------------- causal depthwise conv + SiLU ----------------
__global__ void k_conv(const float* __restrict__ zx, const float* __restrict__ cw,
                       const float* __restrict__ cb, float* __restrict__ xBC) {
  int cidx = blockIdx.x * 256 + threadIdx.x;
  int t = blockIdx.y;
  if (cidx < CONV_DIM) {
    float acc = cb[cidx];
#pragma unroll
    for (int j = 0; j < 4; j++) {
      int tt = t - 3 + j;
      if (tt >= 0) acc += zx[(size_t)tt * D_INPROJ + D_INNER + cidx] * cw[cidx * 4 + j];
    }
    xBC[(size_t)t * CONV_DIM + cidx] = siluf(acc);
  }
}

// ---------------- scan: intra-chunk (Q=64, swizzled LDS key (r>>2)&7, Cs/Gs union, fp16 X) ----------------
__global__ __launch_bounds__(256) void k_scan_intra(
    const float* __restrict__ xBC, const float* __restrict__ dtp,
    const float* __restrict__ dtA, float* __restrict__ y, float* __restrict__ S,
    float* __restrict__ cumA, float* __restrict__ Atot) {
  __shared__ float Bs[64 * 128];
  __shared__ float CG[64 * 128];
  __shared__ _Float16 Xs[64 * 64];
  __shared__ float da_s[64], a_s[64], dt_sh[64], w_sh[64];
  int c = blockIdx.x, h = blockIdx.y, tid = threadIdx.x;
  int t0 = c * QCHUNK;
#pragma unroll
  for (int i = 0; i < 8; i++) {
    int id = tid + 256 * i;
    int r = id >> 5, nc = id & 31;
    int sc = (nc ^ ((r >> 2) & 7)) * 4;
    *(float4*)&Bs[r * 128 + sc] = *(const float4*)&xBC[(size_t)(t0 + r) * CONV_DIM + D_INNER + nc * 4];
    *(float4*)&CG[r * 128 + sc] = *(const float4*)&xBC[(size_t)(t0 + r) * CONV_DIM + D_INNER + N_STATE + nc * 4];
  }
#pragma unroll
  for (int i = 0; i < 4; i++) {
    int id = tid + 256 * i;
    int r = id >> 4, p4 = (id & 15) * 4;
    float4 v = *(const float4*)&xBC[(size_t)(t0 + r) * CONV_DIM + h * P_HEAD + p4];
    f16x4 hv;
    hv[0] = (_Float16)v.x; hv[1] = (_Float16)v.y; hv[2] = (_Float16)v.z; hv[3] = (_Float16)v.w;
    *(f16x4*)&Xs[r * 64 + p4] = hv;
  }
  if (tid < 64) {
    da_s[tid] = dtA[(size_t)(t0 + tid) * HEADS + h];
    dt_sh[tid] = dtp[(size_t)(t0 + tid) * HEADS + h];
  }
  __syncthreads();
  if (tid < 64) {
    float a = 0.f;
    for (int i = 0; i <= tid; i++) a += da_s[i];
    a_s[tid] = a;
    cumA[((size_t)c * HEADS + h) * QCHUNK + tid] = a;
  }
  __syncthreads();
  if (tid < 64) {
    w_sh[tid] = __expf(a_s[63] - a_s[tid]) * dt_sh[tid];
    if (tid == 0) Atot[c * HEADS + h] = a_s[63];
  }
  __syncthreads();
  float gacc[4][4];
  {
    int tq = tid >> 4, sq = tid & 15;
#pragma unroll
    for (int j = 0; j < 4; j++)
#pragma unroll
      for (int jj = 0; jj < 4; jj++) gacc[j][jj] = 0.f;
    for (int nc = 0; nc < 32; nc++) {
      float4 cv[4], bv[4];
#pragma unroll
      for (int j = 0; j < 4; j++) {
        int rt = tq * 4 + j;
        cv[j] = *(const float4*)&CG[rt * 128 + ((nc ^ ((rt >> 2) & 7)) * 4)];
        int rs = sq * 4 + j;
        bv[j] = *(const float4*)&Bs[rs * 128 + ((nc ^ ((rs >> 2) & 7)) * 4)];
      }
#pragma unroll
      for (int j = 0; j < 4; j++)
#pragma unroll
        for (int jj = 0; jj < 4; jj++)
          gacc[j][jj] += cv[j].x * bv[jj].x + cv[j].y * bv[jj].y + cv[j].z * bv[jj].z + cv[j].w * bv[jj].w;
    }
  }
  __syncthreads();
  {
    int tq = tid >> 4, sq = tid & 15;
#pragma unroll
    for (int j = 0; j < 4; j++) {
      int t = tq * 4 + j;
      f32x4 gr;
#pragma unroll
      for (int jj = 0; jj < 4; jj++) {
        int s = sq * 4 + jj;
        float arg = fminf(a_s[t] - a_s[s], 0.f);
        gr[jj] = (s <= t) ? gacc[j][jj] * __expf(arg) * dt_sh[s] : 0.f;
      }
      *(f32x4*)&CG[t * 64 + ((sq ^ (t & 7)) * 4)] = gr;
    }
  }
  __syncthreads();
  {
    int tq = tid >> 4, pq = tid & 15;
    float4 acc[4];
#pragma unroll
    for (int j = 0; j < 4; j++) acc[j] = float4{0.f, 0.f, 0.f, 0.f};
    for (int s = 0; s < 64; s++) {
      f16x4 xh = *(const f16x4*)&Xs[s * 64 + pq * 4];
      float xv0 = (float)xh[0], xv1 = (float)xh[1], xv2 = (float)xh[2], xv3 = (float)xh[3];
#pragma unroll
      for (int j = 0; j < 4; j++) {
        int t = tq * 4 + j;
        float g = CG[t * 64 + (((s >> 2) ^ (t & 7)) * 4) + (s & 3)];
        acc[j].x += g * xv0; acc[j].y += g * xv1; acc[j].z += g * xv2; acc[j].w += g * xv3;
      }
    }
#pragma unroll
    for (int j = 0; j < 4; j++) {
      int t = tq * 4 + j;
      *(float4*)&y[(size_t)(t0 + t) * D_INNER + h * P_HEAD + pq * 4] = acc[j];
    }
  }
  {
    int p2 = tid >> 5, ncc = tid & 31;
    float4 acc[8];
#pragma unroll
    for (int j = 0; j < 8; j++) acc[j] = float4{0.f, 0.f, 0.f, 0.f};
    for (int s = 0; s < 64; s++) {
      float4 bvv = *(const float4*)&Bs[s * 128 + ((ncc ^ ((s >> 2) & 7)) * 4)];
      float ws = w_sh[s];
#pragma unroll
      for (int j = 0; j < 8; j++) {
        float xw = (float)Xs[s * 64 + p2 * 8 + j] * ws;
        acc[j].x += xw * bvv.x; acc[j].y += xw * bvv.y; acc[j].z += xw * bvv.z; acc[j].w += xw * bvv.w;
      }
    }
    size_t bb = ((size_t)(c * HEADS + h) * 64) * 128;
#pragma unroll
    for (int j = 0; j < 8; j++)
      *(float4*)&S[bb + (size_t)(p2 * 8 + j) * 128 + ncc * 4] = acc[j];
  }
}

// ---------------- scan: inter-chunk state recurrence ----------------
__global__ void k_scan_state(float* __restrict__ S, const float* __restrict__ Atot) {
  int gid = blockIdx.x * 256 + threadIdx.x;
  int h = gid >> 13;
  int rem = gid & 8191;
  float run = 0.f;
#pragma unroll
  for (int c = 0; c < NCHUNK; c++) {
    size_t idx = ((size_t)(c * HEADS + h) << 13) + rem;
    float s = S[idx];
    S[idx] = run;
    run = run * __expf(Atot[c * HEADS + h]) + s;
  }
}

// ---------------- scan: inter-chunk contribution + D*x (swizzled [64][128] Hs/Cs) ----------------
__global__ __launch_bounds__(256) void k_scan_inter(
    const float* __restrict__ xBC, const float* __restrict__ Hin,
    const float* __restrict__ cumA, const float* __restrict__ Dv,
    float* __restrict__ y) {
  __shared__ float Hs[64 * 128];
  __shared__ float Cs[64 * 128];
  __shared__ float a_l[64];
  int c = blockIdx.x, h = blockIdx.y, tid = threadIdx.x;
  int t0 = c * QCHUNK;
#pragma unroll
  for (int i = 0; i < 8; i++) {
    int id = tid + 256 * i;
    int r = id >> 5, nc = id & 31;
    int sc = (nc ^ ((r >> 2) & 7)) * 4;
    *(float4*)&Hs[r * 128 + sc] = *(const float4*)&Hin[(((size_t)(c * HEADS + h) * 64 + r) << 7) + nc * 4];
    *(float4*)&Cs[r * 128 + sc] = *(const float4*)&xBC[(size_t)(t0 + r) * CONV_DIM + D_INNER + N_STATE + nc * 4];
  }
  if (tid < 64) a_l[tid] = cumA[((size_t)c * HEADS + h) * QCHUNK + tid];
  __syncthreads();
  float Dh = Dv[h];
  int tq = tid >> 4, pq = tid & 15;
  float4 acc[4];
#pragma unroll
  for (int j = 0; j < 4; j++) acc[j] = float4{0.f, 0.f, 0.f, 0.f};
  for (int nc = 0; nc < 32; nc++) {
    float4 cv[4], hv[4];
#pragma unroll
    for (int j = 0; j < 4; j++) {
      int rt = tq * 4 + j;
      cv[j] = *(const float4*)&Cs[rt * 128 + ((nc ^ ((rt >> 2) & 7)) * 4)];
      int rp = pq * 4 + j;
      hv[j] = *(const float4*)&Hs[rp * 128 + ((nc ^ ((rp >> 2) & 7)) * 4)];
    }
#pragma unroll
    for (int j = 0; j < 4; j++) {
      acc[j].x += cv[j].x * hv[0].x + cv[j].y * hv[0].y + cv[j].z * hv[0].z + cv[j].w * hv[0].w;
      acc[j].y += cv[j].x * hv[1].x + cv[j].y * hv[1].y + cv[j].z * hv[1].z + cv[j].w * hv[1].w;
      acc[j].z += cv[j].x * hv[2].x + cv[j].y * hv[2].y + cv[j].z * hv[2].z + cv[j].w * hv[2].w;
      acc[j].w += cv[j].x * hv[3].x + cv[j].y * hv[3].y + cv[j].z * hv[3].z + cv[j].w * hv[3].w;
    }
  }
#pragma unroll
  for (int j = 0; j < 4; j++) {
    int t = tq * 4 + j;
    float e = __expf(a_l[t]);
    float4 xv = *(const float4*)&xBC[(size_t)(t0 + t) * CONV_DIM + h * P_HEAD + pq * 4];
    size_t yoff = (size_t)(t0 + t) * D_INNER + h * P_HEAD + pq * 4;
    float4 yv = *(float4*)&y[yoff];
    yv.x += e * acc[j].x + Dh * xv.x;
    yv.y += e * acc[j].y + Dh * xv.y;
    yv.z += e * acc[j].z + Dh * xv.z;
    yv.w += e * acc[j].w + Dh * xv.w;
    *(float4*)&y[yoff] = yv;
  }
}

// ---------------- gated RMSNorm -> swz32 fp16 plane ----------------
__global__ __launch_bounds__(256) void k_gatednorm_p(const float* __restrict__ y,
                                                     const float* __restrict__ zx,
                                                     const float* __restrict__ w,
                                                     __bf16* __restrict__ ph) {
  __shared__ float vbuf[D_INNER];
  __shared__ float red[4];
  int t = blockIdx.x, tid = threadIdx.x;
  float ss = 0.f;
  for (int i = tid; i < D_INNER / 4; i += 256) {
    float4 yv = *(const float4*)&y[(size_t)t * D_INNER + i * 4];
    float4 zv = *(const float4*)&zx[(size_t)t * D_INPROJ + i * 4];
    float4 v;
    v.x = yv.x * siluf(zv.x); v.y = yv.y * siluf(zv.y);
    v.z = yv.z * siluf(zv.z); v.w = yv.w * siluf(zv.w);
    *(float4*)&vbuf[i * 4] = v;
    ss += v.x * v.x + v.y * v.y + v.z * v.z + v.w * v.w;
  }
  float tot = block_sum256(ss, red);
  float r = rsqrtf(tot / (float)D_INNER + 1e-6f);
  int P = (t >> 1) & 3;
  for (int i = tid; i < D_INNER / 4; i += 256) {
    float4 v = *(const float4*)&vbuf[i * 4];
    float4 wv = *(const float4*)&w[i * 4];
    float4 o;
    o.x = wv.x * v.x * r; o.y = wv.y * v.y * r; o.z = wv.z * v.z * r; o.w = wv.w * v.w * r;
    int p = swz_p(i * 4, P);
    f16x4 hv;
    hv[0] = (_Float16)o.x; hv[1] = (_Float16)o.y; hv[2] = (_Float16)o.z; hv[3] = (_Float16)o.w;
    *(f16x4*)&ph[(size_t)t * D_INNER + p] = hv;
  }
}

// ---------------- router ----------------
__global__ void k_zero(int* counts, int* cursor) {
  int i = threadIdx.x;
  if (i < NEXP) { counts[i] = 0; cursor[i] = 0; }
}

__global__ __launch_bounds__(256) void k_router(const float* __restrict__ xm,
                                                const float* __restrict__ Wr,
                                                int* __restrict__ top_i,
                                                float* __restrict__ top_v,
                                                int* __restrict__ counts) {
  __shared__ float part[16][17];
  __shared__ float lg[16];
  int t = blockIdx.x, tid = threadIdx.x;
  int e = tid & 15, seg = tid >> 4;
  const float* xr = xm + (size_t)t * D_MODEL;
  float s = 0.f;
  for (int i = 0; i < 160; i++) {
    int k = seg * 160 + i;
    s += xr[k] * Wr[(size_t)k * NEXP + e];
  }
  part[seg][e] = s;
  __syncthreads();
  if (tid < 16) {
    float l = 0.f;
    for (int g = 0; g < 16; g++) l += part[g][tid];
    lg[tid] = l;
  }
  __syncthreads();
  if (tid == 0) {
    float mx = lg[0];
    for (int i = 1; i < 16; i++) mx = fmaxf(mx, lg[i]);
    float pe[16];
    for (int i = 0; i < 16; i++) pe[i] = expf(lg[i] - mx);
    int i0 = 0; float v0 = pe[0];
    for (int i = 1; i < 16; i++) if (pe[i] > v0) { v0 = pe[i]; i0 = i; }
    int i1 = -1; float v1 = -1.f;
    for (int i = 0; i < 16; i++) if (i != i0 && pe[i] > v1) { v1 = pe[i]; i1 = i; }
    float inv = 1.f / (v0 + v1);
    top_i[t * 2] = i0; top_i[t * 2 + 1] = i1;
    top_v[t * 2] = v0 * inv; top_v[t * 2 + 1] = v1 * inv;
    atomicAdd(&counts[i0], 1);
    atomicAdd(&counts[i1], 1);
  }
}

__global__ void k_offsets(const int* counts, int* offs, int* cursor) {
  if (threadIdx.x == 0) {
    int s = 0;
    for (int e = 0; e < NEXP; e++) { offs[e] = s; cursor[e] = s; s += counts[e]; }
  }
}

__global__ void k_scatter(const int* __restrict__ top_i, const float* __restrict__ top_v,
                          int* __restrict__ cursor, int* __restrict__ perm,
                          int* __restrict__ slotOf, float* __restrict__ slotw) {
  int t = blockIdx.x * 256 + threadIdx.x;
  if (t < SEQ) {
    for (int k = 0; k < 2; k++) {
      int e = top_i[t * 2 + k];
      int pos = atomicAdd(&cursor[e], 1);
      perm[pos] = t;
      slotOf[t * 2 + k] = pos;
      slotw[pos] = top_v[t * 2 + k];
    }
  }
}

// ---------------- final combine (3 bf16 down-partial planes) ----------------
__global__ void k_final2(const float* __restrict__ hidden, const float* __restrict__ sh,
                         const __bf16* __restrict__ dsP, const int* __restrict__ slotOf,
                         float* __restrict__ out) {
  int t = blockIdx.y;
  int d4 = (blockIdx.x * 256 + threadIdx.x) * 4;
  if (d4 < D_MODEL) {
    int s0 = slotOf[t * 2], s1 = slotOf[t * 2 + 1];
    f32x4 a = *(const f32x4*)&hidden[(size_t)t * D_MODEL + d4];
    f32x4 b = *(const f32x4*)&sh[(size_t)t * D_MODEL + d4];
    f32x4 acc = a + b;
    const size_t PL = (size_t)NSLOTP * D_MODEL;
#pragma unroll
    for (int z = 0; z < 3; z++) {
      bf16x4 p0 = *(const bf16x4*)&dsP[z * PL + (size_t)s0 * D_MODEL + d4];
      bf16x4 p1 = *(const bf16x4*)&dsP[z * PL + (size_t)s1 * D_MODEL + d4];
#pragma unroll
      for (int j = 0; j < 4; j++) acc[j] += (float)p0[j] + (float)p1[j];
    }
    *(f32x4*)&out[(size_t)t * D_MODEL + d4] = acc;
  }
}

// ---------------- launch ----------------
extern "C" void kernel_launch(void* const* d_in, const int* in_sizes, int n_in,
                              void* d_out, int out_size, void* d_ws, size_t ws_size,
                              hipStream_t stream) {
  const float* hs = (const float*)d_in[0];
  const float* w_in = (const float*)d_in[1];
  const float* conv_w = (const float*)d_in[2];
  const float* conv_b = (const float*)d_in[3];
  const float* dt_bias = (const float*)d_in[4];
  const float* A_log = (const float*)d_in[5];
  const float* Dv = (const float*)d_in[6];
  const float* mnw = (const float*)d_in[7];
  const float* w_out = (const float*)d_in[8];
  const float* ln1 = (const float*)d_in[9];
  const float* ln2 = (const float*)d_in[10];
  const float* router_w = (const float*)d_in[11];
  const float* we_gate = (const float*)d_in[12];
  const float* we_up = (const float*)d_in[13];
  const float* we_down = (const float*)d_in[14];
  const float* ws_gate = (const float*)d_in[15];
  const float* ws_up = (const float*)d_in[16];
  const float* ws_down = (const float*)d_in[17];

  char* base = (char*)d_ws;
  size_t off = 0;
  auto A = [&](size_t bytes) -> void* {
    void* p = base + off;
    off += (bytes + 255) & ~(size_t)255;
    return p;
  };
  float* xbc = (float*)A((size_t)SEQ * CONV_DIM * 4);
  float* xmf = (float*)A((size_t)SEQ * D_MODEL * 4);
  float* dtp = (float*)A((size_t)SEQ * HEADS * 4);
  float* dtA = (float*)A((size_t)SEQ * HEADS * 4);
  float* yf = (float*)A((size_t)SEQ * D_INNER * 4);
  float* cumA = (float*)A((size_t)NCHUNK * HEADS * QCHUNK * 4);
  float* Atot = (float*)A((size_t)NCHUNK * HEADS * 4);
  float* Sbuf = (float*)A((size_t)NCHUNK * HEADS * 64 * 128 * 4);
  float* hidden = (float*)A((size_t)SEQ * D_MODEL * 4);
  float* shout = (float*)A((size_t)SEQ * D_MODEL * 4);
  float* top_v = (float*)A(8192);
  float* slotw = (float*)A(8192);
  int* top_i = (int*)A(8192);
  int* counts = (int*)A(64);
  int* offs = (int*)A(64);
  int* cursor = (int*)A(64);
  int* perm = (int*)A(8192);
  int* slotOf = (int*)A(8192);
  __bf16* xp_h = (__bf16*)A((size_t)SEQ * D_MODEL * 2);
  __bf16* ybp_h = (__bf16*)A((size_t)SEQ * D_INNER * 2);
  __bf16* gbuf_bh = (__bf16*)A((size_t)SEQ * MS_INTER * 2);
  char* REG = (char*)A((size_t)163000000);

  // Phase M aliases
  __bf16* winT_h = (__bf16*)REG;                       // [10624][2560] f16 (54.4MB)
  float* zx = (float*)(REG + 60000000);                // [1024][10576] f32 (43.3MB)
  float* partials = (float*)(REG + 104000000);         // 4x1024x2560 f32 (41.9MB)
  __bf16* xdt_h = (__bf16*)(REG + 147000000);          // [1024][2560] bf16 hi (swz32)
  __bf16* xdt_l = (__bf16*)(REG + 152500000);
  __bf16* wdt_h = (__bf16*)(REG + 158000000);          // [128][2560] bf16 hi (swz32)
  __bf16* wdt_l = (__bf16*)(REG + 158700000);
  float* dtP = (float*)(REG + 159400000);              // 8x[1024][80] f32
  __bf16* woutT_h = (__bf16*)REG;                      // [2560][5120] f16 (after in_proj done)
  // Phase S aliases
  __bf16* guT = (__bf16*)REG;                          // [3456][2560] bf16 (gate | up)
  __bf16* downT = (__bf16*)(REG + 18350080);           // [2560][1728] bf16
  float* partials4 = (float*)(REG + 30000000);         // 4x[1024][3456] f32 (56.6 MB)
  // Phase R aliases
  __bf16* Aslots = (__bf16*)REG;                       // [2176][2560] bf16 (11.2MB)
  __bf16* gsl = (__bf16*)(REG + 12000000);             // [2176][864] bf16 (3.8MB)
  __bf16* gateP = (__bf16*)(REG + 16000000);           // 4x[2176][864] bf16 (15.1MB, dead after silumulE)
  __bf16* upP = (__bf16*)(REG + 77000000);             // 4x[2176][864] bf16 (15.1MB, dead after silumulE)
  __bf16* dslotsP = (__bf16*)(REG + 16000000);         // 3x[2176][2560] bf16 (33.4MB, aliases dead gateP)

  // ---- Mamba sub-block ----
  k_rmsnorm_p<true><<<SEQ, 256, 0, stream>>>(hs, ln1, nullptr, xp_h, xdt_h, xdt_l, D_MODEL);
  k_transW<false, true><<<dim3(166, 40), 256, 0, stream>>>(w_in, D_INPROJ, D_MODEL, D_INPROJ,
                                                           winT_h, nullptr);
  k_transW<true, false><<<dim3(2, 40), 256, 0, stream>>>(w_in + 10496, D_INPROJ, D_MODEL, 80,
                                                         wdt_h, wdt_l);
  k_gemm2<false, true, true><<<dim3(8, 83, 1), 256, 0, stream>>>(
      xp_h, nullptr, winT_h, nullptr, zx, SEQ, D_INPROJ, D_MODEL, 1, 80);
  k_gemm2<true, false, false><<<dim3(8, 1, 8), 256, 0, stream>>>(
      xdt_h, xdt_l, wdt_h, wdt_l, dtP, SEQ, 80, D_MODEL, 8, 80);
  k_dtfin<<<SEQ, 128, 0, stream>>>(dtP, dt_bias, A_log, dtp, dtA);
  k_conv<<<dim3(21, SEQ), 256, 0, stream>>>(zx, conv_w, conv_b, xbc);
  k_scan_intra<<<dim3(NCHUNK, HEADS), 256, 0, stream>>>(xbc, dtp, dtA, yf, Sbuf, cumA, Atot);
  k_scan_state<<<2560, 256, 0, stream>>>(Sbuf, Atot);
  k_scan_inter<<<dim3(NCHUNK, HEADS), 256, 0, stream>>>(xbc, Sbuf, cumA, Dv, yf);
  k_gatednorm_p<<<SEQ, 256, 0, stream>>>(yf, zx, mnw, ybp_h);
  k_transW<false, true><<<dim3(40, 80), 256, 0, stream>>>(w_out, D_MODEL, D_INNER, D_MODEL,
                                                          woutT_h, nullptr);
  k_gemm2<false, true, true><<<dim3(8, 20, 4), 256, 0, stream>>>(
      ybp_h, nullptr, woutT_h, nullptr, partials, SEQ, D_MODEL, D_INNER, 4, 160);
  // fused: partials+residual -> hidden; rmsnorm -> xmf + xp_h (bf16 swz32)
  k_redrms<<<SEQ, 256, 0, stream>>>(partials, hs, hidden, ln2, xmf, xp_h);

  // ---- MoE sub-block ----
  k_zero<<<1, 64, 0, stream>>>(counts, cursor);
  k_router<<<SEQ, 256, 0, stream>>>(xmf, router_w, top_i, top_v, counts);
  k_offsets<<<1, 32, 0, stream>>>(counts, offs, cursor);
  k_scatter<<<4, 256, 0, stream>>>(top_i, top_v, cursor, perm, slotOf, slotw);

  // shared experts: combined gate|up GEMM (N=3456), fused reduce+silu
  k_transW<false, false><<<dim3(27, 40), 256, 0, stream>>>(ws_gate, MS_INTER, D_MODEL, MS_INTER,
                                                           guT, nullptr);
  k_transW<false, false><<<dim3(27, 40), 256, 0, stream>>>(ws_up, MS_INTER, D_MODEL, MS_INTER,
                                                           guT + (size_t)MS_INTER * D_MODEL, nullptr);
  k_gemm2<false, false, true><<<dim3(8, 27, 4), 256, 0, stream>>>(
      xp_h, nullptr, guT, nullptr, partials4, SEQ, 3456, D_MODEL, 4, 80);
  k_silumul_sh2<<<SEQ, 256, 0, stream>>>(partials4, gbuf_bh);
  k_transW<false, false><<<dim3(40, 27), 256, 0, stream>>>(ws_down, D_MODEL, MS_INTER, D_MODEL,
                                                           downT, nullptr);
  k_gemm2<false, false, true><<<dim3(8, 20, 4), 256, 0, stream>>>(
      gbuf_bh, nullptr, downT, nullptr, partials4, SEQ, D_MODEL, MS_INTER, 4, 54);
  k_reduce<<<2048, 256, 0, stream>>>(partials4, 4, SEQ * D_MODEL / 4, shout);

  // routed experts: gate|up (KS=4, MS=2 -> 4 bf16 planes), down (KS=3, MS=2 -> 3 bf16 planes)
  k_gatherA<<<NSLOT, 256, 0, stream>>>(xmf, perm, Aslots);
  k_gemmE2<4, 2, true><<<dim3(14, 8, NEXP), 256, 0, stream>>>(
      Aslots, we_gate, we_up, gateP, upP, offs, counts,
      M_INTER, D_MODEL, (long long)D_MODEL * M_INTER, 7);
  k_silumulE<<<NSLOT, 256, 0, stream>>>(gateP, upP, slotw, gsl);
  k_gemmE2<3, 2, false><<<dim3(20, 6, NEXP), 256, 0, stream>>>(
      gsl, we_down, nullptr, dslotsP, nullptr, offs, counts,
      D_MODEL, M_INTER, (long long)M_INTER * D_MODEL, 0);

  k_final2<<<dim3(3, SEQ), 256, 0, stream>>>(hidden, shout, dslotsP, slotOf, (float*)d_out);
}

// Round 24
// 720.838 us; speedup vs baseline: 1.1180x; 1.0068x over previous
//
#include <hip/hip_runtime.h>

// ---------------- types ----------------
typedef __attribute__((ext_vector_type(4))) float f32x4;
typedef __attribute__((ext_vector_type(8))) __bf16 bf16x8;
typedef __attribute__((ext_vector_type(4))) __bf16 bf16x4;
typedef __attribute__((ext_vector_type(8))) _Float16 f16x8;
typedef __attribute__((ext_vector_type(4))) _Float16 f16x4;

#define D_MODEL 2560
#define D_INNER 5120
#define N_STATE 128
#define HEADS 80
#define P_HEAD 64
#define CONV_DIM 5376
#define D_INPROJ 10576
#define SEQ 1024
#define NCHUNK 16
#define QCHUNK 64
#define NEXP 16
#define M_INTER 864
#define MS_INTER 1728
#define NSLOT 2048
#define NSLOTP 2176   // padded slot rows

__device__ __forceinline__ float siluf(float x) { return x / (1.f + __expf(-x)); }

// 32-group swizzle (ALL 16-bit GEMM planes): 16B chunk c (of 4) stored at c ^ P, P = 2-bit key
__device__ __forceinline__ int swz_p(int k4, int P) {
  return (k4 & ~31) | ((((k4 >> 3) & 3) ^ P) << 3) | (k4 & 7);
}

__device__ __forceinline__ void gl16(const __bf16* g, __bf16* l) {
  __builtin_amdgcn_global_load_lds((const __attribute__((address_space(1))) unsigned int*)g,
                                   (__attribute__((address_space(3))) unsigned int*)l, 16, 0, 0);
}

__device__ __forceinline__ float block_sum256(float v, float* red) {
#pragma unroll
  for (int m = 32; m > 0; m >>= 1) v += __shfl_xor(v, m, 64);
  int w = threadIdx.x >> 6;
  if ((threadIdx.x & 63) == 0) red[w] = v;
  __syncthreads();
  return red[0] + red[1] + red[2] + red[3];
}

// ---------------- RMSNorm -> swz32 16-bit plane + optional swz32 bf16 hi/lo planes ----------------
template <bool FP16>
__global__ __launch_bounds__(256) void k_rmsnorm_p(const float* __restrict__ in,
                                                   const float* __restrict__ w,
                                                   float* __restrict__ f32out,
                                                   __bf16* __restrict__ ph,
                                                   __bf16* __restrict__ pdh,
                                                   __bf16* __restrict__ pdl, int D) {
  __shared__ float red[4];
  int t = blockIdx.x, tid = threadIdx.x;
  const float* x = in + (size_t)t * D;
  int nd4 = D >> 2;
  float ss = 0.f;
  for (int i = tid; i < nd4; i += 256) {
    float4 v = ((const float4*)x)[i];
    ss += v.x * v.x + v.y * v.y + v.z * v.z + v.w * v.w;
  }
  float tot = block_sum256(ss, red);
  float r = rsqrtf(tot / (float)D + 1e-6f);
  int P = (t >> 1) & 3;
  for (int i = tid; i < nd4; i += 256) {
    float4 v = ((const float4*)x)[i];
    float4 wv = ((const float4*)w)[i];
    float4 o;
    o.x = wv.x * v.x * r; o.y = wv.y * v.y * r; o.z = wv.z * v.z * r; o.w = wv.w * v.w * r;
    if (f32out) ((float4*)(f32out + (size_t)t * D))[i] = o;
    int p = swz_p(i * 4, P);
    if constexpr (FP16) {
      f16x4 hv;
      hv[0] = (_Float16)o.x; hv[1] = (_Float16)o.y; hv[2] = (_Float16)o.z; hv[3] = (_Float16)o.w;
      *(f16x4*)&ph[(size_t)t * D + p] = hv;
    } else {
      bf16x4 hv;
      hv[0] = (__bf16)o.x; hv[1] = (__bf16)o.y; hv[2] = (__bf16)o.z; hv[3] = (__bf16)o.w;
      *(bf16x4*)&ph[(size_t)t * D + p] = hv;
    }
    if (pdh) {
      int pp = swz_p(i * 4, P);
      bf16x4 hv, lv;
      hv[0] = (__bf16)o.x; hv[1] = (__bf16)o.y; hv[2] = (__bf16)o.z; hv[3] = (__bf16)o.w;
      lv[0] = (__bf16)(o.x - (float)hv[0]); lv[1] = (__bf16)(o.y - (float)hv[1]);
      lv[2] = (__bf16)(o.z - (float)hv[2]); lv[3] = (__bf16)(o.w - (float)hv[3]);
      *(bf16x4*)&pdh[(size_t)t * D + pp] = hv;
      *(bf16x4*)&pdl[(size_t)t * D + pp] = lv;
    }
  }
}

// ---------------- fused: sum 4 out_proj f32 partials + residual -> hidden; rmsnorm -> xmf + swz32 bf16 ----------------
__global__ __launch_bounds__(256) void k_redrms(const float* __restrict__ Pp,
                                                const float* __restrict__ res,
                                                float* __restrict__ hidden,
                                                const float* __restrict__ w,
                                                float* __restrict__ f32out,
                                                __bf16* __restrict__ ph) {
  __shared__ float vbuf[D_MODEL];
  __shared__ float red[4];
  int t = blockIdx.x, tid = threadIdx.x;
  const int n4 = D_MODEL / 4;
  float ss = 0.f;
  for (int i = tid; i < n4; i += 256) {
    f32x4 a = *(const f32x4*)&res[(size_t)t * D_MODEL + i * 4];
#pragma unroll
    for (int z = 0; z < 4; z++)
      a += *(const f32x4*)&Pp[(size_t)z * SEQ * D_MODEL + (size_t)t * D_MODEL + i * 4];
    *(f32x4*)&vbuf[i * 4] = a;
    *(f32x4*)&hidden[(size_t)t * D_MODEL + i * 4] = a;
    ss += a[0] * a[0] + a[1] * a[1] + a[2] * a[2] + a[3] * a[3];
  }
  float tot = block_sum256(ss, red);
  float r = rsqrtf(tot / (float)D_MODEL + 1e-6f);
  int P = (t >> 1) & 3;
  for (int i = tid; i < n4; i += 256) {
    f32x4 v = *(const f32x4*)&vbuf[i * 4];
    float4 wv = *(const float4*)&w[i * 4];
    f32x4 o;
    o[0] = wv.x * v[0] * r; o[1] = wv.y * v[1] * r; o[2] = wv.z * v[2] * r; o[3] = wv.w * v[3] * r;
    *(f32x4*)&f32out[(size_t)t * D_MODEL + i * 4] = o;
    int p = swz_p(i * 4, P);
    bf16x4 hv;
    hv[0] = (__bf16)o[0]; hv[1] = (__bf16)o[1]; hv[2] = (__bf16)o[2]; hv[3] = (__bf16)o[3];
    *(bf16x4*)&ph[(size_t)t * D_MODEL + p] = hv;
  }
}

// ---------------- weight transpose+convert: f32 [K][ld] (cols n0..n0+N) -> 16-bit [Npad][K] (swz32) ----------------
template <bool SPLIT, bool FP16>
__global__ __launch_bounds__(256) void k_transW(const float* __restrict__ W, int ld, int K, int N,
                                                __bf16* __restrict__ Th, __bf16* __restrict__ Tl) {
  __shared__ float T[64][65];
  const int n0 = blockIdx.x * 64, k0 = blockIdx.y * 64, tid = threadIdx.x;
#pragma unroll
  for (int i = 0; i < 16; i++) {
    int idx = tid + i * 256;
    int k = idx >> 6, n = idx & 63;
    float v = 0.f;
    if (n0 + n < N) v = W[(size_t)(k0 + k) * ld + n0 + n];
    T[k][n] = v;
  }
  __syncthreads();
#pragma unroll
  for (int i = 0; i < 4; i++) {
    int idx = tid + i * 256;
    int n = idx >> 4, p4 = (idx & 15) * 4;
    int nn = n0 + n;
    int P = (nn >> 1) & 3;
    if constexpr (SPLIT) {
      bf16x4 hv, lv;
#pragma unroll
      for (int e = 0; e < 4; e++) {
        int p = p4 + e;
        int kk = swz_p(p, P);
        float v = T[kk][n];
        __bf16 h = (__bf16)v;
        hv[e] = h;
        lv[e] = (__bf16)(v - (float)h);
      }
      *(bf16x4*)&Th[(size_t)nn * K + k0 + p4] = hv;
      *(bf16x4*)&Tl[(size_t)nn * K + k0 + p4] = lv;
    } else if constexpr (FP16) {
      f16x4 hv;
#pragma unroll
      for (int e = 0; e < 4; e++) {
        int p = p4 + e;
        int kk = swz_p(p, P);
        hv[e] = (_Float16)T[kk][n];
      }
      *(f16x4*)&Th[(size_t)nn * K + k0 + p4] = hv;
    } else {
      bf16x4 hv;
#pragma unroll
      for (int e = 0; e < 4; e++) {
        int p = p4 + e;
        int kk = swz_p(p, P);
        hv[e] = (__bf16)T[kk][n];
      }
      *(bf16x4*)&Th[(size_t)nn * K + k0 + p4] = hv;
    }
  }
}

// ---------------- 16-bit MFMA GEMM, BK=32, swz32 planes, XCD-grouped remap, optional dbuf pipeline ----------------
// logical grid: (bm=8, bn, z) — all launches have gridDim.x == 8, total % 8 == 0.
// OBF16: store C as bf16 (partial planes)
template <bool SPLIT, bool FP16, bool PIPE, bool OBF16>
__global__ __launch_bounds__(256) void k_gemm2(const __bf16* __restrict__ Ah,
                                               const __bf16* __restrict__ Al,
                                               const __bf16* __restrict__ Bh,
                                               const __bf16* __restrict__ Bl,
                                               void* __restrict__ C,
                                               int M, int N, int K, int ks, int nst) {
  constexpr int PLE = 4096;                   // 128 rows x 32 k
  constexpr int NPL = SPLIT ? 4 : 2;
  constexpr int NBUF = PIPE ? 2 : 1;
  __shared__ __bf16 lds[NBUF * NPL * PLE];

  const int tid = threadIdx.x;
  const int T = gridDim.x * gridDim.y * gridDim.z;
  const int linear = blockIdx.x + gridDim.x * (blockIdx.y + gridDim.y * blockIdx.z);
  const int s_idx = (linear & 7) * (T >> 3) + (linear >> 3);
  const int bm = s_idx & 7;
  const int g = s_idx >> 3;
  const int bn = g % gridDim.y;
  const int z = g / gridDim.y;

  const int m0 = bm * 128, n0 = bn * 128;
  const int s0 = (int)(((long long)z * nst) / ks);
  const int s1 = (int)(((long long)(z + 1) * nst) / ks);

  const int lane = tid & 63, wid = tid >> 6;
  const int wr = wid >> 1, wc = wid & 1;
  const int l16 = lane & 15, kl = lane >> 4;

  const int srow = tid >> 2;
  const int schunk = (tid & 3) * 8;
  const size_t aB0 = (size_t)(m0 + srow) * K + schunk;
  const size_t aB1 = aB0 + (size_t)64 * K;
  const size_t bB0 = (size_t)(n0 + srow) * K + schunk;
  const size_t bB1 = bB0 + (size_t)64 * K;

  int aoff[4], boff[4];
#pragma unroll
  for (int mi = 0; mi < 4; mi++) {
    int ra = wr * 64 + mi * 16 + l16;
    int rb = wc * 64 + mi * 16 + l16;
    aoff[mi] = ra * 64 + ((kl ^ ((ra >> 1) & 3)) << 4);
    boff[mi] = rb * 64 + ((kl ^ ((rb >> 1) & 3)) << 4);
  }

  f32x4 acc[4][4];
#pragma unroll
  for (int mi = 0; mi < 4; mi++)
#pragma unroll
    for (int ni = 0; ni < 4; ni++) acc[mi][ni] = f32x4{0.f, 0.f, 0.f, 0.f};

  auto STAGE = [&](int b, int kof) {
    __bf16* L = lds + (size_t)b * NPL * PLE;
    gl16(Ah + aB0 + kof, L + tid * 8);
    gl16(Ah + aB1 + kof, L + (tid + 256) * 8);
    gl16(Bh + bB0 + kof, L + (SPLIT ? 2 : 1) * PLE + tid * 8);
    gl16(Bh + bB1 + kof, L + (SPLIT ? 2 : 1) * PLE + (tid + 256) * 8);
    if constexpr (SPLIT) {
      gl16(Al + aB0 + kof, L + PLE + tid * 8);
      gl16(Al + aB1 + kof, L + PLE + (tid + 256) * 8);
      gl16(Bl + bB0 + kof, L + 3 * PLE + tid * 8);
      gl16(Bl + bB1 + kof, L + 3 * PLE + (tid + 256) * 8);
    }
  };

  auto COMPUTE = [&](const __bf16* L) {
    const char* AsH = (const char*)L;
    const char* BsH = (const char*)(L + (SPLIT ? 2 : 1) * PLE);
    if constexpr (!SPLIT && FP16) {
      f16x8 ah[4], bh[4];
#pragma unroll
      for (int mi = 0; mi < 4; mi++) ah[mi] = *(const f16x8*)(AsH + aoff[mi]);
#pragma unroll
      for (int ni = 0; ni < 4; ni++) bh[ni] = *(const f16x8*)(BsH + boff[ni]);
#pragma unroll
      for (int mi = 0; mi < 4; mi++)
#pragma unroll
        for (int ni = 0; ni < 4; ni++)
          acc[mi][ni] = __builtin_amdgcn_mfma_f32_16x16x32_f16(ah[mi], bh[ni], acc[mi][ni], 0, 0, 0);
    } else {
      bf16x8 ah[4], bh[4];
#pragma unroll
      for (int mi = 0; mi < 4; mi++) ah[mi] = *(const bf16x8*)(AsH + aoff[mi]);
#pragma unroll
      for (int ni = 0; ni < 4; ni++) bh[ni] = *(const bf16x8*)(BsH + boff[ni]);
#pragma unroll
      for (int mi = 0; mi < 4; mi++)
#pragma unroll
        for (int ni = 0; ni < 4; ni++)
          acc[mi][ni] = __builtin_amdgcn_mfma_f32_16x16x32_bf16(ah[mi], bh[ni], acc[mi][ni], 0, 0, 0);
      if constexpr (SPLIT) {
        const char* AsL = (const char*)(L + PLE);
        const char* BsL = (const char*)(L + 3 * PLE);
        bf16x8 al[4], bl[4];
#pragma unroll
        for (int mi = 0; mi < 4; mi++) al[mi] = *(const bf16x8*)(AsL + aoff[mi]);
#pragma unroll
        for (int ni = 0; ni < 4; ni++) bl[ni] = *(const bf16x8*)(BsL + boff[ni]);
#pragma unroll
        for (int mi = 0; mi < 4; mi++)
#pragma unroll
          for (int ni = 0; ni < 4; ni++) {
            acc[mi][ni] = __builtin_amdgcn_mfma_f32_16x16x32_bf16(ah[mi], bl[ni], acc[mi][ni], 0, 0, 0);
            acc[mi][ni] = __builtin_amdgcn_mfma_f32_16x16x32_bf16(al[mi], bh[ni], acc[mi][ni], 0, 0, 0);
          }
      }
    }
  };

  if constexpr (PIPE) {
    STAGE(0, s0 * 32);
    __syncthreads();
    int cur = 0;
    for (int s = s0; s < s1; ++s) {
      if (s + 1 < s1) STAGE(cur ^ 1, (s + 1) * 32);
      COMPUTE(lds + (size_t)cur * NPL * PLE);
      __syncthreads();
      cur ^= 1;
    }
  } else {
    for (int s = s0; s < s1; ++s) {
      __syncthreads();
      STAGE(0, s * 32);
      __syncthreads();
      COMPUTE(lds);
    }
  }

  if constexpr (OBF16) {
    __bf16* __restrict__ Cp = (__bf16*)C + (size_t)z * M * N;
#pragma unroll
    for (int mi = 0; mi < 4; mi++)
#pragma unroll
      for (int ni = 0; ni < 4; ni++)
#pragma unroll
        for (int r = 0; r < 4; r++) {
          int row = m0 + wr * 64 + mi * 16 + kl * 4 + r;
          int col = n0 + wc * 64 + ni * 16 + l16;
          if (col < N) Cp[(size_t)row * N + col] = (__bf16)acc[mi][ni][r];
        }
  } else {
    float* __restrict__ Cp = (float*)C + (size_t)z * M * N;
#pragma unroll
    for (int mi = 0; mi < 4; mi++)
#pragma unroll
      for (int ni = 0; ni < 4; ni++)
#pragma unroll
        for (int r = 0; r < 4; r++) {
          int row = m0 + wr * 64 + mi * 16 + kl * 4 + r;
          int col = n0 + wc * 64 + ni * 16 + l16;
          if (col < N) Cp[(size_t)row * N + col] = acc[mi][ni][r];
        }
  }
}

// ---------------- partial reduce (bf16 planes, no residual) ----------------
__global__ void k_reduce(const __bf16* __restrict__ Pp, int np, int n4, float* __restrict__ out) {
  int i = blockIdx.x * 256 + threadIdx.x;
  int stride = gridDim.x * 256;
  for (; i < n4; i += stride) {
    f32x4 a = f32x4{0.f, 0.f, 0.f, 0.f};
    for (int z = 0; z < np; z++) {
      bf16x4 b = ((const bf16x4*)Pp)[(size_t)z * n4 + i];
#pragma unroll
      for (int j = 0; j < 4; j++) a[j] += (float)b[j];
    }
    *(f32x4*)&out[(size_t)i * 4] = a;
  }
}

// ---------------- dt finalize: sum 8 split-K partials + bias -> softplus ----------------
__global__ void k_dtfin(const float* __restrict__ dtP, const float* __restrict__ dt_bias,
                        const float* __restrict__ A_log, float* __restrict__ dtp,
                        float* __restrict__ dtA) {
  int t = blockIdx.x, h = threadIdx.x;
  if (h < HEADS) {
    float v = dt_bias[h];
#pragma unroll
    for (int z = 0; z < 8; z++) v += dtP[((size_t)z * SEQ + t) * 80 + h];
    float sp = fmaxf(v, 0.f) + log1pf(expf(-fabsf(v)));
    dtp[t * HEADS + h] = sp;
    dtA[t * HEADS + h] = sp * (-expf(A_log[h]));
  }
}

// ---------------- gather slot activations -> swz32 bf16 ----------------
__global__ __launch_bounds__(256) void k_gatherA(const float* __restrict__ xm,
                                                 const int* __restrict__ perm,
                                                 __bf16* __restrict__ Aslots) {
  int s = blockIdx.x, tid = threadIdx.x;
  int t = perm[s];
  int P = (s >> 1) & 3;
  const float* src = xm + (size_t)t * D_MODEL;
  __bf16* dst = Aslots + (size_t)s * D_MODEL;
  for (int i = tid; i < D_MODEL / 4; i += 256) {
    float4 v = ((const float4*)src)[i];
    int p = swz_p(i * 4, P);
    bf16x4 h;
    h[0] = (__bf16)v.x; h[1] = (__bf16)v.y; h[2] = (__bf16)v.z; h[3] = (__bf16)v.w;
    *(bf16x4*)&dst[p] = h;
  }
}

// ---------------- routed expert GEMM: A bf16 slots (swz32), B f32 [K][N], step split-K + M-split, dual-B ----------------
// XCD-grouped remap; Bsl row permutation (write conflicts 16->4-way). bf16 partial-plane output.
template <int KS, int MS, bool DUAL>
__global__ __launch_bounds__(256) void k_gemmE2(const __bf16* __restrict__ Aall,
                                                const float* __restrict__ Bg,
                                                const float* __restrict__ Bg2,
                                                __bf16* __restrict__ Cp,
                                                __bf16* __restrict__ Cp2,
                                                const int* __restrict__ expOff,
                                                const int* __restrict__ expCnt,
                                                int N, int K, long long strideB, int bnHalf) {
  __shared__ __bf16 Asl[2][128 * 32];
  __shared__ __bf16 Bsl[2][128][40];
  const int tid = threadIdx.x;
  // ---- XCD-grouped remap (bijective; hw xcd = linear % 8). Requires total % 8 == 0. ----
  const int nbn = gridDim.x;
  const int T = gridDim.x * gridDim.y * gridDim.z;
  const int lin = blockIdx.x + gridDim.x * (blockIdx.y + gridDim.y * blockIdx.z);
  const int s_rm = (lin & 7) * (T >> 3) + (lin >> 3);
  const int chunk = T >> 3;
  const int xcd = s_rm / chunk;
  const int cpos = s_rm % chunk;
  const int gsub = cpos / nbn;
  int bn = cpos % nbn;
  const int grp = xcd + 8 * gsub;
  const int sub = grp % (KS * MS);
  const int ks = sub % KS;
  const int mh = sub / KS;
  const int e = grp / (KS * MS);

  const int cnt = expCnt[e], base = expOff[e];
  if (cnt == 0) return;
  const float* Bp = Bg;
  __bf16* Cdst = Cp;
  if constexpr (DUAL) {
    if (bn >= bnHalf) {
      bn -= bnHalf;
      Bp = Bg2;
      Cdst = Cp2;
    }
  }
  Bp += (long long)e * strideB;
  const int n0 = bn * 128;
  const int nSteps = K / 32;
  const int st0 = (ks * nSteps) / KS;
  const int st1 = ((ks + 1) * nSteps) / KS;
  const int kBeg = st0 * 32;
  const int nIter = st1 - st0;
  __bf16* __restrict__ Cpl = Cdst + (size_t)ks * NSLOTP * N;
  const int lane = tid & 63, wid = tid >> 6;
  const int wr = wid >> 1, wc = wid & 1;
  const int l16 = lane & 15, kl = lane >> 4;
  const int kb = tid >> 5, cb = tid & 31;
  const int arow = tid >> 2, achk = (tid & 3) * 8;
  const bool bok = (n0 + cb * 4) < N;

  // Bsl physical rows for this thread's 4 written columns: (4cb+e4) -> 4cb + (e4 ^ (cb&3))
  const int cbl = cb & 3;
  int wrow[4];
#pragma unroll
  for (int e4 = 0; e4 < 4; e4++) wrow[e4] = cb * 4 + (e4 ^ cbl);

  int boffs[4];
#pragma unroll
  for (int ni = 0; ni < 4; ni++) {
    int col = wc * 64 + ni * 16 + l16;
    int prow = (col & ~3) | ((col & 3) ^ ((col >> 2) & 3));
    boffs[ni] = prow * 40 + kl * 8;
  }

  for (int bm = mh; bm * 128 < cnt; bm += MS) {
    const int rbase = base + bm * 128;
    int aoff[4];
#pragma unroll
    for (int mi = 0; mi < 4; mi++) {
      int r = wr * 64 + mi * 16 + l16;
      int P = ((rbase + r) >> 1) & 3;
      aoff[mi] = r * 64 + ((kl ^ P) << 4);
    }
    f32x4 acc[4][4];
#pragma unroll
    for (int mi = 0; mi < 4; mi++)
#pragma unroll
      for (int ni = 0; ni < 4; ni++) acc[mi][ni] = f32x4{0.f, 0.f, 0.f, 0.f};

    const size_t aBase = (size_t)(rbase + arow) * K + achk + kBeg;
    const size_t aBase2 = aBase + (size_t)64 * K;

    gl16(Aall + aBase, &Asl[0][tid * 8]);
    gl16(Aall + aBase2, &Asl[0][(tid + 256) * 8]);
    {
      const float* src = Bp + (size_t)(kBeg + kb * 4) * N + n0 + cb * 4;
      f32x4 bv[4];
#pragma unroll
      for (int j = 0; j < 4; j++)
        bv[j] = bok ? *(const f32x4*)(src + (size_t)j * N) : f32x4{0.f, 0.f, 0.f, 0.f};
#pragma unroll
      for (int e4 = 0; e4 < 4; e4++) {
        bf16x4 h;
        h[0] = (__bf16)bv[0][e4]; h[1] = (__bf16)bv[1][e4];
        h[2] = (__bf16)bv[2][e4]; h[3] = (__bf16)bv[3][e4];
        *(bf16x4*)&Bsl[0][wrow[e4]][kb * 4] = h;
      }
    }
    __syncthreads();
    int cur = 0;
    for (int kt = 0; kt < nIter; ++kt) {
      const bool more = (kt + 1 < nIter);
      f32x4 nv[4];
      if (more) {
        const int kOff = (kt + 1) * 32;
        gl16(Aall + aBase + kOff, &Asl[cur ^ 1][tid * 8]);
        gl16(Aall + aBase2 + kOff, &Asl[cur ^ 1][(tid + 256) * 8]);
        const float* src = Bp + (size_t)(kBeg + kOff + kb * 4) * N + n0 + cb * 4;
#pragma unroll
        for (int j = 0; j < 4; j++)
          nv[j] = bok ? *(const f32x4*)(src + (size_t)j * N) : f32x4{0.f, 0.f, 0.f, 0.f};
      }
      bf16x8 ah[4], bh[4];
#pragma unroll
      for (int mi = 0; mi < 4; mi++) ah[mi] = *(const bf16x8*)((const char*)&Asl[cur][0] + aoff[mi]);
#pragma unroll
      for (int ni = 0; ni < 4; ni++) bh[ni] = *(const bf16x8*)&Bsl[cur][0][boffs[ni]];
#pragma unroll
      for (int mi = 0; mi < 4; mi++)
#pragma unroll
        for (int ni = 0; ni < 4; ni++)
          acc[mi][ni] = __builtin_amdgcn_mfma_f32_16x16x32_bf16(ah[mi], bh[ni], acc[mi][ni], 0, 0, 0);
      if (more) {
#pragma unroll
        for (int e4 = 0; e4 < 4; e4++) {
          bf16x4 h;
          h[0] = (__bf16)nv[0][e4]; h[1] = (__bf16)nv[1][e4];
          h[2] = (__bf16)nv[2][e4]; h[3] = (__bf16)nv[3][e4];
          *(bf16x4*)&Bsl[cur ^ 1][wrow[e4]][kb * 4] = h;
        }
      }
      __syncthreads();
      cur ^= 1;
    }
#pragma unroll
    for (int mi = 0; mi < 4; mi++)
#pragma unroll
      for (int ni = 0; ni < 4; ni++)
#pragma unroll
        for (int r = 0; r < 4; r++) {
          int rl = bm * 128 + wr * 64 + mi * 16 + kl * 4 + r;
          int col = n0 + wc * 64 + ni * 16 + l16;
          if (rl < cnt && col < N) Cpl[(size_t)(base + rl) * N + col] = (__bf16)acc[mi][ni][r];
        }
  }
}

// ---------------- routed: reduce gate/up bf16 partials (4 planes) + silu-mul + scale -> swz32 bf16 ----------------
__global__ __launch_bounds__(256) void k_silumulE(const __bf16* __restrict__ gP,
                                                  const __bf16* __restrict__ uP,
                                                  const float* __restrict__ slotw,
                                                  __bf16* __restrict__ outp) {
  int s = blockIdx.x, tid = threadIdx.x;
  float w = slotw[s];
  int P = (s >> 1) & 3;
  const size_t PL = (size_t)NSLOTP * M_INTER;
  for (int i = tid; i < M_INTER / 4; i += 256) {
    f32x4 g = f32x4{0.f, 0.f, 0.f, 0.f}, u = f32x4{0.f, 0.f, 0.f, 0.f};
#pragma unroll
    for (int z = 0; z < 4; z++) {
      bf16x4 gv = *(const bf16x4*)&gP[z * PL + (size_t)s * M_INTER + i * 4];
      bf16x4 uv = *(const bf16x4*)&uP[z * PL + (size_t)s * M_INTER + i * 4];
#pragma unroll
      for (int j = 0; j < 4; j++) {
        g[j] += (float)gv[j];
        u[j] += (float)uv[j];
      }
    }
    int p = swz_p(i * 4, P);
    bf16x4 h;
    h[0] = (__bf16)(siluf(g[0]) * u[0] * w);
    h[1] = (__bf16)(siluf(g[1]) * u[1] * w);
    h[2] = (__bf16)(siluf(g[2]) * u[2] * w);
    h[3] = (__bf16)(siluf(g[3]) * u[3] * w);
    *(bf16x4*)&outp[(size_t)s * M_INTER + p] = h;
  }
}

// ---------------- shared: reduce combined gate|up bf16 partials + silu-mul -> swz32 bf16 ----------------
__global__ __launch_bounds__(256) void k_silumul_sh2(const __bf16* __restrict__ P4,
                                                     __bf16* __restrict__ outp) {
  int t = blockIdx.x, tid = threadIdx.x;
  int P = (t >> 1) & 3;
  const size_t PL = (size_t)SEQ * 3456;
  for (int i = tid; i < MS_INTER / 4; i += 256) {
    f32x4 g = f32x4{0.f, 0.f, 0.f, 0.f}, u = f32x4{0.f, 0.f, 0.f, 0.f};
#pragma unroll
    for (int z = 0; z < 4; z++) {
      bf16x4 gv = *(const bf16x4*)&P4[z * PL + (size_t)t * 3456 + i * 4];
      bf16x4 uv = *(const bf16x4*)&P4[z * PL + (size_t)t * 3456 + 1728 + i * 4];
#pragma unroll
      for (int j = 0; j < 4; j++) {
        g[j] += (float)gv[j];
        u[j] += (float)uv[j];
      }
    }
    int p = swz_p(i * 4, P);
    bf16x4 h;
    h[0] = (__bf16)(siluf(g[0]) * u[0]);
    h[1] = (__bf16)(siluf(g[1]) * u[1]);
    h[2] = (__bf16)(siluf(g[2]) * u[2]);
    h[3] = (__bf16)(siluf(g[3]) * u[3]);
    *(bf16x4*)&outp[(size_t)t * MS_INTER + p] = h;
  }
}

// ---------------- causal depthwise conv + SiLU ----------------
__global__ void k_conv(const float* __restrict__ zx, const float* __restrict__ cw,
                       const float* __restrict__ cb, float* __restrict__ xBC) {
  int cidx = blockIdx.x * 256 + threadIdx.x;
  int t = blockIdx.y;
  if (cidx < CONV_DIM) {
    float acc = cb[cidx];
#pragma unroll
    for (int j = 0; j < 4; j++) {
      int tt = t - 3 + j;
      if (tt >= 0) acc += zx[(size_t)tt * D_INPROJ + D_INNER + cidx] * cw[cidx * 4 + j];
    }
    xBC[(size_t)t * CONV_DIM + cidx] = siluf(acc);
  }
}

// ---------------- scan: intra-chunk (Q=64, swizzled LDS key (r>>2)&7, Cs/Gs union, fp16 X) ----------------
__global__ __launch_bounds__(256) void k_scan_intra(
    const float* __restrict__ xBC, const float* __restrict__ dtp,
    const float* __restrict__ dtA, float* __restrict__ y, float* __restrict__ S,
    float* __restrict__ cumA, float* __restrict__ Atot) {
  __shared__ float Bs[64 * 128];
  __shared__ float CG[64 * 128];
  __shared__ _Float16 Xs[64 * 64];
  __shared__ float da_s[64], a_s[64], dt_sh[64], w_sh[64];
  int c = blockIdx.x, h = blockIdx.y, tid = threadIdx.x;
  int t0 = c * QCHUNK;
#pragma unroll
  for (int i = 0; i < 8; i++) {
    int id = tid + 256 * i;
    int r = id >> 5, nc = id & 31;
    int sc = (nc ^ ((r >> 2) & 7)) * 4;
    *(float4*)&Bs[r * 128 + sc] = *(const float4*)&xBC[(size_t)(t0 + r) * CONV_DIM + D_INNER + nc * 4];
    *(float4*)&CG[r * 128 + sc] = *(const float4*)&xBC[(size_t)(t0 + r) * CONV_DIM + D_INNER + N_STATE + nc * 4];
  }
#pragma unroll
  for (int i = 0; i < 4; i++) {
    int id = tid + 256 * i;
    int r = id >> 4, p4 = (id & 15) * 4;
    float4 v = *(const float4*)&xBC[(size_t)(t0 + r) * CONV_DIM + h * P_HEAD + p4];
    f16x4 hv;
    hv[0] = (_Float16)v.x; hv[1] = (_Float16)v.y; hv[2] = (_Float16)v.z; hv[3] = (_Float16)v.w;
    *(f16x4*)&Xs[r * 64 + p4] = hv;
  }
  if (tid < 64) {
    da_s[tid] = dtA[(size_t)(t0 + tid) * HEADS + h];
    dt_sh[tid] = dtp[(size_t)(t0 + tid) * HEADS + h];
  }
  __syncthreads();
  if (tid < 64) {
    float a = 0.f;
    for (int i = 0; i <= tid; i++) a += da_s[i];
    a_s[tid] = a;
    cumA[((size_t)c * HEADS + h) * QCHUNK + tid] = a;
  }
  __syncthreads();
  if (tid < 64) {
    w_sh[tid] = __expf(a_s[63] - a_s[tid]) * dt_sh[tid];
    if (tid == 0) Atot[c * HEADS + h] = a_s[63];
  }
  __syncthreads();
  float gacc[4][4];
  {
    int tq = tid >> 4, sq = tid & 15;
#pragma unroll
    for (int j = 0; j < 4; j++)
#pragma unroll
      for (int jj = 0; jj < 4; jj++) gacc[j][jj] = 0.f;
    for (int nc = 0; nc < 32; nc++) {
      float4 cv[4], bv[4];
#pragma unroll
      for (int j = 0; j < 4; j++) {
        int rt = tq * 4 + j;
        cv[j] = *(const float4*)&CG[rt * 128 + ((nc ^ ((rt >> 2) & 7)) * 4)];
        int rs = sq * 4 + j;
        bv[j] = *(const float4*)&Bs[rs * 128 + ((nc ^ ((rs >> 2) & 7)) * 4)];
      }
#pragma unroll
      for (int j = 0; j < 4; j++)
#pragma unroll
        for (int jj = 0; jj < 4; jj++)
          gacc[j][jj] += cv[j].x * bv[jj].x + cv[j].y * bv[jj].y + cv[j].z * bv[jj].z + cv[j].w * bv[jj].w;
    }
  }
  __syncthreads();
  {
    int tq = tid >> 4, sq = tid & 15;
#pragma unroll
    for (int j = 0; j < 4; j++) {
      int t = tq * 4 + j;
      f32x4 gr;
#pragma unroll
      for (int jj = 0; jj < 4; jj++) {
        int s = sq * 4 + jj;
        float arg = fminf(a_s[t] - a_s[s], 0.f);
        gr[jj] = (s <= t) ? gacc[j][jj] * __expf(arg) * dt_sh[s] : 0.f;
      }
      *(f32x4*)&CG[t * 64 + ((sq ^ (t & 7)) * 4)] = gr;
    }
  }
  __syncthreads();
  {
    int tq = tid >> 4, pq = tid & 15;
    float4 acc[4];
#pragma unroll
    for (int j = 0; j < 4; j++) acc[j] = float4{0.f, 0.f, 0.f, 0.f};
    for (int s = 0; s < 64; s++) {
      f16x4 xh = *(const f16x4*)&Xs[s * 64 + pq * 4];
      float xv0 = (float)xh[0], xv1 = (float)xh[1], xv2 = (float)xh[2], xv3 = (float)xh[3];
#pragma unroll
      for (int j = 0; j < 4; j++) {
        int t = tq * 4 + j;
        float g = CG[t * 64 + (((s >> 2) ^ (t & 7)) * 4) + (s & 3)];
        acc[j].x += g * xv0; acc[j].y += g * xv1; acc[j].z += g * xv2; acc[j].w += g * xv3;
      }
    }
#pragma unroll
    for (int j = 0; j < 4; j++) {
      int t = tq * 4 + j;
      *(float4*)&y[(size_t)(t0 + t) * D_INNER + h * P_HEAD + pq * 4] = acc[j];
    }
  }
  {
    int p2 = tid >> 5, ncc = tid & 31;
    float4 acc[8];
#pragma unroll
    for (int j = 0; j < 8; j++) acc[j] = float4{0.f, 0.f, 0.f, 0.f};
    for (int s = 0; s < 64; s++) {
      float4 bvv = *(const float4*)&Bs[s * 128 + ((ncc ^ ((s >> 2) & 7)) * 4)];
      float ws = w_sh[s];
#pragma unroll
      for (int j = 0; j < 8; j++) {
        float xw = (float)Xs[s * 64 + p2 * 8 + j] * ws;
        acc[j].x += xw * bvv.x; acc[j].y += xw * bvv.y; acc[j].z += xw * bvv.z; acc[j].w += xw * bvv.w;
      }
    }
    size_t bb = ((size_t)(c * HEADS + h) * 64) * 128;
#pragma unroll
    for (int j = 0; j < 8; j++)
      *(float4*)&S[bb + (size_t)(p2 * 8 + j) * 128 + ncc * 4] = acc[j];
  }
}

// ---------------- scan: inter-chunk state recurrence ----------------
__global__ void k_scan_state(float* __restrict__ S, const float* __restrict__ Atot) {
  int gid = blockIdx.x * 256 + threadIdx.x;
  int h = gid >> 13;
  int rem = gid & 8191;
  float run = 0.f;
#pragma unroll
  for (int c = 0; c < NCHUNK; c++) {
    size_t idx = ((size_t)(c * HEADS + h) << 13) + rem;
    float s = S[idx];
    S[idx] = run;
    run = run * __expf(Atot[c * HEADS + h]) + s;
  }
}

// ---------------- scan: inter-chunk contribution + D*x (swizzled [64][128] Hs/Cs) ----------------
__global__ __launch_bounds__(256) void k_scan_inter(
    const float* __restrict__ xBC, const float* __restrict__ Hin,
    const float* __restrict__ cumA, const float* __restrict__ Dv,
    float* __restrict__ y) {
  __shared__ float Hs[64 * 128];
  __shared__ float Cs[64 * 128];
  __shared__ float a_l[64];
  int c = blockIdx.x, h = blockIdx.y, tid = threadIdx.x;
  int t0 = c * QCHUNK;
#pragma unroll
  for (int i = 0; i < 8; i++) {
    int id = tid + 256 * i;
    int r = id >> 5, nc = id & 31;
    int sc = (nc ^ ((r >> 2) & 7)) * 4;
    *(float4*)&Hs[r * 128 + sc] = *(const float4*)&Hin[(((size_t)(c * HEADS + h) * 64 + r) << 7) + nc * 4];
    *(float4*)&Cs[r * 128 + sc] = *(const float4*)&xBC[(size_t)(t0 + r) * CONV_DIM + D_INNER + N_STATE + nc * 4];
  }
  if (tid < 64) a_l[tid] = cumA[((size_t)c * HEADS + h) * QCHUNK + tid];
  __syncthreads();
  float Dh = Dv[h];
  int tq = tid >> 4, pq = tid & 15;
  float4 acc[4];
#pragma unroll
  for (int j = 0; j < 4; j++) acc[j] = float4{0.f, 0.f, 0.f, 0.f};
  for (int nc = 0; nc < 32; nc++) {
    float4 cv[4], hv[4];
#pragma unroll
    for (int j = 0; j < 4; j++) {
      int rt = tq * 4 + j;
      cv[j] = *(const float4*)&Cs[rt * 128 + ((nc ^ ((rt >> 2) & 7)) * 4)];
      int rp = pq * 4 + j;
      hv[j] = *(const float4*)&Hs[rp * 128 + ((nc ^ ((rp >> 2) & 7)) * 4)];
    }
#pragma unroll
    for (int j = 0; j < 4; j++) {
      acc[j].x += cv[j].x * hv[0].x + cv[j].y * hv[0].y + cv[j].z * hv[0].z + cv[j].w * hv[0].w;
      acc[j].y += cv[j].x * hv[1].x + cv[j].y * hv[1].y + cv[j].z * hv[1].z + cv[j].w * hv[1].w;
      acc[j].z += cv[j].x * hv[2].x + cv[j].y * hv[2].y + cv[j].z * hv[2].z + cv[j].w * hv[2].w;
      acc[j].w += cv[j].x * hv[3].x + cv[j].y * hv[3].y + cv[j].z * hv[3].z + cv[j].w * hv[3].w;
    }
  }
#pragma unroll
  for (int j = 0; j < 4; j++) {
    int t = tq * 4 + j;
    float e = __expf(a_l[t]);
    float4 xv = *(const float4*)&xBC[(size_t)(t0 + t) * CONV_DIM + h * P_HEAD + pq * 4];
    size_t yoff = (size_t)(t0 + t) * D_INNER + h * P_HEAD + pq * 4;
    float4 yv = *(float4*)&y[yoff];
    yv.x += e * acc[j].x + Dh * xv.x;
    yv.y += e * acc[j].y + Dh * xv.y;
    yv.z += e * acc[j].z + Dh * xv.z;
    yv.w += e * acc[j].w + Dh * xv.w;
    *(float4*)&y[yoff] = yv;
  }
}

// ---------------- gated RMSNorm -> swz32 fp16 plane ----------------
__global__ __launch_bounds__(256) void k_gatednorm_p(const float* __restrict__ y,
                                                     const float* __restrict__ zx,
                                                     const float* __restrict__ w,
                                                     __bf16* __restrict__ ph) {
  __shared__ float vbuf[D_INNER];
  __shared__ float red[4];
  int t = blockIdx.x, tid = threadIdx.x;
  float ss = 0.f;
  for (int i = tid; i < D_INNER / 4; i += 256) {
    float4 yv = *(const float4*)&y[(size_t)t * D_INNER + i * 4];
    float4 zv = *(const float4*)&zx[(size_t)t * D_INPROJ + i * 4];
    float4 v;
    v.x = yv.x * siluf(zv.x); v.y = yv.y * siluf(zv.y);
    v.z = yv.z * siluf(zv.z); v.w = yv.w * siluf(zv.w);
    *(float4*)&vbuf[i * 4] = v;
    ss += v.x * v.x + v.y * v.y + v.z * v.z + v.w * v.w;
  }
  float tot = block_sum256(ss, red);
  float r = rsqrtf(tot / (float)D_INNER + 1e-6f);
  int P = (t >> 1) & 3;
  for (int i = tid; i < D_INNER / 4; i += 256) {
    float4 v = *(const float4*)&vbuf[i * 4];
    float4 wv = *(const float4*)&w[i * 4];
    float4 o;
    o.x = wv.x * v.x * r; o.y = wv.y * v.y * r; o.z = wv.z * v.z * r; o.w = wv.w * v.w * r;
    int p = swz_p(i * 4, P);
    f16x4 hv;
    hv[0] = (_Float16)o.x; hv[1] = (_Float16)o.y; hv[2] = (_Float16)o.z; hv[3] = (_Float16)o.w;
    *(f16x4*)&ph[(size_t)t * D_INNER + p] = hv;
  }
}

// ---------------- router ----------------
__global__ void k_zero(int* counts, int* cursor) {
  int i = threadIdx.x;
  if (i < NEXP) { counts[i] = 0; cursor[i] = 0; }
}

__global__ __launch_bounds__(256) void k_router(const float* __restrict__ xm,
                                                const float* __restrict__ Wr,
                                                int* __restrict__ top_i,
                                                float* __restrict__ top_v,
                                                int* __restrict__ counts) {
  __shared__ float part[16][17];
  __shared__ float lg[16];
  int t = blockIdx.x, tid = threadIdx.x;
  int e = tid & 15, seg = tid >> 4;
  const float* xr = xm + (size_t)t * D_MODEL;
  float s = 0.f;
  for (int i = 0; i < 160; i++) {
    int k = seg * 160 + i;
    s += xr[k] * Wr[(size_t)k * NEXP + e];
  }
  part[seg][e] = s;
  __syncthreads();
  if (tid < 16) {
    float l = 0.f;
    for (int g = 0; g < 16; g++) l += part[g][tid];
    lg[tid] = l;
  }
  __syncthreads();
  if (tid == 0) {
    float mx = lg[0];
    for (int i = 1; i < 16; i++) mx = fmaxf(mx, lg[i]);
    float pe[16];
    for (int i = 0; i < 16; i++) pe[i] = expf(lg[i] - mx);
    int i0 = 0; float v0 = pe[0];
    for (int i = 1; i < 16; i++) if (pe[i] > v0) { v0 = pe[i]; i0 = i; }
    int i1 = -1; float v1 = -1.f;
    for (int i = 0; i < 16; i++) if (i != i0 && pe[i] > v1) { v1 = pe[i]; i1 = i; }
    float inv = 1.f / (v0 + v1);
    top_i[t * 2] = i0; top_i[t * 2 + 1] = i1;
    top_v[t * 2] = v0 * inv; top_v[t * 2 + 1] = v1 * inv;
    atomicAdd(&counts[i0], 1);
    atomicAdd(&counts[i1], 1);
  }
}

__global__ void k_offsets(const int* counts, int* offs, int* cursor) {
  if (threadIdx.x == 0) {
    int s = 0;
    for (int e = 0; e < NEXP; e++) { offs[e] = s; cursor[e] = s; s += counts[e]; }
  }
}

__global__ void k_scatter(const int* __restrict__ top_i, const float* __restrict__ top_v,
                          int* __restrict__ cursor, int* __restrict__ perm,
                          int* __restrict__ slotOf, float* __restrict__ slotw) {
  int t = blockIdx.x * 256 + threadIdx.x;
  if (t < SEQ) {
    for (int k = 0; k < 2; k++) {
      int e = top_i[t * 2 + k];
      int pos = atomicAdd(&cursor[e], 1);
      perm[pos] = t;
      slotOf[t * 2 + k] = pos;
      slotw[pos] = top_v[t * 2 + k];
    }
  }
}

// ---------------- final combine (3 bf16 down-partial planes) ----------------
__global__ void k_final2(const float* __restrict__ hidden, const float* __restrict__ sh,
                         const __bf16* __restrict__ dsP, const int* __restrict__ slotOf,
                         float* __restrict__ out) {
  int t = blockIdx.y;
  int d4 = (blockIdx.x * 256 + threadIdx.x) * 4;
  if (d4 < D_MODEL) {
    int s0 = slotOf[t * 2], s1 = slotOf[t * 2 + 1];
    f32x4 a = *(const f32x4*)&hidden[(size_t)t * D_MODEL + d4];
    f32x4 b = *(const f32x4*)&sh[(size_t)t * D_MODEL + d4];
    f32x4 acc = a + b;
    const size_t PL = (size_t)NSLOTP * D_MODEL;
#pragma unroll
    for (int z = 0; z < 3; z++) {
      bf16x4 p0 = *(const bf16x4*)&dsP[z * PL + (size_t)s0 * D_MODEL + d4];
      bf16x4 p1 = *(const bf16x4*)&dsP[z * PL + (size_t)s1 * D_MODEL + d4];
#pragma unroll
      for (int j = 0; j < 4; j++) acc[j] += (float)p0[j] + (float)p1[j];
    }
    *(f32x4*)&out[(size_t)t * D_MODEL + d4] = acc;
  }
}

// ---------------- launch ----------------
extern "C" void kernel_launch(void* const* d_in, const int* in_sizes, int n_in,
                              void* d_out, int out_size, void* d_ws, size_t ws_size,
                              hipStream_t stream) {
  const float* hs = (const float*)d_in[0];
  const float* w_in = (const float*)d_in[1];
  const float* conv_w = (const float*)d_in[2];
  const float* conv_b = (const float*)d_in[3];
  const float* dt_bias = (const float*)d_in[4];
  const float* A_log = (const float*)d_in[5];
  const float* Dv = (const float*)d_in[6];
  const float* mnw = (const float*)d_in[7];
  const float* w_out = (const float*)d_in[8];
  const float* ln1 = (const float*)d_in[9];
  const float* ln2 = (const float*)d_in[10];
  const float* router_w = (const float*)d_in[11];
  const float* we_gate = (const float*)d_in[12];
  const float* we_up = (const float*)d_in[13];
  const float* we_down = (const float*)d_in[14];
  const float* ws_gate = (const float*)d_in[15];
  const float* ws_up = (const float*)d_in[16];
  const float* ws_down = (const float*)d_in[17];

  char* base = (char*)d_ws;
  size_t off = 0;
  auto A = [&](size_t bytes) -> void* {
    void* p = base + off;
    off += (bytes + 255) & ~(size_t)255;
    return p;
  };
  float* xbc = (float*)A((size_t)SEQ * CONV_DIM * 4);
  float* xmf = (float*)A((size_t)SEQ * D_MODEL * 4);
  float* dtp = (float*)A((size_t)SEQ * HEADS * 4);
  float* dtA = (float*)A((size_t)SEQ * HEADS * 4);
  float* yf = (float*)A((size_t)SEQ * D_INNER * 4);
  float* cumA = (float*)A((size_t)NCHUNK * HEADS * QCHUNK * 4);
  float* Atot = (float*)A((size_t)NCHUNK * HEADS * 4);
  float* Sbuf = (float*)A((size_t)NCHUNK * HEADS * 64 * 128 * 4);
  float* hidden = (float*)A((size_t)SEQ * D_MODEL * 4);
  float* shout = (float*)A((size_t)SEQ * D_MODEL * 4);
  float* top_v = (float*)A(8192);
  float* slotw = (float*)A(8192);
  int* top_i = (int*)A(8192);
  int* counts = (int*)A(64);
  int* offs = (int*)A(64);
  int* cursor = (int*)A(64);
  int* perm = (int*)A(8192);
  int* slotOf = (int*)A(8192);
  __bf16* xp_h = (__bf16*)A((size_t)SEQ * D_MODEL * 2);
  __bf16* ybp_h = (__bf16*)A((size_t)SEQ * D_INNER * 2);
  __bf16* gbuf_bh = (__bf16*)A((size_t)SEQ * MS_INTER * 2);
  char* REG = (char*)A((size_t)163000000);

  // Phase M aliases
  __bf16* winT_h = (__bf16*)REG;                       // [10624][2560] f16 (54.4MB)
  float* zx = (float*)(REG + 60000000);                // [1024][10576] f32 (43.3MB)
  float* partials = (float*)(REG + 104000000);         // 4x1024x2560 f32 (41.9MB) — f32: feeds router
  __bf16* xdt_h = (__bf16*)(REG + 147000000);          // [1024][2560] bf16 hi (swz32)
  __bf16* xdt_l = (__bf16*)(REG + 152500000);
  __bf16* wdt_h = (__bf16*)(REG + 158000000);          // [128][2560] bf16 hi (swz32)
  __bf16* wdt_l = (__bf16*)(REG + 158700000);
  float* dtP = (float*)(REG + 159400000);              // 8x[1024][80] f32
  __bf16* woutT_h = (__bf16*)REG;                      // [2560][5120] f16 (after in_proj done)
  // Phase S aliases
  __bf16* guT = (__bf16*)REG;                          // [3456][2560] bf16 (gate | up)
  __bf16* downT = (__bf16*)(REG + 18350080);           // [2560][1728] bf16
  __bf16* partials4 = (__bf16*)(REG + 30000000);       // 4x[1024][3456] bf16 (28.3 MB)
  // Phase R aliases
  __bf16* Aslots = (__bf16*)REG;                       // [2176][2560] bf16 (11.2MB)
  __bf16* gsl = (__bf16*)(REG + 12000000);             // [2176][864] bf16 (3.8MB)
  __bf16* gateP = (__bf16*)(REG + 16000000);           // 4x[2176][864] bf16 (15.1MB, dead after silumulE)
  __bf16* upP = (__bf16*)(REG + 77000000);             // 4x[2176][864] bf16 (15.1MB, dead after silumulE)
  __bf16* dslotsP = (__bf16*)(REG + 16000000);         // 3x[2176][2560] bf16 (33.4MB, aliases dead gateP)

  // ---- Mamba sub-block ----
  k_rmsnorm_p<true><<<SEQ, 256, 0, stream>>>(hs, ln1, nullptr, xp_h, xdt_h, xdt_l, D_MODEL);
  k_transW<false, true><<<dim3(166, 40), 256, 0, stream>>>(w_in, D_INPROJ, D_MODEL, D_INPROJ,
                                                           winT_h, nullptr);
  k_transW<true, false><<<dim3(2, 40), 256, 0, stream>>>(w_in + 10496, D_INPROJ, D_MODEL, 80,
                                                         wdt_h, wdt_l);
  k_gemm2<false, true, true, false><<<dim3(8, 83, 1), 256, 0, stream>>>(
      xp_h, nullptr, winT_h, nullptr, zx, SEQ, D_INPROJ, D_MODEL, 1, 80);
  k_gemm2<true, false, false, false><<<dim3(8, 1, 8), 256, 0, stream>>>(
      xdt_h, xdt_l, wdt_h, wdt_l, dtP, SEQ, 80, D_MODEL, 8, 80);
  k_dtfin<<<SEQ, 128, 0, stream>>>(dtP, dt_bias, A_log, dtp, dtA);
  k_conv<<<dim3(21, SEQ), 256, 0, stream>>>(zx, conv_w, conv_b, xbc);
  k_scan_intra<<<dim3(NCHUNK, HEADS), 256, 0, stream>>>(xbc, dtp, dtA, yf, Sbuf, cumA, Atot);
  k_scan_state<<<2560, 256, 0, stream>>>(Sbuf, Atot);
  k_scan_inter<<<dim3(NCHUNK, HEADS), 256, 0, stream>>>(xbc, Sbuf, cumA, Dv, yf);
  k_gatednorm_p<<<SEQ, 256, 0, stream>>>(yf, zx, mnw, ybp_h);
  k_transW<false, true><<<dim3(40, 80), 256, 0, stream>>>(w_out, D_MODEL, D_INNER, D_MODEL,
                                                          woutT_h, nullptr);
  k_gemm2<false, true, true, false><<<dim3(8, 20, 4), 256, 0, stream>>>(
      ybp_h, nullptr, woutT_h, nullptr, partials, SEQ, D_MODEL, D_INNER, 4, 160);
  // fused: f32 partials+residual -> hidden; rmsnorm -> xmf + xp_h (bf16 swz32)
  k_redrms<<<SEQ, 256, 0, stream>>>(partials, hs, hidden, ln2, xmf, xp_h);

  // ---- MoE sub-block ----
  k_zero<<<1, 64, 0, stream>>>(counts, cursor);
  k_router<<<SEQ, 256, 0, stream>>>(xmf, router_w, top_i, top_v, counts);
  k_offsets<<<1, 32, 0, stream>>>(counts, offs, cursor);
  k_scatter<<<4, 256, 0, stream>>>(top_i, top_v, cursor, perm, slotOf, slotw);

  // shared experts: combined gate|up GEMM (N=3456), fused reduce+silu (bf16 partials)
  k_transW<false, false><<<dim3(27, 40), 256, 0, stream>>>(ws_gate, MS_INTER, D_MODEL, MS_INTER,
                                                           guT, nullptr);
  k_transW<false, false><<<dim3(27, 40), 256, 0, stream>>>(ws_up, MS_INTER, D_MODEL, MS_INTER,
                                                           guT + (size_t)MS_INTER * D_MODEL, nullptr);
  k_gemm2<false, false, true, true><<<dim3(8, 27, 4), 256, 0, stream>>>(
      xp_h, nullptr, guT, nullptr, partials4, SEQ, 3456, D_MODEL, 4, 80);
  k_silumul_sh2<<<SEQ, 256, 0, stream>>>(partials4, gbuf_bh);
  k_transW<false, false><<<dim3(40, 27), 256, 0, stream>>>(ws_down, D_MODEL, MS_INTER, D_MODEL,
                                                           downT, nullptr);
  k_gemm2<false, false, true, true><<<dim3(8, 20, 4), 256, 0, stream>>>(
      gbuf_bh, nullptr, downT, nullptr, partials4, SEQ, D_MODEL, MS_INTER, 4, 54);
  k_reduce<<<2048, 256, 0, stream>>>(partials4, 4, SEQ * D_MODEL / 4, shout);

  // routed experts: gate|up (KS=4, MS=2 -> 4 bf16 planes), down (KS=3, MS=2 -> 3 bf16 planes)
  k_gatherA<<<NSLOT, 256, 0, stream>>>(xmf, perm, Aslots);
  k_gemmE2<4, 2, true><<<dim3(14, 8, NEXP), 256, 0, stream>>>(
      Aslots, we_gate, we_up, gateP, upP, offs, counts,
      M_INTER, D_MODEL, (long long)D_MODEL * M_INTER, 7);
  k_silumulE<<<NSLOT, 256, 0, stream>>>(gateP, upP, slotw, gsl);
  k_gemmE2<3, 2, false><<<dim3(20, 6, NEXP), 256, 0, stream>>>(
      gsl, we_down, nullptr, dslotsP, nullptr, offs, counts,
      D_MODEL, M_INTER, (long long)M_INTER * D_MODEL, 0);

  k_final2<<<dim3(3, SEQ), 256, 0, stream>>>(hidden, shout, dslotsP, slotOf, (float*)d_out);
}

// Round 25
// 709.729 us; speedup vs baseline: 1.1355x; 1.0157x over previous
//
#include <hip/hip_runtime.h>

// ---------------- types ----------------
typedef __attribute__((ext_vector_type(4))) float f32x4;
typedef __attribute__((ext_vector_type(8))) __bf16 bf16x8;
typedef __attribute__((ext_vector_type(4))) __bf16 bf16x4;
typedef __attribute__((ext_vector_type(8))) _Float16 f16x8;
typedef __attribute__((ext_vector_type(4))) _Float16 f16x4;

#define D_MODEL 2560
#define D_INNER 5120
#define N_STATE 128
#define HEADS 80
#define P_HEAD 64
#define CONV_DIM 5376
#define D_INPROJ 10576
#define SEQ 1024
#define NCHUNK 16
#define QCHUNK 64
#define NEXP 16
#define M_INTER 864
#define MS_INTER 1728
#define NSLOT 2048
#define NSLOTP 2176   // padded slot rows

__device__ __forceinline__ float siluf(float x) { return x / (1.f + __expf(-x)); }

// 32-group swizzle (ALL 16-bit GEMM planes): 16B chunk c (of 4) stored at c ^ P, P = 2-bit key
__device__ __forceinline__ int swz_p(int k4, int P) {
  return (k4 & ~31) | ((((k4 >> 3) & 3) ^ P) << 3) | (k4 & 7);
}

__device__ __forceinline__ void gl16(const __bf16* g, __bf16* l) {
  __builtin_amdgcn_global_load_lds((const __attribute__((address_space(1))) unsigned int*)g,
                                   (__attribute__((address_space(3))) unsigned int*)l, 16, 0, 0);
}

__device__ __forceinline__ float block_sum256(float v, float* red) {
#pragma unroll
  for (int m = 32; m > 0; m >>= 1) v += __shfl_xor(v, m, 64);
  int w = threadIdx.x >> 6;
  if ((threadIdx.x & 63) == 0) red[w] = v;
  __syncthreads();
  return red[0] + red[1] + red[2] + red[3];
}

// ---------------- RMSNorm -> swz32 16-bit plane + optional swz32 bf16 hi/lo planes ----------------
template <bool FP16>
__global__ __launch_bounds__(256) void k_rmsnorm_p(const float* __restrict__ in,
                                                   const float* __restrict__ w,
                                                   float* __restrict__ f32out,
                                                   __bf16* __restrict__ ph,
                                                   __bf16* __restrict__ pdh,
                                                   __bf16* __restrict__ pdl, int D) {
  __shared__ float red[4];
  int t = blockIdx.x, tid = threadIdx.x;
  const float* x = in + (size_t)t * D;
  int nd4 = D >> 2;
  float ss = 0.f;
  for (int i = tid; i < nd4; i += 256) {
    float4 v = ((const float4*)x)[i];
    ss += v.x * v.x + v.y * v.y + v.z * v.z + v.w * v.w;
  }
  float tot = block_sum256(ss, red);
  float r = rsqrtf(tot / (float)D + 1e-6f);
  int P = (t >> 1) & 3;
  for (int i = tid; i < nd4; i += 256) {
    float4 v = ((const float4*)x)[i];
    float4 wv = ((const float4*)w)[i];
    float4 o;
    o.x = wv.x * v.x * r; o.y = wv.y * v.y * r; o.z = wv.z * v.z * r; o.w = wv.w * v.w * r;
    if (f32out) ((float4*)(f32out + (size_t)t * D))[i] = o;
    int p = swz_p(i * 4, P);
    if constexpr (FP16) {
      f16x4 hv;
      hv[0] = (_Float16)o.x; hv[1] = (_Float16)o.y; hv[2] = (_Float16)o.z; hv[3] = (_Float16)o.w;
      *(f16x4*)&ph[(size_t)t * D + p] = hv;
    } else {
      bf16x4 hv;
      hv[0] = (__bf16)o.x; hv[1] = (__bf16)o.y; hv[2] = (__bf16)o.z; hv[3] = (__bf16)o.w;
      *(bf16x4*)&ph[(size_t)t * D + p] = hv;
    }
    if (pdh) {
      int pp = swz_p(i * 4, P);
      bf16x4 hv, lv;
      hv[0] = (__bf16)o.x; hv[1] = (__bf16)o.y; hv[2] = (__bf16)o.z; hv[3] = (__bf16)o.w;
      lv[0] = (__bf16)(o.x - (float)hv[0]); lv[1] = (__bf16)(o.y - (float)hv[1]);
      lv[2] = (__bf16)(o.z - (float)hv[2]); lv[3] = (__bf16)(o.w - (float)hv[3]);
      *(bf16x4*)&pdh[(size_t)t * D + pp] = hv;
      *(bf16x4*)&pdl[(size_t)t * D + pp] = lv;
    }
  }
}

// ---------------- fused: sum 4 out_proj f32 partials + residual -> hidden; rmsnorm -> xmf + swz32 bf16 ----------------
__global__ __launch_bounds__(256) void k_redrms(const float* __restrict__ Pp,
                                                const float* __restrict__ res,
                                                float* __restrict__ hidden,
                                                const float* __restrict__ w,
                                                float* __restrict__ f32out,
                                                __bf16* __restrict__ ph) {
  __shared__ float vbuf[D_MODEL];
  __shared__ float red[4];
  int t = blockIdx.x, tid = threadIdx.x;
  const int n4 = D_MODEL / 4;
  float ss = 0.f;
  for (int i = tid; i < n4; i += 256) {
    f32x4 a = *(const f32x4*)&res[(size_t)t * D_MODEL + i * 4];
#pragma unroll
    for (int z = 0; z < 4; z++)
      a += *(const f32x4*)&Pp[(size_t)z * SEQ * D_MODEL + (size_t)t * D_MODEL + i * 4];
    *(f32x4*)&vbuf[i * 4] = a;
    *(f32x4*)&hidden[(size_t)t * D_MODEL + i * 4] = a;
    ss += a[0] * a[0] + a[1] * a[1] + a[2] * a[2] + a[3] * a[3];
  }
  float tot = block_sum256(ss, red);
  float r = rsqrtf(tot / (float)D_MODEL + 1e-6f);
  int P = (t >> 1) & 3;
  for (int i = tid; i < n4; i += 256) {
    f32x4 v = *(const f32x4*)&vbuf[i * 4];
    float4 wv = *(const float4*)&w[i * 4];
    f32x4 o;
    o[0] = wv.x * v[0] * r; o[1] = wv.y * v[1] * r; o[2] = wv.z * v[2] * r; o[3] = wv.w * v[3] * r;
    *(f32x4*)&f32out[(size_t)t * D_MODEL + i * 4] = o;
    int p = swz_p(i * 4, P);
    bf16x4 hv;
    hv[0] = (__bf16)o[0]; hv[1] = (__bf16)o[1]; hv[2] = (__bf16)o[2]; hv[3] = (__bf16)o[3];
    *(bf16x4*)&ph[(size_t)t * D_MODEL + p] = hv;
  }
}

// ---------------- weight transpose+convert: f32 [K][ld] (cols n0..n0+N) -> 16-bit [Npad][K] (swz32) ----------------
template <bool SPLIT, bool FP16>
__global__ __launch_bounds__(256) void k_transW(const float* __restrict__ W, int ld, int K, int N,
                                                __bf16* __restrict__ Th, __bf16* __restrict__ Tl) {
  __shared__ float T[64][65];
  const int n0 = blockIdx.x * 64, k0 = blockIdx.y * 64, tid = threadIdx.x;
#pragma unroll
  for (int i = 0; i < 16; i++) {
    int idx = tid + i * 256;
    int k = idx >> 6, n = idx & 63;
    float v = 0.f;
    if (n0 + n < N) v = W[(size_t)(k0 + k) * ld + n0 + n];
    T[k][n] = v;
  }
  __syncthreads();
#pragma unroll
  for (int i = 0; i < 4; i++) {
    int idx = tid + i * 256;
    int n = idx >> 4, p4 = (idx & 15) * 4;
    int nn = n0 + n;
    int P = (nn >> 1) & 3;
    if constexpr (SPLIT) {
      bf16x4 hv, lv;
#pragma unroll
      for (int e = 0; e < 4; e++) {
        int p = p4 + e;
        int kk = swz_p(p, P);
        float v = T[kk][n];
        __bf16 h = (__bf16)v;
        hv[e] = h;
        lv[e] = (__bf16)(v - (float)h);
      }
      *(bf16x4*)&Th[(size_t)nn * K + k0 + p4] = hv;
      *(bf16x4*)&Tl[(size_t)nn * K + k0 + p4] = lv;
    } else if constexpr (FP16) {
      f16x4 hv;
#pragma unroll
      for (int e = 0; e < 4; e++) {
        int p = p4 + e;
        int kk = swz_p(p, P);
        hv[e] = (_Float16)T[kk][n];
      }
      *(f16x4*)&Th[(size_t)nn * K + k0 + p4] = hv;
    } else {
      bf16x4 hv;
#pragma unroll
      for (int e = 0; e < 4; e++) {
        int p = p4 + e;
        int kk = swz_p(p, P);
        hv[e] = (__bf16)T[kk][n];
      }
      *(bf16x4*)&Th[(size_t)nn * K + k0 + p4] = hv;
    }
  }
}

// ---------------- 16-bit MFMA GEMM, BK=32, swz32 planes, XCD-grouped remap, optional dbuf pipeline ----------------
// logical grid: (bm=8, bn, z) — all launches have gridDim.x == 8, total % 8 == 0.
// OBF16: store C as bf16 (partial planes)
template <bool SPLIT, bool FP16, bool PIPE, bool OBF16>
__global__ __launch_bounds__(256) void k_gemm2(const __bf16* __restrict__ Ah,
                                               const __bf16* __restrict__ Al,
                                               const __bf16* __restrict__ Bh,
                                               const __bf16* __restrict__ Bl,
                                               void* __restrict__ C,
                                               int M, int N, int K, int ks, int nst) {
  constexpr int PLE = 4096;                   // 128 rows x 32 k
  constexpr int NPL = SPLIT ? 4 : 2;
  constexpr int NBUF = PIPE ? 2 : 1;
  __shared__ __bf16 lds[NBUF * NPL * PLE];

  const int tid = threadIdx.x;
  const int T = gridDim.x * gridDim.y * gridDim.z;
  const int linear = blockIdx.x + gridDim.x * (blockIdx.y + gridDim.y * blockIdx.z);
  const int s_idx = (linear & 7) * (T >> 3) + (linear >> 3);
  const int bm = s_idx & 7;
  const int g = s_idx >> 3;
  const int bn = g % gridDim.y;
  const int z = g / gridDim.y;

  const int m0 = bm * 128, n0 = bn * 128;
  const int s0 = (int)(((long long)z * nst) / ks);
  const int s1 = (int)(((long long)(z + 1) * nst) / ks);

  const int lane = tid & 63, wid = tid >> 6;
  const int wr = wid >> 1, wc = wid & 1;
  const int l16 = lane & 15, kl = lane >> 4;

  const int srow = tid >> 2;
  const int schunk = (tid & 3) * 8;
  const size_t aB0 = (size_t)(m0 + srow) * K + schunk;
  const size_t aB1 = aB0 + (size_t)64 * K;
  const size_t bB0 = (size_t)(n0 + srow) * K + schunk;
  const size_t bB1 = bB0 + (size_t)64 * K;

  int aoff[4], boff[4];
#pragma unroll
  for (int mi = 0; mi < 4; mi++) {
    int ra = wr * 64 + mi * 16 + l16;
    int rb = wc * 64 + mi * 16 + l16;
    aoff[mi] = ra * 64 + ((kl ^ ((ra >> 1) & 3)) << 4);
    boff[mi] = rb * 64 + ((kl ^ ((rb >> 1) & 3)) << 4);
  }

  f32x4 acc[4][4];
#pragma unroll
  for (int mi = 0; mi < 4; mi++)
#pragma unroll
    for (int ni = 0; ni < 4; ni++) acc[mi][ni] = f32x4{0.f, 0.f, 0.f, 0.f};

  auto STAGE = [&](int b, int kof) {
    __bf16* L = lds + (size_t)b * NPL * PLE;
    gl16(Ah + aB0 + kof, L + tid * 8);
    gl16(Ah + aB1 + kof, L + (tid + 256) * 8);
    gl16(Bh + bB0 + kof, L + (SPLIT ? 2 : 1) * PLE + tid * 8);
    gl16(Bh + bB1 + kof, L + (SPLIT ? 2 : 1) * PLE + (tid + 256) * 8);
    if constexpr (SPLIT) {
      gl16(Al + aB0 + kof, L + PLE + tid * 8);
      gl16(Al + aB1 + kof, L + PLE + (tid + 256) * 8);
      gl16(Bl + bB0 + kof, L + 3 * PLE + tid * 8);
      gl16(Bl + bB1 + kof, L + 3 * PLE + (tid + 256) * 8);
    }
  };

  auto COMPUTE = [&](const __bf16* L) {
    const char* AsH = (const char*)L;
    const char* BsH = (const char*)(L + (SPLIT ? 2 : 1) * PLE);
    if constexpr (!SPLIT && FP16) {
      f16x8 ah[4], bh[4];
#pragma unroll
      for (int mi = 0; mi < 4; mi++) ah[mi] = *(const f16x8*)(AsH + aoff[mi]);
#pragma unroll
      for (int ni = 0; ni < 4; ni++) bh[ni] = *(const f16x8*)(BsH + boff[ni]);
#pragma unroll
      for (int mi = 0; mi < 4; mi++)
#pragma unroll
        for (int ni = 0; ni < 4; ni++)
          acc[mi][ni] = __builtin_amdgcn_mfma_f32_16x16x32_f16(ah[mi], bh[ni], acc[mi][ni], 0, 0, 0);
    } else {
      bf16x8 ah[4], bh[4];
#pragma unroll
      for (int mi = 0; mi < 4; mi++) ah[mi] = *(const bf16x8*)(AsH + aoff[mi]);
#pragma unroll
      for (int ni = 0; ni < 4; ni++) bh[ni] = *(const bf16x8*)(BsH + boff[ni]);
#pragma unroll
      for (int mi = 0; mi < 4; mi++)
#pragma unroll
        for (int ni = 0; ni < 4; ni++)
          acc[mi][ni] = __builtin_amdgcn_mfma_f32_16x16x32_bf16(ah[mi], bh[ni], acc[mi][ni], 0, 0, 0);
      if constexpr (SPLIT) {
        const char* AsL = (const char*)(L + PLE);
        const char* BsL = (const char*)(L + 3 * PLE);
        bf16x8 al[4], bl[4];
#pragma unroll
        for (int mi = 0; mi < 4; mi++) al[mi] = *(const bf16x8*)(AsL + aoff[mi]);
#pragma unroll
        for (int ni = 0; ni < 4; ni++) bl[ni] = *(const bf16x8*)(BsL + boff[ni]);
#pragma unroll
        for (int mi = 0; mi < 4; mi++)
#pragma unroll
          for (int ni = 0; ni < 4; ni++) {
            acc[mi][ni] = __builtin_amdgcn_mfma_f32_16x16x32_bf16(ah[mi], bl[ni], acc[mi][ni], 0, 0, 0);
            acc[mi][ni] = __builtin_amdgcn_mfma_f32_16x16x32_bf16(al[mi], bh[ni], acc[mi][ni], 0, 0, 0);
          }
      }
    }
  };

  if constexpr (PIPE) {
    STAGE(0, s0 * 32);
    __syncthreads();
    int cur = 0;
    for (int s = s0; s < s1; ++s) {
      if (s + 1 < s1) STAGE(cur ^ 1, (s + 1) * 32);
      COMPUTE(lds + (size_t)cur * NPL * PLE);
      __syncthreads();
      cur ^= 1;
    }
  } else {
    for (int s = s0; s < s1; ++s) {
      __syncthreads();
      STAGE(0, s * 32);
      __syncthreads();
      COMPUTE(lds);
    }
  }

  if constexpr (OBF16) {
    __bf16* __restrict__ Cp = (__bf16*)C + (size_t)z * M * N;
#pragma unroll
    for (int mi = 0; mi < 4; mi++)
#pragma unroll
      for (int ni = 0; ni < 4; ni++)
#pragma unroll
        for (int r = 0; r < 4; r++) {
          int row = m0 + wr * 64 + mi * 16 + kl * 4 + r;
          int col = n0 + wc * 64 + ni * 16 + l16;
          if (col < N) Cp[(size_t)row * N + col] = (__bf16)acc[mi][ni][r];
        }
  } else {
    float* __restrict__ Cp = (float*)C + (size_t)z * M * N;
#pragma unroll
    for (int mi = 0; mi < 4; mi++)
#pragma unroll
      for (int ni = 0; ni < 4; ni++)
#pragma unroll
        for (int r = 0; r < 4; r++) {
          int row = m0 + wr * 64 + mi * 16 + kl * 4 + r;
          int col = n0 + wc * 64 + ni * 16 + l16;
          if (col < N) Cp[(size_t)row * N + col] = acc[mi][ni][r];
        }
  }
}

// ---------------- partial reduce (bf16 planes, no residual) ----------------
__global__ void k_reduce(const __bf16* __restrict__ Pp, int np, int n4, float* __restrict__ out) {
  int i = blockIdx.x * 256 + threadIdx.x;
  int stride = gridDim.x * 256;
  for (; i < n4; i += stride) {
    f32x4 a = f32x4{0.f, 0.f, 0.f, 0.f};
    for (int z = 0; z < np; z++) {
      bf16x4 b = ((const bf16x4*)Pp)[(size_t)z * n4 + i];
#pragma unroll
      for (int j = 0; j < 4; j++) a[j] += (float)b[j];
    }
    *(f32x4*)&out[(size_t)i * 4] = a;
  }
}

// ---------------- dt finalize: sum 8 split-K partials + bias -> softplus ----------------
__global__ void k_dtfin(const float* __restrict__ dtP, const float* __restrict__ dt_bias,
                        const float* __restrict__ A_log, float* __restrict__ dtp,
                        float* __restrict__ dtA) {
  int t = blockIdx.x, h = threadIdx.x;
  if (h < HEADS) {
    float v = dt_bias[h];
#pragma unroll
    for (int z = 0; z < 8; z++) v += dtP[((size_t)z * SEQ + t) * 80 + h];
    float sp = fmaxf(v, 0.f) + log1pf(expf(-fabsf(v)));
    dtp[t * HEADS + h] = sp;
    dtA[t * HEADS + h] = sp * (-expf(A_log[h]));
  }
}

// ---------------- gather slot activations -> swz32 bf16 ----------------
__global__ __launch_bounds__(256) void k_gatherA(const float* __restrict__ xm,
                                                 const int* __restrict__ perm,
                                                 __bf16* __restrict__ Aslots) {
  int s = blockIdx.x, tid = threadIdx.x;
  int t = perm[s];
  int P = (s >> 1) & 3;
  const float* src = xm + (size_t)t * D_MODEL;
  __bf16* dst = Aslots + (size_t)s * D_MODEL;
  for (int i = tid; i < D_MODEL / 4; i += 256) {
    float4 v = ((const float4*)src)[i];
    int p = swz_p(i * 4, P);
    bf16x4 h;
    h[0] = (__bf16)v.x; h[1] = (__bf16)v.y; h[2] = (__bf16)v.z; h[3] = (__bf16)v.w;
    *(bf16x4*)&dst[p] = h;
  }
}

// ---------------- routed expert GEMM: A bf16 slots (swz32), B f32 [K][N], step split-K + M-split, dual-B ----------------
// XCD-grouped remap; Bsl row permutation (write conflicts 16->4-way). bf16 partial-plane output.
template <int KS, int MS, bool DUAL>
__global__ __launch_bounds__(256) void k_gemmE2(const __bf16* __restrict__ Aall,
                                                const float* __restrict__ Bg,
                                                const float* __restrict__ Bg2,
                                                __bf16* __restrict__ Cp,
                                                __bf16* __restrict__ Cp2,
                                                const int* __restrict__ expOff,
                                                const int* __restrict__ expCnt,
                                                int N, int K, long long strideB, int bnHalf) {
  __shared__ __bf16 Asl[2][128 * 32];
  __shared__ __bf16 Bsl[2][128][40];
  const int tid = threadIdx.x;
  // ---- XCD-grouped remap (bijective; hw xcd = linear % 8). Requires total % 8 == 0. ----
  const int nbn = gridDim.x;
  const int T = gridDim.x * gridDim.y * gridDim.z;
  const int lin = blockIdx.x + gridDim.x * (blockIdx.y + gridDim.y * blockIdx.z);
  const int s_rm = (lin & 7) * (T >> 3) + (lin >> 3);
  const int chunk = T >> 3;
  const int xcd = s_rm / chunk;
  const int cpos = s_rm % chunk;
  const int gsub = cpos / nbn;
  int bn = cpos % nbn;
  const int grp = xcd + 8 * gsub;
  const int sub = grp % (KS * MS);
  const int ks = sub % KS;
  const int mh = sub / KS;
  const int e = grp / (KS * MS);

  const int cnt = expCnt[e], base = expOff[e];
  if (cnt == 0) return;
  const float* Bp = Bg;
  __bf16* Cdst = Cp;
  if constexpr (DUAL) {
    if (bn >= bnHalf) {
      bn -= bnHalf;
      Bp = Bg2;
      Cdst = Cp2;
    }
  }
  Bp += (long long)e * strideB;
  const int n0 = bn * 128;
  const int nSteps = K / 32;
  const int st0 = (ks * nSteps) / KS;
  const int st1 = ((ks + 1) * nSteps) / KS;
  const int kBeg = st0 * 32;
  const int nIter = st1 - st0;
  __bf16* __restrict__ Cpl = Cdst + (size_t)ks * NSLOTP * N;
  const int lane = tid & 63, wid = tid >> 6;
  const int wr = wid >> 1, wc = wid & 1;
  const int l16 = lane & 15, kl = lane >> 4;
  const int kb = tid >> 5, cb = tid & 31;
  const int arow = tid >> 2, achk = (tid & 3) * 8;
  const bool bok = (n0 + cb * 4) < N;

  // Bsl physical rows for this thread's 4 written columns: (4cb+e4) -> 4cb + (e4 ^ (cb&3))
  const int cbl = cb & 3;
  int wrow[4];
#pragma unroll
  for (int e4 = 0; e4 < 4; e4++) wrow[e4] = cb * 4 + (e4 ^ cbl);

  int boffs[4];
#pragma unroll
  for (int ni = 0; ni < 4; ni++) {
    int col = wc * 64 + ni * 16 + l16;
    int prow = (col & ~3) | ((col & 3) ^ ((col >> 2) & 3));
    boffs[ni] = prow * 40 + kl * 8;
  }

  for (int bm = mh; bm * 128 < cnt; bm += MS) {
    const int rbase = base + bm * 128;
    int aoff[4];
#pragma unroll
    for (int mi = 0; mi < 4; mi++) {
      int r = wr * 64 + mi * 16 + l16;
      int P = ((rbase + r) >> 1) & 3;
      aoff[mi] = r * 64 + ((kl ^ P) << 4);
    }
    f32x4 acc[4][4];
#pragma unroll
    for (int mi = 0; mi < 4; mi++)
#pragma unroll
      for (int ni = 0; ni < 4; ni++) acc[mi][ni] = f32x4{0.f, 0.f, 0.f, 0.f};

    const size_t aBase = (size_t)(rbase + arow) * K + achk + kBeg;
    const size_t aBase2 = aBase + (size_t)64 * K;

    gl16(Aall + aBase, &Asl[0][tid * 8]);
    gl16(Aall + aBase2, &Asl[0][(tid + 256) * 8]);
    {
      const float* src = Bp + (size_t)(kBeg + kb * 4) * N + n0 + cb * 4;
      f32x4 bv[4];
#pragma unroll
      for (int j = 0; j < 4; j++)
        bv[j] = bok ? *(const f32x4*)(src + (size_t)j * N) : f32x4{0.f, 0.f, 0.f, 0.f};
#pragma unroll
      for (int e4 = 0; e4 < 4; e4++) {
        bf16x4 h;
        h[0] = (__bf16)bv[0][e4]; h[1] = (__bf16)bv[1][e4];
        h[2] = (__bf16)bv[2][e4]; h[3] = (__bf16)bv[3][e4];
        *(bf16x4*)&Bsl[0][wrow[e4]][kb * 4] = h;
      }
    }
    __syncthreads();
    int cur = 0;
    for (int kt = 0; kt < nIter; ++kt) {
      const bool more = (kt + 1 < nIter);
      f32x4 nv[4];
      if (more) {
        const int kOff = (kt + 1) * 32;
        gl16(Aall + aBase + kOff, &Asl[cur ^ 1][tid * 8]);
        gl16(Aall + aBase2 + kOff, &Asl[cur ^ 1][(tid + 256) * 8]);
        const float* src = Bp + (size_t)(kBeg + kOff + kb * 4) * N + n0 + cb * 4;
#pragma unroll
        for (int j = 0; j < 4; j++)
          nv[j] = bok ? *(const f32x4*)(src + (size_t)j * N) : f32x4{0.f, 0.f, 0.f, 0.f};
      }
      bf16x8 ah[4], bh[4];
#pragma unroll
      for (int mi = 0; mi < 4; mi++) ah[mi] = *(const bf16x8*)((const char*)&Asl[cur][0] + aoff[mi]);
#pragma unroll
      for (int ni = 0; ni < 4; ni++) bh[ni] = *(const bf16x8*)&Bsl[cur][0][boffs[ni]];
#pragma unroll
      for (int mi = 0; mi < 4; mi++)
#pragma unroll
        for (int ni = 0; ni < 4; ni++)
          acc[mi][ni] = __builtin_amdgcn_mfma_f32_16x16x32_bf16(ah[mi], bh[ni], acc[mi][ni], 0, 0, 0);
      if (more) {
#pragma unroll
        for (int e4 = 0; e4 < 4; e4++) {
          bf16x4 h;
          h[0] = (__bf16)nv[0][e4]; h[1] = (__bf16)nv[1][e4];
          h[2] = (__bf16)nv[2][e4]; h[3] = (__bf16)nv[3][e4];
          *(bf16x4*)&Bsl[cur ^ 1][wrow[e4]][kb * 4] = h;
        }
      }
      __syncthreads();
      cur ^= 1;
    }
#pragma unroll
    for (int mi = 0; mi < 4; mi++)
#pragma unroll
      for (int ni = 0; ni < 4; ni++)
#pragma unroll
        for (int r = 0; r < 4; r++) {
          int rl = bm * 128 + wr * 64 + mi * 16 + kl * 4 + r;
          int col = n0 + wc * 64 + ni * 16 + l16;
          if (rl < cnt && col < N) Cpl[(size_t)(base + rl) * N + col] = (__bf16)acc[mi][ni][r];
        }
  }
}

// ---------------- routed: reduce gate/up bf16 partials (8 planes) + silu-mul + scale -> swz32 bf16 ----------------
__global__ __launch_bounds__(256) void k_silumulE(const __bf16* __restrict__ gP,
                                                  const __bf16* __restrict__ uP,
                                                  const float* __restrict__ slotw,
                                                  __bf16* __restrict__ outp) {
  int s = blockIdx.x, tid = threadIdx.x;
  float w = slotw[s];
  int P = (s >> 1) & 3;
  const size_t PL = (size_t)NSLOTP * M_INTER;
  for (int i = tid; i < M_INTER / 4; i += 256) {
    f32x4 g = f32x4{0.f, 0.f, 0.f, 0.f}, u = f32x4{0.f, 0.f, 0.f, 0.f};
#pragma unroll
    for (int z = 0; z < 8; z++) {
      bf16x4 gv = *(const bf16x4*)&gP[z * PL + (size_t)s * M_INTER + i * 4];
      bf16x4 uv = *(const bf16x4*)&uP[z * PL + (size_t)s * M_INTER + i * 4];
#pragma unroll
      for (int j = 0; j < 4; j++) {
        g[j] += (float)gv[j];
        u[j] += (float)uv[j];
      }
    }
    int p = swz_p(i * 4, P);
    bf16x4 h;
    h[0] = (__bf16)(siluf(g[0]) * u[0] * w);
    h[1] = (__bf16)(siluf(g[1]) * u[1] * w);
    h[2] = (__bf16)(siluf(g[2]) * u[2] * w);
    h[3] = (__bf16)(siluf(g[3]) * u[3] * w);
    *(bf16x4*)&outp[(size_t)s * M_INTER + p] = h;
  }
}

// ---------------- shared: reduce combined gate|up bf16 partials + silu-mul -> swz32 bf16 ----------------
__global__ __launch_bounds__(256) void k_silumul_sh2(const __bf16* __restrict__ P4,
                                                     __bf16* __restrict__ outp) {
  int t = blockIdx.x, tid = threadIdx.x;
  int P = (t >> 1) & 3;
  const size_t PL = (size_t)SEQ * 3456;
  for (int i = tid; i < MS_INTER / 4; i += 256) {
    f32x4 g = f32x4{0.f, 0.f, 0.f, 0.f}, u = f32x4{0.f, 0.f, 0.f, 0.f};
#pragma unroll
    for (int z = 0; z < 4; z++) {
      bf16x4 gv = *(const bf16x4*)&P4[z * PL + (size_t)t * 3456 + i * 4];
      bf16x4 uv = *(const bf16x4*)&P4[z * PL + (size_t)t * 3456 + 1728 + i * 4];
#pragma unroll
      for (int j = 0; j < 4; j++) {
        g[j] += (float)gv[j];
        u[j] += (float)uv[j];
      }
    }
    int p = swz_p(i * 4, P);
    bf16x4 h;
    h[0] = (__bf16)(siluf(g[0]) * u[0]);
    h[1] = (__bf16)(siluf(g[1]) * u[1]);
    h[2] = (__bf16)(siluf(g[2]) * u[2]);
    h[3] = (__bf16)(siluf(g[3]) * u[3]);
    *(bf16x4*)&outp[(size_t)t * MS_INTER + p] = h;
  }
}

// ---------------- causal depthwise conv + SiLU ----------------
__global__ void k_conv(const float* __restrict__ zx, const float* __restrict__ cw,
                       const float* __restrict__ cb, float* __restrict__ xBC) {
  int cidx = blockIdx.x * 256 + threadIdx.x;
  int t = blockIdx.y;
  if (cidx < CONV_DIM) {
    float acc = cb[cidx];
#pragma unroll
    for (int j = 0; j < 4; j++) {
      int tt = t - 3 + j;
      if (tt >= 0) acc += zx[(size_t)tt * D_INPROJ + D_INNER + cidx] * cw[cidx * 4 + j];
    }
    xBC[(size_t)t * CONV_DIM + cidx] = siluf(acc);
  }
}

// ---------------- scan: intra-chunk (Q=64, swizzled LDS key (r>>2)&7, Cs/Gs union, fp16 X) ----------------
__global__ __launch_bounds__(256) void k_scan_intra(
    const float* __restrict__ xBC, const float* __restrict__ dtp,
    const float* __restrict__ dtA, float* __restrict__ y, float* __restrict__ S,
    float* __restrict__ cumA, float* __restrict__ Atot) {
  __shared__ float Bs[64 * 128];
  __shared__ float CG[64 * 128];
  __shared__ _Float16 Xs[64 * 64];
  __shared__ float da_s[64], a_s[64], dt_sh[64], w_sh[64];
  int c = blockIdx.x, h = blockIdx.y, tid = threadIdx.x;
  int t0 = c * QCHUNK;
#pragma unroll
  for (int i = 0; i < 8; i++) {
    int id = tid + 256 * i;
    int r = id >> 5, nc = id & 31;
    int sc = (nc ^ ((r >> 2) & 7)) * 4;
    *(float4*)&Bs[r * 128 + sc] = *(const float4*)&xBC[(size_t)(t0 + r) * CONV_DIM + D_INNER + nc * 4];
    *(float4*)&CG[r * 128 + sc] = *(const float4*)&xBC[(size_t)(t0 + r) * CONV_DIM + D_INNER + N_STATE + nc * 4];
  }
#pragma unroll
  for (int i = 0; i < 4; i++) {
    int id = tid + 256 * i;
    int r = id >> 4, p4 = (id & 15) * 4;
    float4 v = *(const float4*)&xBC[(size_t)(t0 + r) * CONV_DIM + h * P_HEAD + p4];
    f16x4 hv;
    hv[0] = (_Float16)v.x; hv[1] = (_Float16)v.y; hv[2] = (_Float16)v.z; hv[3] = (_Float16)v.w;
    *(f16x4*)&Xs[r * 64 + p4] = hv;
  }
  if (tid < 64) {
    da_s[tid] = dtA[(size_t)(t0 + tid) * HEADS + h];
    dt_sh[tid] = dtp[(size_t)(t0 + tid) * HEADS + h];
  }
  __syncthreads();
  if (tid < 64) {
    float a = 0.f;
    for (int i = 0; i <= tid; i++) a += da_s[i];
    a_s[tid] = a;
    cumA[((size_t)c * HEADS + h) * QCHUNK + tid] = a;
  }
  __syncthreads();
  if (tid < 64) {
    w_sh[tid] = __expf(a_s[63] - a_s[tid]) * dt_sh[tid];
    if (tid == 0) Atot[c * HEADS + h] = a_s[63];
  }
  __syncthreads();
  float gacc[4][4];
  {
    int tq = tid >> 4, sq = tid & 15;
#pragma unroll
    for (int j = 0; j < 4; j++)
#pragma unroll
      for (int jj = 0; jj < 4; jj++) gacc[j][jj] = 0.f;
    for (int nc = 0; nc < 32; nc++) {
      float4 cv[4], bv[4];
#pragma unroll
      for (int j = 0; j < 4; j++) {
        int rt = tq * 4 + j;
        cv[j] = *(const float4*)&CG[rt * 128 + ((nc ^ ((rt >> 2) & 7)) * 4)];
        int rs = sq * 4 + j;
        bv[j] = *(const float4*)&Bs[rs * 128 + ((nc ^ ((rs >> 2) & 7)) * 4)];
      }
#pragma unroll
      for (int j = 0; j < 4; j++)
#pragma unroll
        for (int jj = 0; jj < 4; jj++)
          gacc[j][jj] += cv[j].x * bv[jj].x + cv[j].y * bv[jj].y + cv[j].z * bv[jj].z + cv[j].w * bv[jj].w;
    }
  }
  __syncthreads();
  {
    int tq = tid >> 4, sq = tid & 15;
#pragma unroll
    for (int j = 0; j < 4; j++) {
      int t = tq * 4 + j;
      f32x4 gr;
#pragma unroll
      for (int jj = 0; jj < 4; jj++) {
        int s = sq * 4 + jj;
        float arg = fminf(a_s[t] - a_s[s], 0.f);
        gr[jj] = (s <= t) ? gacc[j][jj] * __expf(arg) * dt_sh[s] : 0.f;
      }
      *(f32x4*)&CG[t * 64 + ((sq ^ (t & 7)) * 4)] = gr;
    }
  }
  __syncthreads();
  {
    int tq = tid >> 4, pq = tid & 15;
    float4 acc[4];
#pragma unroll
    for (int j = 0; j < 4; j++) acc[j] = float4{0.f, 0.f, 0.f, 0.f};
    for (int s = 0; s < 64; s++) {
      f16x4 xh = *(const f16x4*)&Xs[s * 64 + pq * 4];
      float xv0 = (float)xh[0], xv1 = (float)xh[1], xv2 = (float)xh[2], xv3 = (float)xh[3];
#pragma unroll
      for (int j = 0; j < 4; j++) {
        int t = tq * 4 + j;
        float g = CG[t * 64 + (((s >> 2) ^ (t & 7)) * 4) + (s & 3)];
        acc[j].x += g * xv0; acc[j].y += g * xv1; acc[j].z += g * xv2; acc[j].w += g * xv3;
      }
    }
#pragma unroll
    for (int j = 0; j < 4; j++) {
      int t = tq * 4 + j;
      *(float4*)&y[(size_t)(t0 + t) * D_INNER + h * P_HEAD + pq * 4] = acc[j];
    }
  }
  {
    int p2 = tid >> 5, ncc = tid & 31;
    float4 acc[8];
#pragma unroll
    for (int j = 0; j < 8; j++) acc[j] = float4{0.f, 0.f, 0.f, 0.f};
    for (int s = 0; s < 64; s++) {
      float4 bvv = *(const float4*)&Bs[s * 128 + ((ncc ^ ((s >> 2) & 7)) * 4)];
      float ws = w_sh[s];
#pragma unroll
      for (int j = 0; j < 8; j++) {
        float xw = (float)Xs[s * 64 + p2 * 8 + j] * ws;
        acc[j].x += xw * bvv.x; acc[j].y += xw * bvv.y; acc[j].z += xw * bvv.z; acc[j].w += xw * bvv.w;
      }
    }
    size_t bb = ((size_t)(c * HEADS + h) * 64) * 128;
#pragma unroll
    for (int j = 0; j < 8; j++)
      *(float4*)&S[bb + (size_t)(p2 * 8 + j) * 128 + ncc * 4] = acc[j];
  }
}

// ---------------- scan: inter-chunk state recurrence ----------------
__global__ void k_scan_state(float* __restrict__ S, const float* __restrict__ Atot) {
  int gid = blockIdx.x * 256 + threadIdx.x;
  int h = gid >> 13;
  int rem = gid & 8191;
  float run = 0.f;
#pragma unroll
  for (int c = 0; c < NCHUNK; c++) {
    size_t idx = ((size_t)(c * HEADS + h) << 13) + rem;
    float s = S[idx];
    S[idx] = run;
    run = run * __expf(Atot[c * HEADS + h]) + s;
  }
}

// ---------------- scan: inter-chunk contribution + D*x (swizzled [64][128] Hs/Cs) ----------------
__global__ __launch_bounds__(256) void k_scan_inter(
    const float* __restrict__ xBC, const float* __restrict__ Hin,
    const float* __restrict__ cumA, const float* __restrict__ Dv,
    float* __restrict__ y) {
  __shared__ float Hs[64 * 128];
  __shared__ float Cs[64 * 128];
  __shared__ float a_l[64];
  int c = blockIdx.x, h = blockIdx.y, tid = threadIdx.x;
  int t0 = c * QCHUNK;
#pragma unroll
  for (int i = 0; i < 8; i++) {
    int id = tid + 256 * i;
    int r = id >> 5, nc = id & 31;
    int sc = (nc ^ ((r >> 2) & 7)) * 4;
    *(float4*)&Hs[r * 128 + sc] = *(const float4*)&Hin[(((size_t)(c * HEADS + h) * 64 + r) << 7) + nc * 4];
    *(float4*)&Cs[r * 128 + sc] = *(const float4*)&xBC[(size_t)(t0 + r) * CONV_DIM + D_INNER + N_STATE + nc * 4];
  }
  if (tid < 64) a_l[tid] = cumA[((size_t)c * HEADS + h) * QCHUNK + tid];
  __syncthreads();
  float Dh = Dv[h];
  int tq = tid >> 4, pq = tid & 15;
  float4 acc[4];
#pragma unroll
  for (int j = 0; j < 4; j++) acc[j] = float4{0.f, 0.f, 0.f, 0.f};
  for (int nc = 0; nc < 32; nc++) {
    float4 cv[4], hv[4];
#pragma unroll
    for (int j = 0; j < 4; j++) {
      int rt = tq * 4 + j;
      cv[j] = *(const float4*)&Cs[rt * 128 + ((nc ^ ((rt >> 2) & 7)) * 4)];
      int rp = pq * 4 + j;
      hv[j] = *(const float4*)&Hs[rp * 128 + ((nc ^ ((rp >> 2) & 7)) * 4)];
    }
#pragma unroll
    for (int j = 0; j < 4; j++) {
      acc[j].x += cv[j].x * hv[0].x + cv[j].y * hv[0].y + cv[j].z * hv[0].z + cv[j].w * hv[0].w;
      acc[j].y += cv[j].x * hv[1].x + cv[j].y * hv[1].y + cv[j].z * hv[1].z + cv[j].w * hv[1].w;
      acc[j].z += cv[j].x * hv[2].x + cv[j].y * hv[2].y + cv[j].z * hv[2].z + cv[j].w * hv[2].w;
      acc[j].w += cv[j].x * hv[3].x + cv[j].y * hv[3].y + cv[j].z * hv[3].z + cv[j].w * hv[3].w;
    }
  }
#pragma unroll
  for (int j = 0; j < 4; j++) {
    int t = tq * 4 + j;
    float e = __expf(a_l[t]);
    float4 xv = *(const float4*)&xBC[(size_t)(t0 + t) * CONV_DIM + h * P_HEAD + pq * 4];
    size_t yoff = (size_t)(t0 + t) * D_INNER + h * P_HEAD + pq * 4;
    float4 yv = *(float4*)&y[yoff];
    yv.x += e * acc[j].x + Dh * xv.x;
    yv.y += e * acc[j].y + Dh * xv.y;
    yv.z += e * acc[j].z + Dh * xv.z;
    yv.w += e * acc[j].w + Dh * xv.w;
    *(float4*)&y[yoff] = yv;
  }
}

// ---------------- gated RMSNorm -> swz32 fp16 plane ----------------
__global__ __launch_bounds__(256) void k_gatednorm_p(const float* __restrict__ y,
                                                     const float* __restrict__ zx,
                                                     const float* __restrict__ w,
                                                     __bf16* __restrict__ ph) {
  __shared__ float vbuf[D_INNER];
  __shared__ float red[4];
  int t = blockIdx.x, tid = threadIdx.x;
  float ss = 0.f;
  for (int i = tid; i < D_INNER / 4; i += 256) {
    float4 yv = *(const float4*)&y[(size_t)t * D_INNER + i * 4];
    float4 zv = *(const float4*)&zx[(size_t)t * D_INPROJ + i * 4];
    float4 v;
    v.x = yv.x * siluf(zv.x); v.y = yv.y * siluf(zv.y);
    v.z = yv.z * siluf(zv.z); v.w = yv.w * siluf(zv.w);
    *(float4*)&vbuf[i * 4] = v;
    ss += v.x * v.x + v.y * v.y + v.z * v.z + v.w * v.w;
  }
  float tot = block_sum256(ss, red);
  float r = rsqrtf(tot / (float)D_INNER + 1e-6f);
  int P = (t >> 1) & 3;
  for (int i = tid; i < D_INNER / 4; i += 256) {
    float4 v = *(const float4*)&vbuf[i * 4];
    float4 wv = *(const float4*)&w[i * 4];
    float4 o;
    o.x = wv.x * v.x * r; o.y = wv.y * v.y * r; o.z = wv.z * v.z * r; o.w = wv.w * v.w * r;
    int p = swz_p(i * 4, P);
    f16x4 hv;
    hv[0] = (_Float16)o.x; hv[1] = (_Float16)o.y; hv[2] = (_Float16)o.z; hv[3] = (_Float16)o.w;
    *(f16x4*)&ph[(size_t)t * D_INNER + p] = hv;
  }
}

// ---------------- router ----------------
__global__ void k_zero(int* counts, int* cursor) {
  int i = threadIdx.x;
  if (i < NEXP) { counts[i] = 0; cursor[i] = 0; }
}

__global__ __launch_bounds__(256) void k_router(const float* __restrict__ xm,
                                                const float* __restrict__ Wr,
                                                int* __restrict__ top_i,
                                                float* __restrict__ top_v,
                                                int* __restrict__ counts) {
  __shared__ float part[16][17];
  __shared__ float lg[16];
  int t = blockIdx.x, tid = threadIdx.x;
  int e = tid & 15, seg = tid >> 4;
  const float* xr = xm + (size_t)t * D_MODEL;
  float s = 0.f;
  for (int i = 0; i < 160; i++) {
    int k = seg * 160 + i;
    s += xr[k] * Wr[(size_t)k * NEXP + e];
  }
  part[seg][e] = s;
  __syncthreads();
  if (tid < 16) {
    float l = 0.f;
    for (int g = 0; g < 16; g++) l += part[g][tid];
    lg[tid] = l;
  }
  __syncthreads();
  if (tid == 0) {
    float mx = lg[0];
    for (int i = 1; i < 16; i++) mx = fmaxf(mx, lg[i]);
    float pe[16];
    for (int i = 0; i < 16; i++) pe[i] = expf(lg[i] - mx);
    int i0 = 0; float v0 = pe[0];
    for (int i = 1; i < 16; i++) if (pe[i] > v0) { v0 = pe[i]; i0 = i; }
    int i1 = -1; float v1 = -1.f;
    for (int i = 0; i < 16; i++) if (i != i0 && pe[i] > v1) { v1 = pe[i]; i1 = i; }
    float inv = 1.f / (v0 + v1);
    top_i[t * 2] = i0; top_i[t * 2 + 1] = i1;
    top_v[t * 2] = v0 * inv; top_v[t * 2 + 1] = v1 * inv;
    atomicAdd(&counts[i0], 1);
    atomicAdd(&counts[i1], 1);
  }
}

__global__ void k_offsets(const int* counts, int* offs, int* cursor) {
  if (threadIdx.x == 0) {
    int s = 0;
    for (int e = 0; e < NEXP; e++) { offs[e] = s; cursor[e] = s; s += counts[e]; }
  }
}

__global__ void k_scatter(const int* __restrict__ top_i, const float* __restrict__ top_v,
                          int* __restrict__ cursor, int* __restrict__ perm,
                          int* __restrict__ slotOf, float* __restrict__ slotw) {
  int t = blockIdx.x * 256 + threadIdx.x;
  if (t < SEQ) {
    for (int k = 0; k < 2; k++) {
      int e = top_i[t * 2 + k];
      int pos = atomicAdd(&cursor[e], 1);
      perm[pos] = t;
      slotOf[t * 2 + k] = pos;
      slotw[pos] = top_v[t * 2 + k];
    }
  }
}

// ---------------- final combine (3 bf16 down-partial planes) ----------------
__global__ void k_final2(const float* __restrict__ hidden, const float* __restrict__ sh,
                         const __bf16* __restrict__ dsP, const int* __restrict__ slotOf,
                         float* __restrict__ out) {
  int t = blockIdx.y;
  int d4 = (blockIdx.x * 256 + threadIdx.x) * 4;
  if (d4 < D_MODEL) {
    int s0 = slotOf[t * 2], s1 = slotOf[t * 2 + 1];
    f32x4 a = *(const f32x4*)&hidden[(size_t)t * D_MODEL + d4];
    f32x4 b = *(const f32x4*)&sh[(size_t)t * D_MODEL + d4];
    f32x4 acc = a + b;
    const size_t PL = (size_t)NSLOTP * D_MODEL;
#pragma unroll
    for (int z = 0; z < 3; z++) {
      bf16x4 p0 = *(const bf16x4*)&dsP[z * PL + (size_t)s0 * D_MODEL + d4];
      bf16x4 p1 = *(const bf16x4*)&dsP[z * PL + (size_t)s1 * D_MODEL + d4];
#pragma unroll
      for (int j = 0; j < 4; j++) acc[j] += (float)p0[j] + (float)p1[j];
    }
    *(f32x4*)&out[(size_t)t * D_MODEL + d4] = acc;
  }
}

// ---------------- launch ----------------
extern "C" void kernel_launch(void* const* d_in, const int* in_sizes, int n_in,
                              void* d_out, int out_size, void* d_ws, size_t ws_size,
                              hipStream_t stream) {
  const float* hs = (const float*)d_in[0];
  const float* w_in = (const float*)d_in[1];
  const float* conv_w = (const float*)d_in[2];
  const float* conv_b = (const float*)d_in[3];
  const float* dt_bias = (const float*)d_in[4];
  const float* A_log = (const float*)d_in[5];
  const float* Dv = (const float*)d_in[6];
  const float* mnw = (const float*)d_in[7];
  const float* w_out = (const float*)d_in[8];
  const float* ln1 = (const float*)d_in[9];
  const float* ln2 = (const float*)d_in[10];
  const float* router_w = (const float*)d_in[11];
  const float* we_gate = (const float*)d_in[12];
  const float* we_up = (const float*)d_in[13];
  const float* we_down = (const float*)d_in[14];
  const float* ws_gate = (const float*)d_in[15];
  const float* ws_up = (const float*)d_in[16];
  const float* ws_down = (const float*)d_in[17];

  char* base = (char*)d_ws;
  size_t off = 0;
  auto A = [&](size_t bytes) -> void* {
    void* p = base + off;
    off += (bytes + 255) & ~(size_t)255;
    return p;
  };
  float* xbc = (float*)A((size_t)SEQ * CONV_DIM * 4);
  float* xmf = (float*)A((size_t)SEQ * D_MODEL * 4);
  float* dtp = (float*)A((size_t)SEQ * HEADS * 4);
  float* dtA = (float*)A((size_t)SEQ * HEADS * 4);
  float* yf = (float*)A((size_t)SEQ * D_INNER * 4);
  float* cumA = (float*)A((size_t)NCHUNK * HEADS * QCHUNK * 4);
  float* Atot = (float*)A((size_t)NCHUNK * HEADS * 4);
  float* Sbuf = (float*)A((size_t)NCHUNK * HEADS * 64 * 128 * 4);
  float* hidden = (float*)A((size_t)SEQ * D_MODEL * 4);
  float* shout = (float*)A((size_t)SEQ * D_MODEL * 4);
  float* top_v = (float*)A(8192);
  float* slotw = (float*)A(8192);
  int* top_i = (int*)A(8192);
  int* counts = (int*)A(64);
  int* offs = (int*)A(64);
  int* cursor = (int*)A(64);
  int* perm = (int*)A(8192);
  int* slotOf = (int*)A(8192);
  __bf16* xp_h = (__bf16*)A((size_t)SEQ * D_MODEL * 2);
  __bf16* ybp_h = (__bf16*)A((size_t)SEQ * D_INNER * 2);
  __bf16* gbuf_bh = (__bf16*)A((size_t)SEQ * MS_INTER * 2);
  char* REG = (char*)A((size_t)163000000);

  // Phase M aliases
  __bf16* winT_h = (__bf16*)REG;                       // [10624][2560] f16 (54.4MB)
  float* zx = (float*)(REG + 60000000);                // [1024][10576] f32 (43.3MB)
  float* partials = (float*)(REG + 104000000);         // 4x1024x2560 f32 (41.9MB) — f32: feeds router
  __bf16* xdt_h = (__bf16*)(REG + 147000000);          // [1024][2560] bf16 hi (swz32)
  __bf16* xdt_l = (__bf16*)(REG + 152500000);
  __bf16* wdt_h = (__bf16*)(REG + 158000000);          // [128][2560] bf16 hi (swz32)
  __bf16* wdt_l = (__bf16*)(REG + 158700000);
  float* dtP = (float*)(REG + 159400000);              // 8x[1024][80] f32
  __bf16* woutT_h = (__bf16*)REG;                      // [2560][5120] f16 (after in_proj done)
  // Phase S aliases
  __bf16* guT = (__bf16*)REG;                          // [3456][2560] bf16 (gate | up)
  __bf16* downT = (__bf16*)(REG + 18350080);           // [2560][1728] bf16
  __bf16* partials4 = (__bf16*)(REG + 30000000);       // 4x[1024][3456] bf16 (28.3 MB)
  // Phase R aliases
  __bf16* Aslots = (__bf16*)REG;                       // [2176][2560] bf16 (11.2MB)
  __bf16* gsl = (__bf16*)(REG + 12000000);             // [2176][864] bf16 (3.8MB)
  __bf16* gateP = (__bf16*)(REG + 16000000);           // 8x[2176][864] bf16 (30.1MB, dead after silumulE)
  __bf16* upP = (__bf16*)(REG + 77000000);             // 8x[2176][864] bf16 (30.1MB, dead after silumulE)
  __bf16* dslotsP = (__bf16*)(REG + 16000000);         // 3x[2176][2560] bf16 (33.4MB, aliases dead gateP)

  // ---- Mamba sub-block ----
  k_rmsnorm_p<true><<<SEQ, 256, 0, stream>>>(hs, ln1, nullptr, xp_h, xdt_h, xdt_l, D_MODEL);
  k_transW<false, true><<<dim3(166, 40), 256, 0, stream>>>(w_in, D_INPROJ, D_MODEL, D_INPROJ,
                                                           winT_h, nullptr);
  k_transW<true, false><<<dim3(2, 40), 256, 0, stream>>>(w_in + 10496, D_INPROJ, D_MODEL, 80,
                                                         wdt_h, wdt_l);
  k_gemm2<false, true, true, false><<<dim3(8, 83, 1), 256, 0, stream>>>(
      xp_h, nullptr, winT_h, nullptr, zx, SEQ, D_INPROJ, D_MODEL, 1, 80);
  k_gemm2<true, false, false, false><<<dim3(8, 1, 8), 256, 0, stream>>>(
      xdt_h, xdt_l, wdt_h, wdt_l, dtP, SEQ, 80, D_MODEL, 8, 80);
  k_dtfin<<<SEQ, 128, 0, stream>>>(dtP, dt_bias, A_log, dtp, dtA);
  k_conv<<<dim3(21, SEQ), 256, 0, stream>>>(zx, conv_w, conv_b, xbc);
  k_scan_intra<<<dim3(NCHUNK, HEADS), 256, 0, stream>>>(xbc, dtp, dtA, yf, Sbuf, cumA, Atot);
  k_scan_state<<<2560, 256, 0, stream>>>(Sbuf, Atot);
  k_scan_inter<<<dim3(NCHUNK, HEADS), 256, 0, stream>>>(xbc, Sbuf, cumA, Dv, yf);
  k_gatednorm_p<<<SEQ, 256, 0, stream>>>(yf, zx, mnw, ybp_h);
  k_transW<false, true><<<dim3(40, 80), 256, 0, stream>>>(w_out, D_MODEL, D_INNER, D_MODEL,
                                                          woutT_h, nullptr);
  k_gemm2<false, true, true, false><<<dim3(8, 20, 4), 256, 0, stream>>>(
      ybp_h, nullptr, woutT_h, nullptr, partials, SEQ, D_MODEL, D_INNER, 4, 160);
  // fused: f32 partials+residual -> hidden; rmsnorm -> xmf + xp_h (bf16 swz32)
  k_redrms<<<SEQ, 256, 0, stream>>>(partials, hs, hidden, ln2, xmf, xp_h);

  // ---- MoE sub-block ----
  k_zero<<<1, 64, 0, stream>>>(counts, cursor);
  k_router<<<SEQ, 256, 0, stream>>>(xmf, router_w, top_i, top_v, counts);
  k_offsets<<<1, 32, 0, stream>>>(counts, offs, cursor);
  k_scatter<<<4, 256, 0, stream>>>(top_i, top_v, cursor, perm, slotOf, slotw);

  // shared experts: combined gate|up GEMM (N=3456), fused reduce+silu (bf16 partials)
  k_transW<false, false><<<dim3(27, 40), 256, 0, stream>>>(ws_gate, MS_INTER, D_MODEL, MS_INTER,
                                                           guT, nullptr);
  k_transW<false, false><<<dim3(27, 40), 256, 0, stream>>>(ws_up, MS_INTER, D_MODEL, MS_INTER,
                                                           guT + (size_t)MS_INTER * D_MODEL, nullptr);
  k_gemm2<false, false, true, true><<<dim3(8, 27, 4), 256, 0, stream>>>(
      xp_h, nullptr, guT, nullptr, partials4, SEQ, 3456, D_MODEL, 4, 80);
  k_silumul_sh2<<<SEQ, 256, 0, stream>>>(partials4, gbuf_bh);
  k_transW<false, false><<<dim3(40, 27), 256, 0, stream>>>(ws_down, D_MODEL, MS_INTER, D_MODEL,
                                                           downT, nullptr);
  k_gemm2<false, false, true, true><<<dim3(8, 20, 4), 256, 0, stream>>>(
      gbuf_bh, nullptr, downT, nullptr, partials4, SEQ, D_MODEL, MS_INTER, 4, 54);
  k_reduce<<<2048, 256, 0, stream>>>(partials4, 4, SEQ * D_MODEL / 4, shout);

  // routed experts: gate|up (KS=8, MS=1 -> 8 bf16 planes), down (KS=3, MS=2 -> 3 bf16 planes)
  k_gatherA<<<NSLOT, 256, 0, stream>>>(xmf, perm, Aslots);
  k_gemmE2<8, 1, true><<<dim3(14, 8, NEXP), 256, 0, stream>>>(
      Aslots, we_gate, we_up, gateP, upP, offs, counts,
      M_INTER, D_MODEL, (long long)D_MODEL * M_INTER, 7);
  k_silumulE<<<NSLOT, 256, 0, stream>>>(gateP, upP, slotw, gsl);
  k_gemmE2<3, 2, false><<<dim3(20, 6, NEXP), 256, 0, stream>>>(
      gsl, we_down, nullptr, dslotsP, nullptr, offs, counts,
      D_MODEL, M_INTER, (long long)M_INTER * D_MODEL, 0);

  k_final2<<<dim3(3, SEQ), 256, 0, stream>>>(hidden, shout, dslotsP, slotOf, (float*)d_out);
}